// Round 6
// baseline (1168.953 us; speedup 1.0000x reference)
//
#include <hip/hip_runtime.h>
#include <math.h>

// ---------------- problem constants ----------------
#define BB   64
#define HH   128
#define WW   128
#define GG   16
#define NN   256     // G*G tokens
#define EE   256
#define FD   320
#define NSL  8       // slots
#define NHEAD 4
#define HD   64
#define KIM  768     // 12*8*8 im2col K

#define K320P 328
#define K256P 264
#define K640P 648

using short8 = __attribute__((ext_vector_type(8))) short;
using f32x4  = __attribute__((ext_vector_type(4))) float;

__device__ __forceinline__ float sigm(float x) { return 1.0f / (1.0f + expf(-x)); }
__device__ __forceinline__ float gelu_exact(float x) {
    return 0.5f * x * (1.0f + erff(x * 0.70710678118654752f));
}
// round-to-nearest-even f32 -> bf16
__device__ __forceinline__ unsigned short f2b(float x) {
    unsigned u = __float_as_uint(x);
    u += 0x7fffu + ((u >> 16) & 1u);
    return (unsigned short)(u >> 16);
}
__device__ __forceinline__ float b2f(unsigned short u) {
    return __uint_as_float(((unsigned)u) << 16);
}
__device__ __forceinline__ void gload_lds16(const void* g, void* lds) {
    __builtin_amdgcn_global_load_lds(
        (const __attribute__((address_space(1))) unsigned int*)g,
        (__attribute__((address_space(3))) unsigned int*)lds, 16, 0, 0);
}
__device__ __forceinline__ void store_el(float* p, float v) { *p = v; }
__device__ __forceinline__ void store_el(unsigned short* p, float v) { *p = f2b(v); }

// ---------------- all weight conversions in one kernel ----------------
__global__ __launch_bounds__(256) void cvt_weights(
    const float* __restrict__ w0, const float* __restrict__ w1,
    const float* __restrict__ w2, const float* __restrict__ w3,
    const float* __restrict__ w4, const float* __restrict__ w5,
    const float* __restrict__ w6, const float* __restrict__ w7,
    const float* __restrict__ w8, const float* __restrict__ w9,
    const float* __restrict__ w10, const float* __restrict__ w11,
    unsigned short* __restrict__ dst) {
    int i = blockIdx.x * 256 + threadIdx.x;   // < 2011136
    float v;
    if      (i <  196608) v = w0[i];
    else if (i <  327680) v = w1[i - 196608];
    else if (i <  458752) v = w2[i - 327680];
    else if (i <  655360) v = w3[i - 458752];
    else if (i <  720896) v = w4[i - 655360];
    else if (i <  802816) v = w5[i - 720896];
    else if (i <  884736) v = w6[i - 802816];
    else if (i <  987136) v = w7[i - 884736];
    else if (i < 1294336) v = w8[i - 987136];
    else if (i < 1601536) v = w9[i - 1294336];
    else if (i < 1806336) v = w10[i - 1601536];
    else                  v = w11[i - 1806336];
    dst[i] = f2b(v);
}

// ---------------- RoPE tables: cs/sn[n][d], n<256, d<64 ----------------
__global__ __launch_bounds__(256) void rope_tab(float* __restrict__ cs,
                                                float* __restrict__ sn) {
    int i = blockIdx.x * 256 + threadIdx.x;   // 16384
    int d = i & 63, n = i >> 6;
    int pos = (d < 32) ? (n >> 4) : (n & 15);
    int j = d & 31;
    float freq = powf(10000.0f, -(float)(j & 15) / 16.0f);
    float p = (float)pos * freq;
    float ang = (j < 16) ? sinf(p) : cosf(p);
    cs[i] = cosf(ang);
    sn[i] = sinf(ang);
}

// ---------------- Sobel + one-hot + im2col (bf16 out, exact) ----------------
__global__ __launch_bounds__(256) void sobel_im2col(const float* __restrict__ state,
                                                    unsigned short* __restrict__ X0) {
    int idx = blockIdx.x * 256 + threadIdx.x;
    if (idx >= BB * HH * WW) return;
    int w = idx % WW;
    int h = (idx / WW) % HH;
    int b = idx / (HH * WW);
    const float* st = state + (long)b * HH * WW;
    auto at = [&](int y, int x) {
        y = min(max(y, 0), HH - 1);
        x = min(max(x, 0), WW - 1);
        return st[y * WW + x];
    };
    float v00 = at(h-1, w-1), v01 = at(h-1, w), v02 = at(h-1, w+1);
    float v10 = at(h,   w-1),                  v12 = at(h,   w+1);
    float v20 = at(h+1, w-1), v21 = at(h+1, w), v22 = at(h+1, w+1);
    float sx = (v02 - v00) + 2.0f * (v12 - v10) + (v22 - v20);
    float sy = (v20 - v00) + 2.0f * (v21 - v01) + (v22 - v02);
    int id = (int)st[h * WW + w];
    int gy = h >> 3, i = h & 7, gx = w >> 3, j = w & 7;
    long row = (long)b * NN + gy * GG + gx;
    unsigned short* xr = X0 + row * KIM + i * 8 + j;
#pragma unroll
    for (int c = 0; c < 10; c++) xr[c * 64] = (id == c) ? 0x3F80u : 0u;
    xr[10 * 64] = f2b(sx);
    xr[11 * 64] = f2b(sy);
}

// ---------------- bf16 MFMA NT GEMM (big path) ----------------
// tr==1: Cb written transposed per-256-row-batch: [(row>>8)][col][row&255]
template <int BM, int BN, int ACT>
__global__ __launch_bounds__(256) void gemm_bf16(
    const unsigned short* __restrict__ A, const unsigned short* __restrict__ W,
    const float* __restrict__ bias, const float* __restrict__ res,
    float* __restrict__ C, unsigned short* __restrict__ Cb,
    int K, long sA, long sW, long sC1, long sC2, int cdiv, int ldc, float scale,
    int tr)
{
    constexpr int WN = BN / 64;
    __shared__ __align__(16) unsigned short As[BM * 32];
    __shared__ __align__(16) unsigned short Bs[BN * 32];
    const int tid = threadIdx.x;
    const int w = tid >> 6, l = tid & 63;
    const int wm = w / WN, wn = w % WN;
    const int bz = blockIdx.z;
    const unsigned short* Ab = A + (long)bz * sA + (long)(blockIdx.y * BM) * K;
    const unsigned short* Wb = W + (long)bz * sW + (long)(blockIdx.x * BN) * K;
    const long offC = (long)(bz / cdiv) * sC1 + (long)(bz % cdiv) * sC2;

    const int rA  = l >> 2;
    const int swz = ((l & 3) ^ ((l >> 3) & 3)) * 8;

    f32x4 acc[4][4] = {};

    for (int k0 = 0; k0 < K; k0 += 32) {
#pragma unroll
        for (int c = 0; c < BM / 64; c++) {
            const int chunk = w * (BM / 64) + c;
            gload_lds16(Ab + (long)(chunk * 16 + rA) * K + k0 + swz, (char*)As + chunk * 1024);
        }
#pragma unroll
        for (int c = 0; c < BN / 64; c++) {
            const int chunk = w * (BN / 64) + c;
            gload_lds16(Wb + (long)(chunk * 16 + rA) * K + k0 + swz, (char*)Bs + chunk * 1024);
        }
        __syncthreads();
        short8 af[4], bfr[4];
#pragma unroll
        for (int m = 0; m < 4; m++) {
            const int row = wm * 64 + m * 16 + (l & 15);
            const int byte = row * 64 + (((l >> 4) ^ ((row >> 1) & 3)) << 4);
            af[m] = *(const short8*)((const char*)As + byte);
        }
#pragma unroll
        for (int n = 0; n < 4; n++) {
            const int row = wn * 64 + n * 16 + (l & 15);
            const int byte = row * 64 + (((l >> 4) ^ ((row >> 1) & 3)) << 4);
            bfr[n] = *(const short8*)((const char*)Bs + byte);
        }
#pragma unroll
        for (int m = 0; m < 4; m++)
#pragma unroll
            for (int n = 0; n < 4; n++)
                acc[m][n] = __builtin_amdgcn_mfma_f32_16x16x32_bf16(af[m], bfr[n], acc[m][n], 0, 0, 0);
        __syncthreads();
    }

    const int crow0 = blockIdx.y * BM + wm * 64;
    const int ccol0 = blockIdx.x * BN + wn * 64;
#pragma unroll
    for (int m = 0; m < 4; m++) {
#pragma unroll
        for (int n = 0; n < 4; n++) {
            const int row = crow0 + m * 16 + ((l >> 4) << 2);
            const int col = ccol0 + n * 16 + (l & 15);
#pragma unroll
            for (int r = 0; r < 4; r++) {
                float v = acc[m][n][r] * scale;
                if (bias) v += bias[col];
                if (ACT == 1) v = gelu_exact(v);
                const long idx = offC + (long)(row + r) * ldc + col;
                if (res) v += res[idx];
                if (C)  C[idx] = v;
                if (Cb) {
                    long cidx = tr ? (((long)((row + r) >> 8) * ldc + col) * 256 + ((row + r) & 255))
                                   : idx;
                    Cb[cidx] = f2b(v);
                }
            }
        }
    }
}

// ---------------- LayerNorm (wave per row) ----------------
template <typename OT>
__global__ __launch_bounds__(256) void ln_rows(const float* __restrict__ X,
                                               OT* __restrict__ Y,
                                               const float* __restrict__ g,
                                               const float* __restrict__ b,
                                               int rows, int D) {
    int gtid = blockIdx.x * 256 + threadIdx.x;
    int row = gtid >> 6;
    int lane = gtid & 63;
    if (row >= rows) return;
    const float* x = X + (long)row * D;
    const int nv = D >> 6;
    float v[5];
    float s = 0.0f;
#pragma unroll 5
    for (int i = 0; i < nv; i++) { v[i] = x[lane + (i << 6)]; s += v[i]; }
#pragma unroll
    for (int o = 32; o; o >>= 1) s += __shfl_down(s, o);
    s = __shfl(s, 0);
    float mean = s / (float)D;
    float s2 = 0.0f;
#pragma unroll 5
    for (int i = 0; i < nv; i++) { float d = v[i] - mean; s2 += d * d; }
#pragma unroll
    for (int o = 32; o; o >>= 1) s2 += __shfl_down(s2, o);
    s2 = __shfl(s2, 0);
    float inv = rsqrtf(s2 / (float)D + 1e-5f);
    OT* y = Y + (long)row * D;
#pragma unroll 5
    for (int i = 0; i < nv; i++) {
        int d = lane + (i << 6);
        store_el(&y[d], (v[i] - mean) * inv * g[d] + b[d]);
    }
}

// ---------------- table-driven RoPE: QKVb -> Qr, Kr (bf16) ----------------
__global__ __launch_bounds__(256) void rope_qk(const unsigned short* __restrict__ QKVb,
                                               const float* __restrict__ cs,
                                               const float* __restrict__ sn,
                                               unsigned short* __restrict__ Qr,
                                               unsigned short* __restrict__ Kr) {
    const int rid = blockIdx.x * 256 + threadIdx.x;   // b*1024 + h*256 + n
    const int n = rid & 255;
    const int h = (rid >> 8) & 3;
    const int b = rid >> 10;
    const unsigned short* src = QKVb + ((long)(b * 256 + n)) * 768 + h * 64;
    float cv[64], sv[64];
#pragma unroll
    for (int i = 0; i < 16; i++) {
        *(float4*)&cv[i * 4] = *(const float4*)(cs + n * 64 + i * 4);
        *(float4*)&sv[i * 4] = *(const float4*)(sn + n * 64 + i * 4);
    }
#pragma unroll
    for (int qk = 0; qk < 2; qk++) {
        const unsigned short* s0 = src + qk * 256;
        unsigned short* dst = (qk == 0 ? Qr : Kr) + (long)rid * 64;
        float x[64];
#pragma unroll
        for (int i = 0; i < 8; i++) {
            short8 v = *(const short8*)(s0 + i * 8);
#pragma unroll
            for (int j = 0; j < 8; j++) x[i * 8 + j] = b2f((unsigned short)v[j]);
        }
        unsigned short o[64];
#pragma unroll
        for (int d = 0; d < 64; d++) {
            const float rot = (d < 32) ? -x[2 * d + 1] : x[2 * (d - 32)];
            o[d] = f2b(x[d] * cv[d] + rot * sv[d]);
        }
#pragma unroll
        for (int i = 0; i < 8; i++)
            *(short8*)(dst + i * 8) = *(short8*)&o[i * 8];
    }
}

// ---------------- fused attention: one wg per (b,h) ----------------
__global__ __launch_bounds__(256, 1) void fused_attn(
    const unsigned short* __restrict__ Qr,
    const unsigned short* __restrict__ Kr,
    const unsigned short* __restrict__ QKVb,
    unsigned short* __restrict__ AOb)
{
    __shared__ __align__(16) char SL[49152];   // V^T 32KB + P 16KB
    const int h = blockIdx.x, b = blockIdx.y;
    const int tid = threadIdx.x;
    const int w = tid >> 6, l = tid & 63;
    const int gw = l >> 4, l15 = l & 15;
    const long bh = (long)b * 4 + h;
    const unsigned short* Qb = Qr + bh * NN * 64;
    const unsigned short* Kb = Kr + bh * NN * 64;

    {
        const int n0 = (tid & 127) * 2;
        const int dh = tid >> 7;
        const unsigned short* v0p = QKVb + ((long)b * NN + n0) * 768 + h * 64 + 512 + dh * 32;
        const unsigned short* v1p = v0p + 768;
        unsigned short v0[32], v1[32];
#pragma unroll
        for (int i = 0; i < 4; i++) {
            *(short8*)&v0[i * 8] = *(const short8*)(v0p + i * 8);
            *(short8*)&v1[i * 8] = *(const short8*)(v1p + i * 8);
        }
#pragma unroll
        for (int i = 0; i < 32; i++) {
            const int d = dh * 32 + i;
            const unsigned val = (unsigned)v0[i] | ((unsigned)v1[i] << 16);
            *(unsigned*)(SL + d * 512 + (((n0 >> 3) ^ (d & 15)) << 4) + (n0 & 7) * 2) = val;
        }
    }
    __syncthreads();

    char* Pw = SL + 32768 + w * 4096;

#pragma unroll
    for (int p = 0; p < 2; p++) {
        const int mbase = w * 64 + p * 32;
        f32x4 accs[16][2] = {};
#pragma unroll
        for (int kk = 0; kk < 2; kk++) {
            short8 bq[2];
#pragma unroll
            for (int mf = 0; mf < 2; mf++)
                bq[mf] = *(const short8*)(Qb + ((mbase + mf * 16 + l15) << 6) + kk * 32 + gw * 8);
#pragma unroll
            for (int nf = 0; nf < 16; nf++) {
                const short8 ak = *(const short8*)(Kb + ((nf * 16 + l15) << 6) + kk * 32 + gw * 8);
#pragma unroll
                for (int mf = 0; mf < 2; mf++)
                    accs[nf][mf] = __builtin_amdgcn_mfma_f32_16x16x32_bf16(ak, bq[mf], accs[nf][mf], 0, 0, 0);
            }
        }
        float rs[2];
#pragma unroll
        for (int mf = 0; mf < 2; mf++) {
            float mx = -1e30f;
#pragma unroll
            for (int nf = 0; nf < 16; nf++)
#pragma unroll
                for (int r = 0; r < 4; r++) mx = fmaxf(mx, accs[nf][mf][r]);
            mx = fmaxf(mx, __shfl_xor(mx, 16));
            mx = fmaxf(mx, __shfl_xor(mx, 32));
            float sum = 0.0f;
#pragma unroll
            for (int nf = 0; nf < 16; nf++)
#pragma unroll
                for (int r = 0; r < 4; r++) {
                    const float e = expf((accs[nf][mf][r] - mx) * 0.125f);
                    accs[nf][mf][r] = e;
                    sum += e;
                }
            sum += __shfl_xor(sum, 16);
            sum += __shfl_xor(sum, 32);
            rs[mf] = 1.0f / sum;
        }
        f32x4 acco[4][2] = {};
#pragma unroll
        for (int c = 0; c < 4; c++) {
#pragma unroll
            for (int nfi = 0; nfi < 4; nfi++) {
                const int nf = c * 4 + nfi;
                const int kt = nf >> 1;
                const int gr = (nf & 1) * 2 + (gw >> 1);
                const int lr = l15 + 16 * gr;
                const int j0 = (gw & 1) * 4;
#pragma unroll
                for (int mf = 0; mf < 2; mf++) {
                    uint2 pk;
                    pk.x = (unsigned)f2b(accs[nf][mf][0] * rs[mf]) |
                           ((unsigned)f2b(accs[nf][mf][1] * rs[mf]) << 16);
                    pk.y = (unsigned)f2b(accs[nf][mf][2] * rs[mf]) |
                           ((unsigned)f2b(accs[nf][mf][3] * rs[mf]) << 16);
                    *(uint2*)(Pw + ((kt & 1) * 2 + mf) * 1024 + lr * 16 + j0 * 2) = pk;
                }
            }
#pragma unroll
            for (int kti = 0; kti < 2; kti++) {
                const int kt = c * 2 + kti;
                short8 vf[4];
#pragma unroll
                for (int df = 0; df < 4; df++) {
                    const int d = df * 16 + l15;
                    vf[df] = *(const short8*)(SL + d * 512 + (((kt * 4 + gw) ^ (d & 15)) << 4));
                }
#pragma unroll
                for (int mf = 0; mf < 2; mf++) {
                    const short8 pf = *(const short8*)(Pw + (kti * 2 + mf) * 1024 + l * 16);
#pragma unroll
                    for (int df = 0; df < 4; df++)
                        acco[df][mf] = __builtin_amdgcn_mfma_f32_16x16x32_bf16(vf[df], pf, acco[df][mf], 0, 0, 0);
                }
            }
        }
#pragma unroll
        for (int df = 0; df < 4; df++)
#pragma unroll
            for (int mf = 0; mf < 2; mf++) {
                const int m = mbase + mf * 16 + l15;
                const int d = df * 16 + gw * 4;
                unsigned short o[4];
#pragma unroll
                for (int r = 0; r < 4; r++) o[r] = f2b(acco[df][mf][r]);
                *(uint2*)(AOb + ((long)(b * NN + m) * 256 + h * 64 + d)) = *(uint2*)o;
            }
    }
}

// ---------------- fully fused slot-attention loop: one wg per batch ----------------
// 64 blocks x 256 threads. All 3 iterations; writes slots + masks to out.
__global__ __launch_bounds__(256, 1) void fused_slots(
    const unsigned short* __restrict__ Kinb,   // [B][256][320]
    const unsigned short* __restrict__ Vtb,    // [B][320][256]
    const unsigned short* __restrict__ q_wb,   // [320][320]
    const unsigned short* __restrict__ wihb,   // [960][320]
    const unsigned short* __restrict__ whhb,   // [960][320]
    const unsigned short* __restrict__ s1b,    // [640][320]
    const unsigned short* __restrict__ s2b,    // [320][640]
    const float* __restrict__ ns_g, const float* __restrict__ ns_b,
    const float* __restrict__ nm_g, const float* __restrict__ nm_b,
    const float* __restrict__ bih, const float* __restrict__ bhh,
    const float* __restrict__ sb1, const float* __restrict__ sb2,
    float* __restrict__ out)
{
    __shared__ float slots[8][320];                          // 10240
    __shared__ __align__(16) unsigned short slotsb[16][K320P]; // 10496
    __shared__ __align__(16) unsigned short sln[16][K320P];    // 10496
    __shared__ __align__(16) char D[27136];                    // scratch union
    __shared__ float colsum[8];
    __shared__ float wred[4][8];

    unsigned short* q_s  = (unsigned short*)D;               // [16][K320P]
    unsigned short* updm = (unsigned short*)D;               // [16][K320P] (after q_s dead)
    float*          P    = (float*)(D + 10496);              // [256][8]
    unsigned short* anT  = (unsigned short*)(D + 18688);     // [16][K256P]
    unsigned short* Mh   = (unsigned short*)D;               // [16][K640P] (phase 2)

    const int b = blockIdx.x;
    const int tid = threadIdx.x;
    const int w = tid >> 6, l = tid & 63;
    const int gw = l >> 4, l15 = l & 15;

    // init: zero slots, pad rows 8..15 of slotsb/sln/anT
    for (int i = tid; i < 8 * 320; i += 256) ((float*)slots)[i] = 0.0f;
    for (int i = tid; i < 8 * K320P; i += 256) {
        ((unsigned short*)slotsb)[8 * K320P + i] = 0;
        ((unsigned short*)sln)[8 * K320P + i] = 0;
    }
    for (int i = tid; i < 8 * K256P; i += 256) anT[8 * K256P + i] = 0;
    __syncthreads();

    for (int it = 0; it < 3; ++it) {
        // ---- 1. slotsb = bf16(slots); sln = bf16(LN_ns(slots))
        for (int rr = w; rr < 8; rr += 4) {
            const float* x = slots[rr];
            float v[5]; float s = 0.0f;
#pragma unroll
            for (int i = 0; i < 5; i++) { v[i] = x[l + (i << 6)]; s += v[i]; }
#pragma unroll
            for (int o = 32; o; o >>= 1) s += __shfl_down(s, o);
            s = __shfl(s, 0);
            const float mean = s * (1.0f / FD);
            float s2 = 0.0f;
#pragma unroll
            for (int i = 0; i < 5; i++) { const float d = v[i] - mean; s2 += d * d; }
#pragma unroll
            for (int o = 32; o; o >>= 1) s2 += __shfl_down(s2, o);
            s2 = __shfl(s2, 0);
            const float inv = rsqrtf(s2 * (1.0f / FD) + 1e-5f);
#pragma unroll
            for (int i = 0; i < 5; i++) {
                const int f = l + (i << 6);
                sln[rr][f] = f2b((v[i] - mean) * inv * ns_g[f] + ns_b[f]);
                slotsb[rr][f] = f2b(v[i]);
            }
        }
        __syncthreads();

        // ---- 2. q_s = sln @ q_w^T  (M=16 pad, N=320, K=320)
        {
            f32x4 acc[5] = {};
            for (int k0 = 0; k0 < 320; k0 += 32) {
                const short8 af = *(const short8*)&sln[l15][k0 + gw * 8];
#pragma unroll
                for (int j = 0; j < 5; j++) {
                    const int n0 = (w * 5 + j) * 16;
                    const short8 bf = *(const short8*)(q_wb + (long)(n0 + l15) * 320 + k0 + gw * 8);
                    acc[j] = __builtin_amdgcn_mfma_f32_16x16x32_bf16(af, bf, acc[j], 0, 0, 0);
                }
            }
#pragma unroll
            for (int j = 0; j < 5; j++) {
                const int col = (w * 5 + j) * 16 + l15;
#pragma unroll
                for (int r = 0; r < 4; r++)
                    q_s[(gw * 4 + r) * K320P + col] = f2b(acc[j][r]);
            }
        }
        __syncthreads();

        // ---- 3. logits = Kin @ q_s^T, softmax over s, colsum
        {
            f32x4 acc[4] = {};
            const unsigned short* Kb = Kinb + (long)b * 256 * 320;
            for (int k0 = 0; k0 < 320; k0 += 32) {
                const short8 bf = *(const short8*)&q_s[l15 * K320P + k0 + gw * 8];
#pragma unroll
                for (int mt = 0; mt < 4; mt++) {
                    const int row = (w * 4 + mt) * 16 + l15;
                    const short8 af = *(const short8*)(Kb + (long)row * 320 + k0 + gw * 8);
                    acc[mt] = __builtin_amdgcn_mfma_f32_16x16x32_bf16(af, bf, acc[mt], 0, 0, 0);
                }
            }
            float psum = 0.0f;
#pragma unroll
            for (int mt = 0; mt < 4; mt++) {
#pragma unroll
                for (int r = 0; r < 4; r++) {
                    const float val = acc[mt][r] * 0.055901699437494740f;  // 1/sqrt(320)
                    float mx = val;
                    mx = fmaxf(mx, __shfl_xor(mx, 1));
                    mx = fmaxf(mx, __shfl_xor(mx, 2));
                    mx = fmaxf(mx, __shfl_xor(mx, 4));
                    const float e = expf(val - mx);
                    float sum = e;
                    sum += __shfl_xor(sum, 1);
                    sum += __shfl_xor(sum, 2);
                    sum += __shfl_xor(sum, 4);
                    const float p = e / sum;
                    const int t = (w * 4 + mt) * 16 + gw * 4 + r;
                    if (l15 < 8) P[t * 8 + l15] = p;
                    psum += p;
                }
            }
            psum += __shfl_down(psum, 32);
            psum += __shfl_down(psum, 16);
            if (gw == 0 && l15 < 8) wred[w][l15] = psum;
        }
        __syncthreads();
        if (tid < 8) colsum[tid] = wred[0][tid] + wred[1][tid] + wred[2][tid] + wred[3][tid]
                                   + (float)NN * 1e-8f;
        __syncthreads();

        // ---- masks out on final iteration (P still live)
        if (it == 2) {
            const int n = tid;
#pragma unroll
            for (int s = 0; s < 8; s++)
                out[163840 + b * 2048 + s * 256 + n] = P[n * 8 + s];
        }

        // ---- 4. anT[s][n] = bf16((P+1e-8)/colsum)
        {
            const int n = tid;
#pragma unroll
            for (int s = 0; s < 8; s++)
                anT[s * K256P + n] = f2b((P[n * 8 + s] + 1e-8f) / colsum[s]);
        }
        __syncthreads();

        // ---- 5. updates = anT @ Vt^T  (M=16 pad, N=320, K=256)
        {
            f32x4 acc[5] = {};
            const unsigned short* Vb = Vtb + (long)b * 320 * 256;
            for (int k0 = 0; k0 < 256; k0 += 32) {
                const short8 af = *(const short8*)&anT[l15 * K256P + k0 + gw * 8];
#pragma unroll
                for (int j = 0; j < 5; j++) {
                    const int f0 = (w * 5 + j) * 16;
                    const short8 bf = *(const short8*)(Vb + (long)(f0 + l15) * 256 + k0 + gw * 8);
                    acc[j] = __builtin_amdgcn_mfma_f32_16x16x32_bf16(af, bf, acc[j], 0, 0, 0);
                }
            }
#pragma unroll
            for (int j = 0; j < 5; j++) {
                const int col = (w * 5 + j) * 16 + l15;
#pragma unroll
                for (int r = 0; r < 4; r++)
                    updm[(gw * 4 + r) * K320P + col] = f2b(acc[j][r]);
            }
        }
        __syncthreads();

        // ---- 6. GRU: GI = upd@wih^T, GH = slotsb@whh^T, gate combine (accs in regs)
        {
            f32x4 gi[3][5] = {}, gh[3][5] = {};
            for (int k0 = 0; k0 < 320; k0 += 32) {
                const short8 ai = *(const short8*)&updm[l15 * K320P + k0 + gw * 8];
                const short8 ah = *(const short8*)&slotsb[l15][k0 + gw * 8];
#pragma unroll
                for (int g = 0; g < 3; g++)
#pragma unroll
                    for (int j = 0; j < 5; j++) {
                        const int n0 = (g * 20 + w * 5 + j) * 16;
                        const short8 bi = *(const short8*)(wihb + (long)(n0 + l15) * 320 + k0 + gw * 8);
                        gi[g][j] = __builtin_amdgcn_mfma_f32_16x16x32_bf16(ai, bi, gi[g][j], 0, 0, 0);
                        const short8 bh2 = *(const short8*)(whhb + (long)(n0 + l15) * 320 + k0 + gw * 8);
                        gh[g][j] = __builtin_amdgcn_mfma_f32_16x16x32_bf16(ah, bh2, gh[g][j], 0, 0, 0);
                    }
            }
#pragma unroll
            for (int j = 0; j < 5; j++) {
                const int f = (w * 5 + j) * 16 + l15;
#pragma unroll
                for (int r = 0; r < 4; r++) {
                    const int s = gw * 4 + r;
                    if (s < 8) {
                        const float gir = gi[0][j][r] + bih[f],       ghr = gh[0][j][r] + bhh[f];
                        const float giz = gi[1][j][r] + bih[320 + f], ghz = gh[1][j][r] + bhh[320 + f];
                        const float gin = gi[2][j][r] + bih[640 + f], ghn = gh[2][j][r] + bhh[640 + f];
                        const float rr2 = sigm(gir + ghr);
                        const float z   = sigm(giz + ghz);
                        const float nn2 = tanhf(gin + rr2 * ghn);
                        slots[s][f] = (1.0f - z) * nn2 + z * slots[s][f];
                    }
                }
            }
        }
        __syncthreads();

        // ---- 7. LN(nm)(slots) -> sln
        for (int rr = w; rr < 8; rr += 4) {
            const float* x = slots[rr];
            float v[5]; float s = 0.0f;
#pragma unroll
            for (int i = 0; i < 5; i++) { v[i] = x[l + (i << 6)]; s += v[i]; }
#pragma unroll
            for (int o = 32; o; o >>= 1) s += __shfl_down(s, o);
            s = __shfl(s, 0);
            const float mean = s * (1.0f / FD);
            float s2 = 0.0f;
#pragma unroll
            for (int i = 0; i < 5; i++) { const float d = v[i] - mean; s2 += d * d; }
#pragma unroll
            for (int o = 32; o; o >>= 1) s2 += __shfl_down(s2, o);
            s2 = __shfl(s2, 0);
            const float inv = rsqrtf(s2 * (1.0f / FD) + 1e-5f);
#pragma unroll
            for (int i = 0; i < 5; i++) {
                const int f = l + (i << 6);
                sln[rr][f] = f2b((v[i] - mean) * inv * nm_g[f] + nm_b[f]);
            }
        }
        __syncthreads();

        // ---- 8. smlp1: Mh = gelu(sln @ s1^T + b1)  (N=640, K=320)
        {
            f32x4 acc[10] = {};
            for (int k0 = 0; k0 < 320; k0 += 32) {
                const short8 af = *(const short8*)&sln[l15][k0 + gw * 8];
#pragma unroll
                for (int j = 0; j < 10; j++) {
                    const int n0 = (w * 10 + j) * 16;
                    const short8 bf = *(const short8*)(s1b + (long)(n0 + l15) * 320 + k0 + gw * 8);
                    acc[j] = __builtin_amdgcn_mfma_f32_16x16x32_bf16(af, bf, acc[j], 0, 0, 0);
                }
            }
#pragma unroll
            for (int j = 0; j < 10; j++) {
                const int col = (w * 10 + j) * 16 + l15;
#pragma unroll
                for (int r = 0; r < 4; r++)
                    Mh[(gw * 4 + r) * K640P + col] = f2b(gelu_exact(acc[j][r] + sb1[col]));
            }
        }
        __syncthreads();

        // ---- 9. smlp2: slots += Mh @ s2^T + b2  (N=320, K=640)
        {
            f32x4 acc[5] = {};
            for (int k0 = 0; k0 < 640; k0 += 32) {
                const short8 af = *(const short8*)&Mh[l15 * K640P + k0 + gw * 8];
#pragma unroll
                for (int j = 0; j < 5; j++) {
                    const int n0 = (w * 5 + j) * 16;
                    const short8 bf = *(const short8*)(s2b + (long)(n0 + l15) * 640 + k0 + gw * 8);
                    acc[j] = __builtin_amdgcn_mfma_f32_16x16x32_bf16(af, bf, acc[j], 0, 0, 0);
                }
            }
#pragma unroll
            for (int j = 0; j < 5; j++) {
                const int col = (w * 5 + j) * 16 + l15;
#pragma unroll
                for (int r = 0; r < 4; r++) {
                    const int s = gw * 4 + r;
                    if (s < 8) slots[s][col] += acc[j][r] + sb2[col];
                }
            }
        }
        __syncthreads();
    }

    // ---- final slots out
    for (int i = tid; i < 2560; i += 256)
        out[b * 2560 + i] = ((const float*)slots)[i];
}

// ---------------- host launcher ----------------
extern "C" void kernel_launch(void* const* d_in, const int* in_sizes, int n_in,
                              void* d_out, int out_size, void* d_ws, size_t ws_size,
                              hipStream_t stream) {
    const float* state    = (const float*)d_in[0];
    const float* conv_w   = (const float*)d_in[1];
    const float* conv_b   = (const float*)d_in[2];
    const float* mlp_ln_g = (const float*)d_in[3];
    const float* mlp_ln_b = (const float*)d_in[4];
    const float* mlp_w1   = (const float*)d_in[5];
    const float* mlp_b1   = (const float*)d_in[6];
    const float* mlp_w2   = (const float*)d_in[7];
    const float* mlp_b2   = (const float*)d_in[8];
    const float* qkv_w    = (const float*)d_in[9];
    const float* qkv_b    = (const float*)d_in[10];
    const float* proj_w   = (const float*)d_in[11];
    const float* proj_b   = (const float*)d_in[12];
    const float* ni_g     = (const float*)d_in[13];
    const float* ni_b     = (const float*)d_in[14];
    const float* ns_g     = (const float*)d_in[15];
    const float* ns_b     = (const float*)d_in[16];
    const float* nm_g     = (const float*)d_in[17];
    const float* nm_b     = (const float*)d_in[18];
    const float* q_w      = (const float*)d_in[19];
    const float* k_w      = (const float*)d_in[20];
    const float* v_w      = (const float*)d_in[21];
    const float* gru_wih  = (const float*)d_in[22];
    const float* gru_whh  = (const float*)d_in[23];
    const float* gru_bih  = (const float*)d_in[24];
    const float* gru_bhh  = (const float*)d_in[25];
    const float* smlp_w1  = (const float*)d_in[26];
    const float* smlp_b1  = (const float*)d_in[27];
    const float* smlp_w2  = (const float*)d_in[28];
    const float* smlp_b2  = (const float*)d_in[29];

    float* ws = (float*)d_ws;
    const int M = BB * NN;  // 16384
    typedef unsigned short u16;

    // ---- workspace layout (float offsets) ----
    u16*   X0b  = (u16*)(ws + 0L);
    u16*   Qr   = (u16*)(ws + 0L);
    u16*   Kr   = (u16*)(ws + 2097152L);
    float* X1   = ws + 6291456L;
    u16*   XLNb = (u16*)(ws + 10485760L);
    u16*   Hbufb= (u16*)(ws + 12582912L);
    u16*   QKVb = (u16*)(ws + 6291456L);
    u16*   X2b  = (u16*)(ws + 23068672L);
    float* X2   = ws + 31457280L;
    u16*   Xnb  = (u16*)(ws + 31457280L);
    float* X3   = ws + 35651584L;
    u16*   Kinb = (u16*)(ws + 39845888L);   // 5242880 u16
    u16*   Vtb  = (u16*)(ws + 42467328L);   // 5242880 u16
    u16*   AOb    = (u16*)(ws + 50331648L);
    u16*   wb     = (u16*)(ws + 52428800L); // 2011136 u16 contiguous
    u16*   conv_wb= wb + 0;
    u16*   mlp_w1b= wb + 196608;
    u16*   mlp_w2b= wb + 327680;
    u16*   qkv_wb = wb + 458752;
    u16*   proj_wb= wb + 655360;
    u16*   k_wb   = wb + 720896;
    u16*   v_wb   = wb + 802816;
    u16*   q_wb   = wb + 884736;
    u16*   wihb   = wb + 987136;
    u16*   whhb   = wb + 1294336;
    u16*   smlp1b = wb + 1601536;
    u16*   smlp2b = wb + 1806336;
    float* CS     = ws + 53434368L;
    float* SN     = ws + 53450752L;

    float* out = (float*)d_out;

    auto gemmA = [&](const u16* A, const u16* Wt, const float* bias, const float* res,
                     float* C, u16* Cb, int Mm, int Nn, int Kk, int batch,
                     long sA, long sW, long sC1, long sC2, int cdiv, int ldc,
                     float scale, int act) {
        dim3 grid(Nn / 128, Mm / 128, batch);
        if (act) gemm_bf16<128, 128, 1><<<grid, 256, 0, stream>>>(A, Wt, bias, res, C, Cb, Kk, sA, sW, sC1, sC2, cdiv, ldc, scale, 0);
        else     gemm_bf16<128, 128, 0><<<grid, 256, 0, stream>>>(A, Wt, bias, res, C, Cb, Kk, sA, sW, sC1, sC2, cdiv, ldc, scale, 0);
    };
    auto gemmB = [&](const u16* A, const u16* Wt, u16* Cb, int Mm, int Nn, int Kk, int tr) {
        dim3 grid(Nn / 64, Mm / 256, 1);
        gemm_bf16<256, 64, 0><<<grid, 256, 0, stream>>>(A, Wt, nullptr, nullptr, nullptr, Cb, Kk, 0, 0, 0, 0, 1, Nn, 1.0f, tr);
    };

    // 0. weight conversions + rope tables
    cvt_weights<<<dim3(2011136 / 256), 256, 0, stream>>>(conv_w, mlp_w1, mlp_w2, qkv_w,
                                                         proj_w, k_w, v_w, q_w,
                                                         gru_wih, gru_whh, smlp_w1, smlp_w2, wb);
    rope_tab<<<dim3(16384 / 256), 256, 0, stream>>>(CS, SN);

    // 1. sobel + onehot + im2col (bf16)
    sobel_im2col<<<dim3((BB * HH * WW) / 256), 256, 0, stream>>>(state, X0b);
    // 2. patch conv GEMM -> X1 fp32
    gemmA(X0b, conv_wb, conv_b, nullptr, X1, nullptr, M, EE, KIM, 1, 0, 0, 0, 0, 1, EE, 1.0f, 0);
    // 3. LN -> bf16, MLP
    ln_rows<u16><<<dim3(M * 64 / 256), 256, 0, stream>>>(X1, XLNb, mlp_ln_g, mlp_ln_b, M, EE);
    gemmA(XLNb, mlp_w1b, mlp_b1, nullptr, nullptr, Hbufb, M, 2 * EE, EE, 1, 0, 0, 0, 0, 1, 2 * EE, 1.0f, 1);
    gemmA(Hbufb, mlp_w2b, mlp_b2, nullptr, X2, X2b, M, EE, 2 * EE, 1, 0, 0, 0, 0, 1, EE, 1.0f, 0);
    // 4. QKV + table rope
    gemmA(X2b, qkv_wb, qkv_b, nullptr, nullptr, QKVb, M, 3 * EE, EE, 1, 0, 0, 0, 0, 1, 3 * EE, 1.0f, 0);
    rope_qk<<<dim3(65536 / 256), 256, 0, stream>>>(QKVb, CS, SN, Qr, Kr);
    // 5. fused attention
    fused_attn<<<dim3(NHEAD, BB), 256, 0, stream>>>(Qr, Kr, QKVb, AOb);
    // 6. proj + residual -> X3 fp32
    gemmA(AOb, proj_wb, proj_b, X2, X3, nullptr, M, EE, EE, 1, 0, 0, 0, 0, 1, EE, 1.0f, 0);
    // 7. LN ni -> bf16, k_in (bf16) / v_in (bf16 transposed)
    ln_rows<u16><<<dim3(M * 64 / 256), 256, 0, stream>>>(X3, Xnb, ni_g, ni_b, M, EE);
    gemmB(Xnb, k_wb, Kinb, M, FD, EE, 0);
    gemmB(Xnb, v_wb, Vtb, M, FD, EE, 1);
    // 8. fully fused slot-attention loop (writes slots + masks into out)
    fused_slots<<<dim3(BB), 256, 0, stream>>>(Kinb, Vtb, q_wb, wihb, whhb, smlp1b, smlp2b,
                                              ns_g, ns_b, nm_g, nm_b,
                                              gru_bih, gru_bhh, smlp_b1, smlp_b2, out);
}

// Round 8
// 627.032 us; speedup vs baseline: 1.8643x; 1.8643x over previous
//
#include <hip/hip_runtime.h>
#include <math.h>

// ---------------- problem constants ----------------
#define BB   64
#define HH   128
#define WW   128
#define GG   16
#define NN   256     // G*G tokens
#define EE   256
#define FD   320
#define NSL  8       // slots
#define NHEAD 4
#define HD   64
#define KIM  768     // 12*8*8 im2col K

using short8 = __attribute__((ext_vector_type(8))) short;
using f32x4  = __attribute__((ext_vector_type(4))) float;

__device__ __forceinline__ float sigm(float x) { return 1.0f / (1.0f + expf(-x)); }
__device__ __forceinline__ float gelu_exact(float x) {
    return 0.5f * x * (1.0f + erff(x * 0.70710678118654752f));
}
// round-to-nearest-even f32 -> bf16
__device__ __forceinline__ unsigned short f2b(float x) {
    unsigned u = __float_as_uint(x);
    u += 0x7fffu + ((u >> 16) & 1u);
    return (unsigned short)(u >> 16);
}
__device__ __forceinline__ float b2f(unsigned short u) {
    return __uint_as_float(((unsigned)u) << 16);
}
__device__ __forceinline__ void gload_lds16(const void* g, void* lds) {
    __builtin_amdgcn_global_load_lds(
        (const __attribute__((address_space(1))) unsigned int*)g,
        (__attribute__((address_space(3))) unsigned int*)lds, 16, 0, 0);
}
__device__ __forceinline__ void store_el(float* p, float v) { *p = v; }
__device__ __forceinline__ void store_el(unsigned short* p, float v) { *p = f2b(v); }

// ---------------- all weight conversions in one kernel ----------------
__global__ __launch_bounds__(256) void cvt_weights(
    const float* __restrict__ w0, const float* __restrict__ w1,
    const float* __restrict__ w2, const float* __restrict__ w3,
    const float* __restrict__ w4, const float* __restrict__ w5,
    const float* __restrict__ w6, const float* __restrict__ w7,
    const float* __restrict__ w8, const float* __restrict__ w9,
    const float* __restrict__ w10, const float* __restrict__ w11,
    unsigned short* __restrict__ dst) {
    int i = blockIdx.x * 256 + threadIdx.x;   // < 2011136
    float v;
    if      (i <  196608) v = w0[i];
    else if (i <  327680) v = w1[i - 196608];
    else if (i <  458752) v = w2[i - 327680];
    else if (i <  655360) v = w3[i - 458752];
    else if (i <  720896) v = w4[i - 655360];
    else if (i <  802816) v = w5[i - 720896];
    else if (i <  884736) v = w6[i - 802816];
    else if (i <  987136) v = w7[i - 884736];
    else if (i < 1294336) v = w8[i - 987136];
    else if (i < 1601536) v = w9[i - 1294336];
    else if (i < 1806336) v = w10[i - 1601536];
    else                  v = w11[i - 1806336];
    dst[i] = f2b(v);
}

// ---------------- RoPE tables: cs/sn[n][d], n<256, d<64 ----------------
__global__ __launch_bounds__(256) void rope_tab(float* __restrict__ cs,
                                                float* __restrict__ sn) {
    int i = blockIdx.x * 256 + threadIdx.x;   // 16384
    int d = i & 63, n = i >> 6;
    int pos = (d < 32) ? (n >> 4) : (n & 15);
    int j = d & 31;
    float freq = powf(10000.0f, -(float)(j & 15) / 16.0f);
    float p = (float)pos * freq;
    float ang = (j < 16) ? sinf(p) : cosf(p);
    cs[i] = cosf(ang);
    sn[i] = sinf(ang);
}

// ---------------- Sobel + one-hot + im2col (bf16 out, exact) ----------------
__global__ __launch_bounds__(256) void sobel_im2col(const float* __restrict__ state,
                                                    unsigned short* __restrict__ X0) {
    int idx = blockIdx.x * 256 + threadIdx.x;
    if (idx >= BB * HH * WW) return;
    int w = idx % WW;
    int h = (idx / WW) % HH;
    int b = idx / (HH * WW);
    const float* st = state + (long)b * HH * WW;
    auto at = [&](int y, int x) {
        y = min(max(y, 0), HH - 1);
        x = min(max(x, 0), WW - 1);
        return st[y * WW + x];
    };
    float v00 = at(h-1, w-1), v01 = at(h-1, w), v02 = at(h-1, w+1);
    float v10 = at(h,   w-1),                  v12 = at(h,   w+1);
    float v20 = at(h+1, w-1), v21 = at(h+1, w), v22 = at(h+1, w+1);
    float sx = (v02 - v00) + 2.0f * (v12 - v10) + (v22 - v20);
    float sy = (v20 - v00) + 2.0f * (v21 - v01) + (v22 - v02);
    int id = (int)st[h * WW + w];
    int gy = h >> 3, i = h & 7, gx = w >> 3, j = w & 7;
    long row = (long)b * NN + gy * GG + gx;
    unsigned short* xr = X0 + row * KIM + i * 8 + j;
#pragma unroll
    for (int c = 0; c < 10; c++) xr[c * 64] = (id == c) ? 0x3F80u : 0u;
    xr[10 * 64] = f2b(sx);
    xr[11 * 64] = f2b(sy);
}

// ---------------- bf16 MFMA NT GEMM (big path) ----------------
template <int BM, int BN, int ACT>
__global__ __launch_bounds__(256) void gemm_bf16(
    const unsigned short* __restrict__ A, const unsigned short* __restrict__ W,
    const float* __restrict__ bias, const float* __restrict__ res,
    float* __restrict__ C, unsigned short* __restrict__ Cb,
    int K, long sA, long sW, long sC1, long sC2, int cdiv, int ldc, float scale)
{
    constexpr int WN = BN / 64;
    __shared__ __align__(16) unsigned short As[BM * 32];
    __shared__ __align__(16) unsigned short Bs[BN * 32];
    const int tid = threadIdx.x;
    const int w = tid >> 6, l = tid & 63;
    const int wm = w / WN, wn = w % WN;
    const int bz = blockIdx.z;
    const unsigned short* Ab = A + (long)bz * sA + (long)(blockIdx.y * BM) * K;
    const unsigned short* Wb = W + (long)bz * sW + (long)(blockIdx.x * BN) * K;
    const long offC = (long)(bz / cdiv) * sC1 + (long)(bz % cdiv) * sC2;

    const int rA  = l >> 2;
    const int swz = ((l & 3) ^ ((l >> 3) & 3)) * 8;

    f32x4 acc[4][4] = {};

    for (int k0 = 0; k0 < K; k0 += 32) {
#pragma unroll
        for (int c = 0; c < BM / 64; c++) {
            const int chunk = w * (BM / 64) + c;
            gload_lds16(Ab + (long)(chunk * 16 + rA) * K + k0 + swz, (char*)As + chunk * 1024);
        }
#pragma unroll
        for (int c = 0; c < BN / 64; c++) {
            const int chunk = w * (BN / 64) + c;
            gload_lds16(Wb + (long)(chunk * 16 + rA) * K + k0 + swz, (char*)Bs + chunk * 1024);
        }
        __syncthreads();
        short8 af[4], bfr[4];
#pragma unroll
        for (int m = 0; m < 4; m++) {
            const int row = wm * 64 + m * 16 + (l & 15);
            const int byte = row * 64 + (((l >> 4) ^ ((row >> 1) & 3)) << 4);
            af[m] = *(const short8*)((const char*)As + byte);
        }
#pragma unroll
        for (int n = 0; n < 4; n++) {
            const int row = wn * 64 + n * 16 + (l & 15);
            const int byte = row * 64 + (((l >> 4) ^ ((row >> 1) & 3)) << 4);
            bfr[n] = *(const short8*)((const char*)Bs + byte);
        }
#pragma unroll
        for (int m = 0; m < 4; m++)
#pragma unroll
            for (int n = 0; n < 4; n++)
                acc[m][n] = __builtin_amdgcn_mfma_f32_16x16x32_bf16(af[m], bfr[n], acc[m][n], 0, 0, 0);
        __syncthreads();
    }

    const int crow0 = blockIdx.y * BM + wm * 64;
    const int ccol0 = blockIdx.x * BN + wn * 64;
#pragma unroll
    for (int m = 0; m < 4; m++) {
#pragma unroll
        for (int n = 0; n < 4; n++) {
            const int row = crow0 + m * 16 + ((l >> 4) << 2);
            const int col = ccol0 + n * 16 + (l & 15);
#pragma unroll
            for (int r = 0; r < 4; r++) {
                float v = acc[m][n][r] * scale;
                if (bias) v += bias[col];
                if (ACT == 1) v = gelu_exact(v);
                const long idx = offC + (long)(row + r) * ldc + col;
                if (res) v += res[idx];
                if (C)  C[idx] = v;
                if (Cb) Cb[idx] = f2b(v);
            }
        }
    }
}

// ---------------- small bf16 MFMA NT GEMM (slot loop): 64x64 tile ----------------
template <int ACT>
__global__ __launch_bounds__(256) void gemm_bf16_s(
    const unsigned short* __restrict__ A, const unsigned short* __restrict__ W,
    const float* __restrict__ bias0, const float* __restrict__ bias1,
    const float* __restrict__ res,
    float* __restrict__ C, unsigned short* __restrict__ Cb,
    int K, int N, long sA, long sW, long sC, float scale)
{
    __shared__ __align__(16) unsigned short As[64 * 32];
    __shared__ __align__(16) unsigned short Bs[64 * 32];
    const int tid = threadIdx.x;
    const int w = tid >> 6, l = tid & 63;
    const int gw = l >> 4, l15 = l & 15;
    const int bz = blockIdx.z;
    const unsigned short* Ab = A + (long)bz * sA + (long)(blockIdx.y * 64) * K;
    const unsigned short* Wb = W + (long)bz * sW + (long)(blockIdx.x * 64) * K;
    const float* bias = (bz == 0) ? bias0 : bias1;
    const long offC = (long)bz * sC;

    const int rA  = l >> 2;
    const int swz = ((l & 3) ^ ((l >> 3) & 3)) * 8;

    f32x4 acc[4] = {};

    for (int k0 = 0; k0 < K; k0 += 32) {
        gload_lds16(Ab + (long)(w * 16 + rA) * K + k0 + swz, (char*)As + w * 1024);
        gload_lds16(Wb + (long)(w * 16 + rA) * K + k0 + swz, (char*)Bs + w * 1024);
        __syncthreads();
        short8 af[4];
#pragma unroll
        for (int m = 0; m < 4; m++) {
            const int row = m * 16 + l15;
            af[m] = *(const short8*)((const char*)As + row * 64 + ((gw ^ ((row >> 1) & 3)) << 4));
        }
        const int brow = w * 16 + l15;
        const short8 bf = *(const short8*)((const char*)Bs + brow * 64 + ((gw ^ ((brow >> 1) & 3)) << 4));
#pragma unroll
        for (int m = 0; m < 4; m++)
            acc[m] = __builtin_amdgcn_mfma_f32_16x16x32_bf16(af[m], bf, acc[m], 0, 0, 0);
        __syncthreads();
    }

    const int col = blockIdx.x * 64 + w * 16 + l15;
    const int row0 = blockIdx.y * 64;
#pragma unroll
    for (int m = 0; m < 4; m++) {
        const int row = row0 + m * 16 + (gw << 2);
#pragma unroll
        for (int r = 0; r < 4; r++) {
            float v = acc[m][r] * scale;
            if (bias) v += bias[col];
            if (ACT == 1) v = gelu_exact(v);
            const long idx = offC + (long)(row + r) * N + col;
            if (res) v += res[idx];
            if (C)  C[idx] = v;
            if (Cb) Cb[idx] = f2b(v);
        }
    }
}

// ---------------- LayerNorm (wave per row) ----------------
template <typename OT>
__global__ __launch_bounds__(256) void ln_rows(const float* __restrict__ X,
                                               OT* __restrict__ Y,
                                               const float* __restrict__ g,
                                               const float* __restrict__ b,
                                               int rows, int D) {
    int gtid = blockIdx.x * 256 + threadIdx.x;
    int row = gtid >> 6;
    int lane = gtid & 63;
    if (row >= rows) return;
    const float* x = X + (long)row * D;
    const int nv = D >> 6;
    float v[5];
    float s = 0.0f;
#pragma unroll 5
    for (int i = 0; i < nv; i++) { v[i] = x[lane + (i << 6)]; s += v[i]; }
#pragma unroll
    for (int o = 32; o; o >>= 1) s += __shfl_down(s, o);
    s = __shfl(s, 0);
    float mean = s / (float)D;
    float s2 = 0.0f;
#pragma unroll 5
    for (int i = 0; i < nv; i++) { float d = v[i] - mean; s2 += d * d; }
#pragma unroll
    for (int o = 32; o; o >>= 1) s2 += __shfl_down(s2, o);
    s2 = __shfl(s2, 0);
    float inv = rsqrtf(s2 / (float)D + 1e-5f);
    OT* y = Y + (long)row * D;
#pragma unroll 5
    for (int i = 0; i < nv; i++) {
        int d = lane + (i << 6);
        store_el(&y[d], (v[i] - mean) * inv * g[d] + b[d]);
    }
}

// ---------------- fused GRU + LayerNorm(nm) (wave per row) ----------------
__global__ __launch_bounds__(256) void gru_ln(const float* __restrict__ GI,
                                              const float* __restrict__ GH,
                                              float* __restrict__ slots,
                                              const float* __restrict__ g,
                                              const float* __restrict__ b,
                                              unsigned short* __restrict__ SLnb) {
    int gtid = blockIdx.x * 256 + threadIdx.x;
    int row = gtid >> 6;        // < 512
    int lane = gtid & 63;
    const float* gi = GI + (long)row * 960;
    const float* gh = GH + (long)row * 960;
    float* sl = slots + (long)row * FD;
    float h[5];
    float s = 0.0f;
#pragma unroll
    for (int i = 0; i < 5; i++) {
        const int f = lane + (i << 6);
        const float rr = sigm(gi[f] + gh[f]);
        const float z  = sigm(gi[320 + f] + gh[320 + f]);
        const float nn = tanhf(gi[640 + f] + rr * gh[640 + f]);
        const float hn = (1.0f - z) * nn + z * sl[f];
        h[i] = hn;
        s += hn;
        sl[f] = hn;
    }
#pragma unroll
    for (int o = 32; o; o >>= 1) s += __shfl_down(s, o);
    s = __shfl(s, 0);
    const float mean = s * (1.0f / FD);
    float s2 = 0.0f;
#pragma unroll
    for (int i = 0; i < 5; i++) { const float d = h[i] - mean; s2 += d * d; }
#pragma unroll
    for (int o = 32; o; o >>= 1) s2 += __shfl_down(s2, o);
    s2 = __shfl(s2, 0);
    const float inv = rsqrtf(s2 * (1.0f / FD) + 1e-5f);
    unsigned short* y = SLnb + (long)row * FD;
#pragma unroll
    for (int i = 0; i < 5; i++) {
        const int f = lane + (i << 6);
        y[f] = f2b((h[i] - mean) * inv * g[f] + b[f]);
    }
}

// ---------------- table-driven RoPE: QKVb -> Qr, Kr (bf16) ----------------
__global__ __launch_bounds__(256) void rope_qk(const unsigned short* __restrict__ QKVb,
                                               const float* __restrict__ cs,
                                               const float* __restrict__ sn,
                                               unsigned short* __restrict__ Qr,
                                               unsigned short* __restrict__ Kr) {
    const int rid = blockIdx.x * 256 + threadIdx.x;   // b*1024 + h*256 + n
    const int n = rid & 255;
    const int h = (rid >> 8) & 3;
    const int b = rid >> 10;
    const unsigned short* src = QKVb + ((long)(b * 256 + n)) * 768 + h * 64;
    float cv[64], sv[64];
#pragma unroll
    for (int i = 0; i < 16; i++) {
        *(float4*)&cv[i * 4] = *(const float4*)(cs + n * 64 + i * 4);
        *(float4*)&sv[i * 4] = *(const float4*)(sn + n * 64 + i * 4);
    }
#pragma unroll
    for (int qk = 0; qk < 2; qk++) {
        const unsigned short* s0 = src + qk * 256;
        unsigned short* dst = (qk == 0 ? Qr : Kr) + (long)rid * 64;
        float x[64];
#pragma unroll
        for (int i = 0; i < 8; i++) {
            short8 v = *(const short8*)(s0 + i * 8);
#pragma unroll
            for (int j = 0; j < 8; j++) x[i * 8 + j] = b2f((unsigned short)v[j]);
        }
        unsigned short o[64];
#pragma unroll
        for (int d = 0; d < 64; d++) {
            const float rot = (d < 32) ? -x[2 * d + 1] : x[2 * (d - 32)];
            o[d] = f2b(x[d] * cv[d] + rot * sv[d]);
        }
#pragma unroll
        for (int i = 0; i < 8; i++)
            *(short8*)(dst + i * 8) = *(short8*)&o[i * 8];
    }
}

// ---------------- fused attention: one wg per (b,h) ----------------
__global__ __launch_bounds__(256, 1) void fused_attn(
    const unsigned short* __restrict__ Qr,
    const unsigned short* __restrict__ Kr,
    const unsigned short* __restrict__ QKVb,
    unsigned short* __restrict__ AOb)
{
    __shared__ __align__(16) char SL[49152];   // V^T 32KB + P 16KB
    const int h = blockIdx.x, b = blockIdx.y;
    const int tid = threadIdx.x;
    const int w = tid >> 6, l = tid & 63;
    const int gw = l >> 4, l15 = l & 15;
    const long bh = (long)b * 4 + h;
    const unsigned short* Qb = Qr + bh * NN * 64;
    const unsigned short* Kb = Kr + bh * NN * 64;

    {
        const int n0 = (tid & 127) * 2;
        const int dh = tid >> 7;
        const unsigned short* v0p = QKVb + ((long)b * NN + n0) * 768 + h * 64 + 512 + dh * 32;
        const unsigned short* v1p = v0p + 768;
        unsigned short v0[32], v1[32];
#pragma unroll
        for (int i = 0; i < 4; i++) {
            *(short8*)&v0[i * 8] = *(const short8*)(v0p + i * 8);
            *(short8*)&v1[i * 8] = *(const short8*)(v1p + i * 8);
        }
#pragma unroll
        for (int i = 0; i < 32; i++) {
            const int d = dh * 32 + i;
            const unsigned val = (unsigned)v0[i] | ((unsigned)v1[i] << 16);
            *(unsigned*)(SL + d * 512 + (((n0 >> 3) ^ (d & 15)) << 4) + (n0 & 7) * 2) = val;
        }
    }
    __syncthreads();

    char* Pw = SL + 32768 + w * 4096;

#pragma unroll
    for (int p = 0; p < 2; p++) {
        const int mbase = w * 64 + p * 32;
        f32x4 accs[16][2] = {};
#pragma unroll
        for (int kk = 0; kk < 2; kk++) {
            short8 bq[2];
#pragma unroll
            for (int mf = 0; mf < 2; mf++)
                bq[mf] = *(const short8*)(Qb + ((mbase + mf * 16 + l15) << 6) + kk * 32 + gw * 8);
#pragma unroll
            for (int nf = 0; nf < 16; nf++) {
                const short8 ak = *(const short8*)(Kb + ((nf * 16 + l15) << 6) + kk * 32 + gw * 8);
#pragma unroll
                for (int mf = 0; mf < 2; mf++)
                    accs[nf][mf] = __builtin_amdgcn_mfma_f32_16x16x32_bf16(ak, bq[mf], accs[nf][mf], 0, 0, 0);
            }
        }
        float rs[2];
#pragma unroll
        for (int mf = 0; mf < 2; mf++) {
            float mx = -1e30f;
#pragma unroll
            for (int nf = 0; nf < 16; nf++)
#pragma unroll
                for (int r = 0; r < 4; r++) mx = fmaxf(mx, accs[nf][mf][r]);
            mx = fmaxf(mx, __shfl_xor(mx, 16));
            mx = fmaxf(mx, __shfl_xor(mx, 32));
            float sum = 0.0f;
#pragma unroll
            for (int nf = 0; nf < 16; nf++)
#pragma unroll
                for (int r = 0; r < 4; r++) {
                    const float e = expf((accs[nf][mf][r] - mx) * 0.125f);
                    accs[nf][mf][r] = e;
                    sum += e;
                }
            sum += __shfl_xor(sum, 16);
            sum += __shfl_xor(sum, 32);
            rs[mf] = 1.0f / sum;
        }
        f32x4 acco[4][2] = {};
#pragma unroll
        for (int c = 0; c < 4; c++) {
#pragma unroll
            for (int nfi = 0; nfi < 4; nfi++) {
                const int nf = c * 4 + nfi;
                const int kt = nf >> 1;
                const int gr = (nf & 1) * 2 + (gw >> 1);
                const int lr = l15 + 16 * gr;
                const int j0 = (gw & 1) * 4;
#pragma unroll
                for (int mf = 0; mf < 2; mf++) {
                    uint2 pk;
                    pk.x = (unsigned)f2b(accs[nf][mf][0] * rs[mf]) |
                           ((unsigned)f2b(accs[nf][mf][1] * rs[mf]) << 16);
                    pk.y = (unsigned)f2b(accs[nf][mf][2] * rs[mf]) |
                           ((unsigned)f2b(accs[nf][mf][3] * rs[mf]) << 16);
                    *(uint2*)(Pw + ((kt & 1) * 2 + mf) * 1024 + lr * 16 + j0 * 2) = pk;
                }
            }
#pragma unroll
            for (int kti = 0; kti < 2; kti++) {
                const int kt = c * 2 + kti;
                short8 vf[4];
#pragma unroll
                for (int df = 0; df < 4; df++) {
                    const int d = df * 16 + l15;
                    vf[df] = *(const short8*)(SL + d * 512 + (((kt * 4 + gw) ^ (d & 15)) << 4));
                }
#pragma unroll
                for (int mf = 0; mf < 2; mf++) {
                    const short8 pf = *(const short8*)(Pw + (kti * 2 + mf) * 1024 + l * 16);
#pragma unroll
                    for (int df = 0; df < 4; df++)
                        acco[df][mf] = __builtin_amdgcn_mfma_f32_16x16x32_bf16(vf[df], pf, acco[df][mf], 0, 0, 0);
                }
            }
        }
#pragma unroll
        for (int df = 0; df < 4; df++)
#pragma unroll
            for (int mf = 0; mf < 2; mf++) {
                const int m = mbase + mf * 16 + l15;
                const int d = df * 16 + gw * 4;
                unsigned short o[4];
#pragma unroll
                for (int r = 0; r < 4; r++) o[r] = f2b(acco[df][mf][r]);
                *(uint2*)(AOb + ((long)(b * NN + m) * 256 + h * 64 + d)) = *(uint2*)o;
            }
    }
}

// ---------------- slot logits + softmax over slots ----------------
// grid (BB, 16); per-chunk sums written to sums2[b][chunk][s] (no global atomics).
// mout != nullptr on last iteration: writes masks [b][s][n].
__global__ __launch_bounds__(256) void slot_logits(const float* __restrict__ Kin,
                                                   const float* __restrict__ Qs,
                                                   float* __restrict__ sattn,
                                                   float* __restrict__ sums2,
                                                   float* __restrict__ mout) {
    const int b = blockIdx.x;
    const int chunk = blockIdx.y;
    __shared__ float qs[NSL][FD];
    __shared__ float colsum[NSL];
    const int tid = threadIdx.x;
    for (int i = tid; i < NSL * FD; i += 256) qs[i / FD][i % FD] = Qs[(long)b * NSL * FD + i];
    if (tid < NSL) colsum[tid] = 0.0f;
    __syncthreads();
    const int wv = tid >> 6, lane = tid & 63;
    float wsum[NSL] = {};
#pragma unroll
    for (int rr = 0; rr < 4; rr++) {
        const int r = chunk * 16 + wv * 4 + rr;
        const float* kr = Kin + ((long)b * NN + r) * FD;
        float acc[NSL] = {};
#pragma unroll
        for (int i = 0; i < 5; i++) {
            const int t = lane + (i << 6);
            const float kv = kr[t];
#pragma unroll
            for (int s = 0; s < NSL; s++) acc[s] = fmaf(kv, qs[s][t], acc[s]);
        }
#pragma unroll
        for (int s = 0; s < NSL; s++)
#pragma unroll
            for (int o = 32; o; o >>= 1) acc[s] += __shfl_down(acc[s], o);
        if (lane == 0) {
            const float scale = 0.055901699437494740f;  // 1/sqrt(320)
            float mx = -1e30f;
#pragma unroll
            for (int s = 0; s < NSL; s++) { acc[s] *= scale; mx = fmaxf(mx, acc[s]); }
            float e[NSL], sum = 0.0f;
#pragma unroll
            for (int s = 0; s < NSL; s++) { e[s] = expf(acc[s] - mx); sum += e[s]; }
            const float rsum = 1.0f / sum;
            float* outp = sattn + ((long)b * NN + r) * NSL;
#pragma unroll
            for (int s = 0; s < NSL; s++) {
                const float pp = e[s] * rsum;
                outp[s] = pp;
                wsum[s] += pp;
                if (mout) mout[(long)b * 2048 + s * 256 + r] = pp;
            }
        }
    }
    if (lane == 0) {
#pragma unroll
        for (int s = 0; s < NSL; s++) atomicAdd(&colsum[s], wsum[s]);
    }
    __syncthreads();
    if (tid < NSL) sums2[((long)(b << 4) + chunk) * NSL + tid] = colsum[tid];
}

// ---------------- slot updates: block per b, LDS reduce, bf16 out ----------------
__global__ __launch_bounds__(256) void slot_updates(const float* __restrict__ sattn,
                                                    const float* __restrict__ sums2,
                                                    const float* __restrict__ Vin,
                                                    unsigned short* __restrict__ Updb) {
    const int b = blockIdx.x;
    const int tid = threadIdx.x;
    const int w = tid >> 6, l = tid & 63;
    __shared__ float inv_s[NSL];
    __shared__ float an_s[NN][NSL];
    __shared__ float red[4][NSL][FD];
    if (tid < NSL) {
        float tot = (float)NN * 1e-8f;
#pragma unroll
        for (int c = 0; c < 16; c++) tot += sums2[((long)(b << 4) + c) * NSL + tid];
        inv_s[tid] = 1.0f / tot;
    }
    __syncthreads();
    {
        const float4 p0 = *(const float4*)(sattn + ((long)b * NN + tid) * NSL);
        const float4 p1 = *(const float4*)(sattn + ((long)b * NN + tid) * NSL + 4);
        an_s[tid][0] = (p0.x + 1e-8f) * inv_s[0];
        an_s[tid][1] = (p0.y + 1e-8f) * inv_s[1];
        an_s[tid][2] = (p0.z + 1e-8f) * inv_s[2];
        an_s[tid][3] = (p0.w + 1e-8f) * inv_s[3];
        an_s[tid][4] = (p1.x + 1e-8f) * inv_s[4];
        an_s[tid][5] = (p1.y + 1e-8f) * inv_s[5];
        an_s[tid][6] = (p1.z + 1e-8f) * inv_s[6];
        an_s[tid][7] = (p1.w + 1e-8f) * inv_s[7];
    }
    __syncthreads();
    float acc[NSL][5] = {};
    const float* vb = Vin + ((long)b * NN + w * 64) * FD;
    for (int i = 0; i < 64; i++) {
        float v[5];
#pragma unroll
        for (int j = 0; j < 5; j++) v[j] = vb[(long)i * FD + l + (j << 6)];
        float a[NSL];
#pragma unroll
        for (int s = 0; s < NSL; s++) a[s] = an_s[w * 64 + i][s];
#pragma unroll
        for (int s = 0; s < NSL; s++)
#pragma unroll
            for (int j = 0; j < 5; j++)
                acc[s][j] = fmaf(a[s], v[j], acc[s][j]);
    }
#pragma unroll
    for (int s = 0; s < NSL; s++)
#pragma unroll
        for (int j = 0; j < 5; j++)
            red[w][s][l + (j << 6)] = acc[s][j];
    __syncthreads();
    for (int idx = tid; idx < NSL * FD; idx += 256) {
        const int s = idx / FD, f = idx % FD;
        const float tot = red[0][s][f] + red[1][s][f] + red[2][s][f] + red[3][s][f];
        Updb[((long)b * NSL + s) * FD + f] = f2b(tot);
    }
}

// ---------------- host launcher ----------------
extern "C" void kernel_launch(void* const* d_in, const int* in_sizes, int n_in,
                              void* d_out, int out_size, void* d_ws, size_t ws_size,
                              hipStream_t stream) {
    const float* state    = (const float*)d_in[0];
    const float* conv_w   = (const float*)d_in[1];
    const float* conv_b   = (const float*)d_in[2];
    const float* mlp_ln_g = (const float*)d_in[3];
    const float* mlp_ln_b = (const float*)d_in[4];
    const float* mlp_w1   = (const float*)d_in[5];
    const float* mlp_b1   = (const float*)d_in[6];
    const float* mlp_w2   = (const float*)d_in[7];
    const float* mlp_b2   = (const float*)d_in[8];
    const float* qkv_w    = (const float*)d_in[9];
    const float* qkv_b    = (const float*)d_in[10];
    const float* proj_w   = (const float*)d_in[11];
    const float* proj_b   = (const float*)d_in[12];
    const float* ni_g     = (const float*)d_in[13];
    const float* ni_b     = (const float*)d_in[14];
    const float* ns_g     = (const float*)d_in[15];
    const float* ns_b     = (const float*)d_in[16];
    const float* nm_g     = (const float*)d_in[17];
    const float* nm_b     = (const float*)d_in[18];
    const float* q_w      = (const float*)d_in[19];
    const float* k_w      = (const float*)d_in[20];
    const float* v_w      = (const float*)d_in[21];
    const float* gru_wih  = (const float*)d_in[22];
    const float* gru_whh  = (const float*)d_in[23];
    const float* gru_bih  = (const float*)d_in[24];
    const float* gru_bhh  = (const float*)d_in[25];
    const float* smlp_w1  = (const float*)d_in[26];
    const float* smlp_b1  = (const float*)d_in[27];
    const float* smlp_w2  = (const float*)d_in[28];
    const float* smlp_b2  = (const float*)d_in[29];

    float* ws = (float*)d_ws;
    const int M = BB * NN;  // 16384
    typedef unsigned short u16;

    // ---- workspace layout (float offsets) ----
    u16*   X0b  = (u16*)(ws + 0L);
    u16*   Qr   = (u16*)(ws + 0L);
    u16*   Kr   = (u16*)(ws + 2097152L);
    float* X1   = ws + 6291456L;
    u16*   XLNb = (u16*)(ws + 10485760L);
    u16*   Hbufb= (u16*)(ws + 12582912L);
    u16*   QKVb = (u16*)(ws + 6291456L);
    u16*   X2b  = (u16*)(ws + 23068672L);
    float* X2   = ws + 31457280L;
    u16*   Xnb  = (u16*)(ws + 31457280L);
    float* X3   = ws + 35651584L;
    float* Slots= ws + 35651584L;     // 163840
    float* Qs   = ws + 35979264L;     // 163840
    float* Satt = ws + 36143104L;     // 131072
    float* Sums2= ws + 36274176L;     // 8192 (b x 16 x 8)
    float* GI   = ws + 36438528L;     // 491520
    float* GH   = ws + 36930048L;     // 491520
    u16*   SLnb = (u16*)(ws + 37421568L);  // 163840 u16
    u16*   Updb = (u16*)(ws + 37503488L);  // 163840 u16
    u16*   Slotsb=(u16*)(ws + 37585408L);  // 163840 u16 (contig after Updb)
    u16*   Mhb  = (u16*)(ws + 37667328L);  // 327680 u16
    float* Kin  = ws + 39845888L;
    float* Vin  = ws + 45088768L;
    u16*   AOb    = (u16*)(ws + 50331648L);
    u16*   wb     = (u16*)(ws + 52428800L);   // 2011136 u16 contiguous
    u16*   conv_wb= wb + 0;
    u16*   mlp_w1b= wb + 196608;
    u16*   mlp_w2b= wb + 327680;
    u16*   qkv_wb = wb + 458752;
    u16*   proj_wb= wb + 655360;
    u16*   k_wb   = wb + 720896;
    u16*   v_wb   = wb + 802816;
    u16*   q_wb   = wb + 884736;
    u16*   wihb   = wb + 987136;
    u16*   whhb   = wb + 1294336;
    u16*   smlp1b = wb + 1601536;
    u16*   smlp2b = wb + 1806336;
    float* CS     = ws + 53434368L;
    float* SN     = ws + 53450752L;

    float* out = (float*)d_out;

    auto gemmA = [&](const u16* A, const u16* Wt, const float* bias, const float* res,
                     float* C, u16* Cb, int Mm, int Nn, int Kk, int batch,
                     long sA, long sW, long sC1, long sC2, int cdiv, int ldc,
                     float scale, int act) {
        dim3 grid(Nn / 128, Mm / 128, batch);
        if (act) gemm_bf16<128, 128, 1><<<grid, 256, 0, stream>>>(A, Wt, bias, res, C, Cb, Kk, sA, sW, sC1, sC2, cdiv, ldc, scale);
        else     gemm_bf16<128, 128, 0><<<grid, 256, 0, stream>>>(A, Wt, bias, res, C, Cb, Kk, sA, sW, sC1, sC2, cdiv, ldc, scale);
    };
    auto gemmB = [&](const u16* A, const u16* Wt, float* C, int Mm, int Nn, int Kk) {
        dim3 grid(Nn / 64, Mm / 256, 1);
        gemm_bf16<256, 64, 0><<<grid, 256, 0, stream>>>(A, Wt, nullptr, nullptr, C, nullptr, Kk, 0, 0, 0, 0, 1, Nn, 1.0f);
    };
    auto gemmS = [&](const u16* A, const u16* Wt, const float* b0, const float* b1,
                     const float* res, float* C, u16* Cb, int Mm, int Nn, int Kk,
                     int batch, long sA, long sW, long sC, int act) {
        dim3 grid(Nn / 64, Mm / 64, batch);
        if (act) gemm_bf16_s<1><<<grid, 256, 0, stream>>>(A, Wt, b0, b1, res, C, Cb, Kk, Nn, sA, sW, sC, 1.0f);
        else     gemm_bf16_s<0><<<grid, 256, 0, stream>>>(A, Wt, b0, b1, res, C, Cb, Kk, Nn, sA, sW, sC, 1.0f);
    };

    // 0. weight conversions + rope tables
    cvt_weights<<<dim3(2011136 / 256), 256, 0, stream>>>(conv_w, mlp_w1, mlp_w2, qkv_w,
                                                         proj_w, k_w, v_w, q_w,
                                                         gru_wih, gru_whh, smlp_w1, smlp_w2, wb);
    rope_tab<<<dim3(16384 / 256), 256, 0, stream>>>(CS, SN);

    // 1. sobel + onehot + im2col (bf16)
    sobel_im2col<<<dim3((BB * HH * WW) / 256), 256, 0, stream>>>(state, X0b);
    // 2. patch conv GEMM -> X1 fp32
    gemmA(X0b, conv_wb, conv_b, nullptr, X1, nullptr, M, EE, KIM, 1, 0, 0, 0, 0, 1, EE, 1.0f, 0);
    // 3. LN -> bf16, MLP
    ln_rows<u16><<<dim3(M * 64 / 256), 256, 0, stream>>>(X1, XLNb, mlp_ln_g, mlp_ln_b, M, EE);
    gemmA(XLNb, mlp_w1b, mlp_b1, nullptr, nullptr, Hbufb, M, 2 * EE, EE, 1, 0, 0, 0, 0, 1, 2 * EE, 1.0f, 1);
    gemmA(Hbufb, mlp_w2b, mlp_b2, nullptr, X2, X2b, M, EE, 2 * EE, 1, 0, 0, 0, 0, 1, EE, 1.0f, 0);
    // 4. QKV + table rope
    gemmA(X2b, qkv_wb, qkv_b, nullptr, nullptr, QKVb, M, 3 * EE, EE, 1, 0, 0, 0, 0, 1, 3 * EE, 1.0f, 0);
    rope_qk<<<dim3(65536 / 256), 256, 0, stream>>>(QKVb, CS, SN, Qr, Kr);
    // 5. fused attention
    fused_attn<<<dim3(NHEAD, BB), 256, 0, stream>>>(Qr, Kr, QKVb, AOb);
    // 6. proj + residual -> X3 fp32
    gemmA(AOb, proj_wb, proj_b, X2, X3, nullptr, M, EE, EE, 1, 0, 0, 0, 0, 1, EE, 1.0f, 0);
    // 7. LN ni -> bf16, k_in / v_in (fp32)
    ln_rows<u16><<<dim3(M * 64 / 256), 256, 0, stream>>>(X3, Xnb, ni_g, ni_b, M, EE);
    gemmB(Xnb, k_wb, Kin, M, FD, EE);
    gemmB(Xnb, v_wb, Vin, M, FD, EE);
    // 8. slot attention loop (bf16 MFMA GEMMs, reduced launch count)
    hipMemsetAsync(Slots, 0, (size_t)BB * NSL * FD * sizeof(float), stream);
    hipMemsetAsync(Slotsb, 0, (size_t)BB * NSL * FD * sizeof(u16), stream);
    for (int it = 0; it < 3; it++) {
        ln_rows<u16><<<dim3(512 * 64 / 256), 256, 0, stream>>>(Slots, SLnb, ns_g, ns_b, 512, FD);
        gemmS(SLnb, q_wb, nullptr, nullptr, nullptr, Qs, nullptr, 512, FD, FD, 1, 0, 0, 0, 0);
        slot_logits<<<dim3(BB, 16), 256, 0, stream>>>(Kin, Qs, Satt, Sums2,
                                                      (it == 2) ? (out + 163840) : nullptr);
        slot_updates<<<dim3(BB), 256, 0, stream>>>(Satt, Sums2, Vin, Updb);
        // GI = Updb@wih + bih ; GH = Slotsb@whh + bhh  (one launch, z=2)
        gemmS(Updb, wihb, gru_bih, gru_bhh, nullptr, GI, nullptr, 512, 960, FD,
              2, 163840, 307200, 491520, 0);
        gru_ln<<<dim3(512 * 64 / 256), 256, 0, stream>>>(GI, GH, Slots, nm_g, nm_b, SLnb);
        gemmS(SLnb, smlp1b, smlp_b1, nullptr, nullptr, nullptr, Mhb, 512, 2 * FD, FD, 1, 0, 0, 0, 1);
        if (it < 2)
            gemmS(Mhb, smlp2b, smlp_b2, nullptr, Slots, Slots, Slotsb, 512, FD, 2 * FD, 1, 0, 0, 0, 0);
        else
            gemmS(Mhb, smlp2b, smlp_b2, nullptr, Slots, out, nullptr, 512, FD, 2 * FD, 1, 0, 0, 0, 0);
    }
}

// Round 9
// 618.133 us; speedup vs baseline: 1.8911x; 1.0144x over previous
//
#include <hip/hip_runtime.h>
#include <math.h>

// ---------------- problem constants ----------------
#define BB   64
#define HH   128
#define WW   128
#define GG   16
#define NN   256     // G*G tokens
#define EE   256
#define FD   320
#define NSL  8       // slots
#define NHEAD 4
#define HD   64
#define KIM  768     // 12*8*8 im2col K

using short8 = __attribute__((ext_vector_type(8))) short;
using f32x4  = __attribute__((ext_vector_type(4))) float;

__device__ __forceinline__ float sigm(float x) { return 1.0f / (1.0f + expf(-x)); }
__device__ __forceinline__ float gelu_exact(float x) {
    return 0.5f * x * (1.0f + erff(x * 0.70710678118654752f));
}
// round-to-nearest-even f32 -> bf16
__device__ __forceinline__ unsigned short f2b(float x) {
    unsigned u = __float_as_uint(x);
    u += 0x7fffu + ((u >> 16) & 1u);
    return (unsigned short)(u >> 16);
}
__device__ __forceinline__ float b2f(unsigned short u) {
    return __uint_as_float(((unsigned)u) << 16);
}
__device__ __forceinline__ void gload_lds16(const void* g, void* lds) {
    __builtin_amdgcn_global_load_lds(
        (const __attribute__((address_space(1))) unsigned int*)g,
        (__attribute__((address_space(3))) unsigned int*)lds, 16, 0, 0);
}
__device__ __forceinline__ void store_el(float* p, float v) { *p = v; }
__device__ __forceinline__ void store_el(unsigned short* p, float v) { *p = f2b(v); }

// ---------------- all weight conversions in one kernel ----------------
__global__ __launch_bounds__(256) void cvt_weights(
    const float* __restrict__ w0, const float* __restrict__ w1,
    const float* __restrict__ w2, const float* __restrict__ w3,
    const float* __restrict__ w4, const float* __restrict__ w5,
    const float* __restrict__ w6, const float* __restrict__ w7,
    const float* __restrict__ w8, const float* __restrict__ w9,
    const float* __restrict__ w10, const float* __restrict__ w11,
    unsigned short* __restrict__ dst) {
    int i = blockIdx.x * 256 + threadIdx.x;   // < 2011136
    float v;
    if      (i <  196608) v = w0[i];
    else if (i <  327680) v = w1[i - 196608];
    else if (i <  458752) v = w2[i - 327680];
    else if (i <  655360) v = w3[i - 458752];
    else if (i <  720896) v = w4[i - 655360];
    else if (i <  802816) v = w5[i - 720896];
    else if (i <  884736) v = w6[i - 802816];
    else if (i <  987136) v = w7[i - 884736];
    else if (i < 1294336) v = w8[i - 987136];
    else if (i < 1601536) v = w9[i - 1294336];
    else if (i < 1806336) v = w10[i - 1601536];
    else                  v = w11[i - 1806336];
    dst[i] = f2b(v);
}

// ---------------- RoPE tables: cs/sn[n][d], n<256, d<64 ----------------
__global__ __launch_bounds__(256) void rope_tab(float* __restrict__ cs,
                                                float* __restrict__ sn) {
    int i = blockIdx.x * 256 + threadIdx.x;   // 16384
    int d = i & 63, n = i >> 6;
    int pos = (d < 32) ? (n >> 4) : (n & 15);
    int j = d & 31;
    float freq = powf(10000.0f, -(float)(j & 15) / 16.0f);
    float p = (float)pos * freq;
    float ang = (j < 16) ? sinf(p) : cosf(p);
    cs[i] = cosf(ang);
    sn[i] = sinf(ang);
}

// ---------------- Sobel + one-hot + im2col (bf16 out, exact) ----------------
__global__ __launch_bounds__(256) void sobel_im2col(const float* __restrict__ state,
                                                    unsigned short* __restrict__ X0) {
    int idx = blockIdx.x * 256 + threadIdx.x;
    if (idx >= BB * HH * WW) return;
    int w = idx % WW;
    int h = (idx / WW) % HH;
    int b = idx / (HH * WW);
    const float* st = state + (long)b * HH * WW;
    auto at = [&](int y, int x) {
        y = min(max(y, 0), HH - 1);
        x = min(max(x, 0), WW - 1);
        return st[y * WW + x];
    };
    float v00 = at(h-1, w-1), v01 = at(h-1, w), v02 = at(h-1, w+1);
    float v10 = at(h,   w-1),                  v12 = at(h,   w+1);
    float v20 = at(h+1, w-1), v21 = at(h+1, w), v22 = at(h+1, w+1);
    float sx = (v02 - v00) + 2.0f * (v12 - v10) + (v22 - v20);
    float sy = (v20 - v00) + 2.0f * (v21 - v01) + (v22 - v02);
    int id = (int)st[h * WW + w];
    int gy = h >> 3, i = h & 7, gx = w >> 3, j = w & 7;
    long row = (long)b * NN + gy * GG + gx;
    unsigned short* xr = X0 + row * KIM + i * 8 + j;
#pragma unroll
    for (int c = 0; c < 10; c++) xr[c * 64] = (id == c) ? 0x3F80u : 0u;
    xr[10 * 64] = f2b(sx);
    xr[11 * 64] = f2b(sy);
}

// ---------------- bf16 MFMA NT GEMM (big path) ----------------
template <int BM, int BN, int ACT>
__global__ __launch_bounds__(256) void gemm_bf16(
    const unsigned short* __restrict__ A, const unsigned short* __restrict__ W,
    const float* __restrict__ bias, const float* __restrict__ res,
    float* __restrict__ C, unsigned short* __restrict__ Cb,
    int K, long sA, long sW, long sC1, long sC2, int cdiv, int ldc, float scale)
{
    constexpr int WN = BN / 64;
    __shared__ __align__(16) unsigned short As[BM * 32];
    __shared__ __align__(16) unsigned short Bs[BN * 32];
    const int tid = threadIdx.x;
    const int w = tid >> 6, l = tid & 63;
    const int wm = w / WN, wn = w % WN;
    const int bz = blockIdx.z;
    const unsigned short* Ab = A + (long)bz * sA + (long)(blockIdx.y * BM) * K;
    const unsigned short* Wb = W + (long)bz * sW + (long)(blockIdx.x * BN) * K;
    const long offC = (long)(bz / cdiv) * sC1 + (long)(bz % cdiv) * sC2;

    const int rA  = l >> 2;
    const int swz = ((l & 3) ^ ((l >> 3) & 3)) * 8;

    f32x4 acc[4][4] = {};

    for (int k0 = 0; k0 < K; k0 += 32) {
#pragma unroll
        for (int c = 0; c < BM / 64; c++) {
            const int chunk = w * (BM / 64) + c;
            gload_lds16(Ab + (long)(chunk * 16 + rA) * K + k0 + swz, (char*)As + chunk * 1024);
        }
#pragma unroll
        for (int c = 0; c < BN / 64; c++) {
            const int chunk = w * (BN / 64) + c;
            gload_lds16(Wb + (long)(chunk * 16 + rA) * K + k0 + swz, (char*)Bs + chunk * 1024);
        }
        __syncthreads();
        short8 af[4], bfr[4];
#pragma unroll
        for (int m = 0; m < 4; m++) {
            const int row = wm * 64 + m * 16 + (l & 15);
            const int byte = row * 64 + (((l >> 4) ^ ((row >> 1) & 3)) << 4);
            af[m] = *(const short8*)((const char*)As + byte);
        }
#pragma unroll
        for (int n = 0; n < 4; n++) {
            const int row = wn * 64 + n * 16 + (l & 15);
            const int byte = row * 64 + (((l >> 4) ^ ((row >> 1) & 3)) << 4);
            bfr[n] = *(const short8*)((const char*)Bs + byte);
        }
#pragma unroll
        for (int m = 0; m < 4; m++)
#pragma unroll
            for (int n = 0; n < 4; n++)
                acc[m][n] = __builtin_amdgcn_mfma_f32_16x16x32_bf16(af[m], bfr[n], acc[m][n], 0, 0, 0);
        __syncthreads();
    }

    const int crow0 = blockIdx.y * BM + wm * 64;
    const int ccol0 = blockIdx.x * BN + wn * 64;
#pragma unroll
    for (int m = 0; m < 4; m++) {
#pragma unroll
        for (int n = 0; n < 4; n++) {
            const int row = crow0 + m * 16 + ((l >> 4) << 2);
            const int col = ccol0 + n * 16 + (l & 15);
#pragma unroll
            for (int r = 0; r < 4; r++) {
                float v = acc[m][n][r] * scale;
                if (bias) v += bias[col];
                if (ACT == 1) v = gelu_exact(v);
                const long idx = offC + (long)(row + r) * ldc + col;
                if (res) v += res[idx];
                if (C)  C[idx] = v;
                if (Cb) Cb[idx] = f2b(v);
            }
        }
    }
}

// ---------------- small bf16 MFMA NT GEMM (slot loop): 64x64 tile ----------------
template <int ACT>
__global__ __launch_bounds__(256) void gemm_bf16_s(
    const unsigned short* __restrict__ A, const unsigned short* __restrict__ W,
    const float* __restrict__ bias0, const float* __restrict__ bias1,
    const float* __restrict__ res,
    float* __restrict__ C, unsigned short* __restrict__ Cb,
    int K, int N, long sA, long sW, long sC, float scale)
{
    __shared__ __align__(16) unsigned short As[64 * 32];
    __shared__ __align__(16) unsigned short Bs[64 * 32];
    const int tid = threadIdx.x;
    const int w = tid >> 6, l = tid & 63;
    const int gw = l >> 4, l15 = l & 15;
    const int bz = blockIdx.z;
    const unsigned short* Ab = A + (long)bz * sA + (long)(blockIdx.y * 64) * K;
    const unsigned short* Wb = W + (long)bz * sW + (long)(blockIdx.x * 64) * K;
    const float* bias = (bz == 0) ? bias0 : bias1;
    const long offC = (long)bz * sC;

    const int rA  = l >> 2;
    const int swz = ((l & 3) ^ ((l >> 3) & 3)) * 8;

    f32x4 acc[4] = {};

    for (int k0 = 0; k0 < K; k0 += 32) {
        gload_lds16(Ab + (long)(w * 16 + rA) * K + k0 + swz, (char*)As + w * 1024);
        gload_lds16(Wb + (long)(w * 16 + rA) * K + k0 + swz, (char*)Bs + w * 1024);
        __syncthreads();
        short8 af[4];
#pragma unroll
        for (int m = 0; m < 4; m++) {
            const int row = m * 16 + l15;
            af[m] = *(const short8*)((const char*)As + row * 64 + ((gw ^ ((row >> 1) & 3)) << 4));
        }
        const int brow = w * 16 + l15;
        const short8 bf = *(const short8*)((const char*)Bs + brow * 64 + ((gw ^ ((brow >> 1) & 3)) << 4));
#pragma unroll
        for (int m = 0; m < 4; m++)
            acc[m] = __builtin_amdgcn_mfma_f32_16x16x32_bf16(af[m], bf, acc[m], 0, 0, 0);
        __syncthreads();
    }

    const int col = blockIdx.x * 64 + w * 16 + l15;
    const int row0 = blockIdx.y * 64;
#pragma unroll
    for (int m = 0; m < 4; m++) {
        const int row = row0 + m * 16 + (gw << 2);
#pragma unroll
        for (int r = 0; r < 4; r++) {
            float v = acc[m][r] * scale;
            if (bias) v += bias[col];
            if (ACT == 1) v = gelu_exact(v);
            const long idx = offC + (long)(row + r) * N + col;
            if (res) v += res[idx];
            if (C)  C[idx] = v;
            if (Cb) Cb[idx] = f2b(v);
        }
    }
}

// ---------------- LayerNorm (wave per row) ----------------
template <typename OT>
__global__ __launch_bounds__(256) void ln_rows(const float* __restrict__ X,
                                               OT* __restrict__ Y,
                                               const float* __restrict__ g,
                                               const float* __restrict__ b,
                                               int rows, int D) {
    int gtid = blockIdx.x * 256 + threadIdx.x;
    int row = gtid >> 6;
    int lane = gtid & 63;
    if (row >= rows) return;
    const float* x = X + (long)row * D;
    const int nv = D >> 6;
    float v[5];
    float s = 0.0f;
#pragma unroll 5
    for (int i = 0; i < nv; i++) { v[i] = x[lane + (i << 6)]; s += v[i]; }
#pragma unroll
    for (int o = 32; o; o >>= 1) s += __shfl_down(s, o);
    s = __shfl(s, 0);
    float mean = s / (float)D;
    float s2 = 0.0f;
#pragma unroll 5
    for (int i = 0; i < nv; i++) { float d = v[i] - mean; s2 += d * d; }
#pragma unroll
    for (int o = 32; o; o >>= 1) s2 += __shfl_down(s2, o);
    s2 = __shfl(s2, 0);
    float inv = rsqrtf(s2 / (float)D + 1e-5f);
    OT* y = Y + (long)row * D;
#pragma unroll 5
    for (int i = 0; i < nv; i++) {
        int d = lane + (i << 6);
        store_el(&y[d], (v[i] - mean) * inv * g[d] + b[d]);
    }
}

// ---------------- fused GRU + LayerNorm(nm) (wave per row) ----------------
__global__ __launch_bounds__(256) void gru_ln(const float* __restrict__ GI,
                                              const float* __restrict__ GH,
                                              float* __restrict__ slots,
                                              const float* __restrict__ g,
                                              const float* __restrict__ b,
                                              unsigned short* __restrict__ SLnb) {
    int gtid = blockIdx.x * 256 + threadIdx.x;
    int row = gtid >> 6;        // < 512
    int lane = gtid & 63;
    const float* gi = GI + (long)row * 960;
    const float* gh = GH + (long)row * 960;
    float* sl = slots + (long)row * FD;
    float h[5];
    float s = 0.0f;
#pragma unroll
    for (int i = 0; i < 5; i++) {
        const int f = lane + (i << 6);
        const float rr = sigm(gi[f] + gh[f]);
        const float z  = sigm(gi[320 + f] + gh[320 + f]);
        const float nn = tanhf(gi[640 + f] + rr * gh[640 + f]);
        const float hn = (1.0f - z) * nn + z * sl[f];
        h[i] = hn;
        s += hn;
        sl[f] = hn;
    }
#pragma unroll
    for (int o = 32; o; o >>= 1) s += __shfl_down(s, o);
    s = __shfl(s, 0);
    const float mean = s * (1.0f / FD);
    float s2 = 0.0f;
#pragma unroll
    for (int i = 0; i < 5; i++) { const float d = h[i] - mean; s2 += d * d; }
#pragma unroll
    for (int o = 32; o; o >>= 1) s2 += __shfl_down(s2, o);
    s2 = __shfl(s2, 0);
    const float inv = rsqrtf(s2 * (1.0f / FD) + 1e-5f);
    unsigned short* y = SLnb + (long)row * FD;
#pragma unroll
    for (int i = 0; i < 5; i++) {
        const int f = lane + (i << 6);
        y[f] = f2b((h[i] - mean) * inv * g[f] + b[f]);
    }
}

// ---------------- table-driven RoPE: QKVb -> Qr, Kr (bf16) ----------------
__global__ __launch_bounds__(256) void rope_qk(const unsigned short* __restrict__ QKVb,
                                               const float* __restrict__ cs,
                                               const float* __restrict__ sn,
                                               unsigned short* __restrict__ Qr,
                                               unsigned short* __restrict__ Kr) {
    const int rid = blockIdx.x * 256 + threadIdx.x;   // b*1024 + h*256 + n
    const int n = rid & 255;
    const int h = (rid >> 8) & 3;
    const int b = rid >> 10;
    const unsigned short* src = QKVb + ((long)(b * 256 + n)) * 768 + h * 64;
    float cv[64], sv[64];
#pragma unroll
    for (int i = 0; i < 16; i++) {
        *(float4*)&cv[i * 4] = *(const float4*)(cs + n * 64 + i * 4);
        *(float4*)&sv[i * 4] = *(const float4*)(sn + n * 64 + i * 4);
    }
#pragma unroll
    for (int qk = 0; qk < 2; qk++) {
        const unsigned short* s0 = src + qk * 256;
        unsigned short* dst = (qk == 0 ? Qr : Kr) + (long)rid * 64;
        float x[64];
#pragma unroll
        for (int i = 0; i < 8; i++) {
            short8 v = *(const short8*)(s0 + i * 8);
#pragma unroll
            for (int j = 0; j < 8; j++) x[i * 8 + j] = b2f((unsigned short)v[j]);
        }
        unsigned short o[64];
#pragma unroll
        for (int d = 0; d < 64; d++) {
            const float rot = (d < 32) ? -x[2 * d + 1] : x[2 * (d - 32)];
            o[d] = f2b(x[d] * cv[d] + rot * sv[d]);
        }
#pragma unroll
        for (int i = 0; i < 8; i++)
            *(short8*)(dst + i * 8) = *(short8*)&o[i * 8];
    }
}

// ---------------- fused attention: one wg per (b,h,p) ----------------
__global__ __launch_bounds__(256, 1) void fused_attn(
    const unsigned short* __restrict__ Qr,
    const unsigned short* __restrict__ Kr,
    const unsigned short* __restrict__ QKVb,
    unsigned short* __restrict__ AOb)
{
    __shared__ __align__(16) char SL[49152];   // V^T 32KB + P 16KB
    const int h = blockIdx.x, b = blockIdx.y;
    const int p = blockIdx.z;
    const int tid = threadIdx.x;
    const int w = tid >> 6, l = tid & 63;
    const int gw = l >> 4, l15 = l & 15;
    const long bh = (long)b * 4 + h;
    const unsigned short* Qb = Qr + bh * NN * 64;
    const unsigned short* Kb = Kr + bh * NN * 64;

    {
        const int n0 = (tid & 127) * 2;
        const int dh = tid >> 7;
        const unsigned short* v0p = QKVb + ((long)b * NN + n0) * 768 + h * 64 + 512 + dh * 32;
        const unsigned short* v1p = v0p + 768;
        unsigned short v0[32], v1[32];
#pragma unroll
        for (int i = 0; i < 4; i++) {
            *(short8*)&v0[i * 8] = *(const short8*)(v0p + i * 8);
            *(short8*)&v1[i * 8] = *(const short8*)(v1p + i * 8);
        }
#pragma unroll
        for (int i = 0; i < 32; i++) {
            const int d = dh * 32 + i;
            const unsigned val = (unsigned)v0[i] | ((unsigned)v1[i] << 16);
            *(unsigned*)(SL + d * 512 + (((n0 >> 3) ^ (d & 15)) << 4) + (n0 & 7) * 2) = val;
        }
    }
    __syncthreads();

    char* Pw = SL + 32768 + w * 4096;

    {
        const int mbase = w * 64 + p * 32;
        f32x4 accs[16][2] = {};
#pragma unroll
        for (int kk = 0; kk < 2; kk++) {
            short8 bq[2];
#pragma unroll
            for (int mf = 0; mf < 2; mf++)
                bq[mf] = *(const short8*)(Qb + ((mbase + mf * 16 + l15) << 6) + kk * 32 + gw * 8);
#pragma unroll
            for (int nf = 0; nf < 16; nf++) {
                const short8 ak = *(const short8*)(Kb + ((nf * 16 + l15) << 6) + kk * 32 + gw * 8);
#pragma unroll
                for (int mf = 0; mf < 2; mf++)
                    accs[nf][mf] = __builtin_amdgcn_mfma_f32_16x16x32_bf16(ak, bq[mf], accs[nf][mf], 0, 0, 0);
            }
        }
        float rs[2];
#pragma unroll
        for (int mf = 0; mf < 2; mf++) {
            float mx = -1e30f;
#pragma unroll
            for (int nf = 0; nf < 16; nf++)
#pragma unroll
                for (int r = 0; r < 4; r++) mx = fmaxf(mx, accs[nf][mf][r]);
            mx = fmaxf(mx, __shfl_xor(mx, 16));
            mx = fmaxf(mx, __shfl_xor(mx, 32));
            float sum = 0.0f;
#pragma unroll
            for (int nf = 0; nf < 16; nf++)
#pragma unroll
                for (int r = 0; r < 4; r++) {
                    const float e = expf((accs[nf][mf][r] - mx) * 0.125f);
                    accs[nf][mf][r] = e;
                    sum += e;
                }
            sum += __shfl_xor(sum, 16);
            sum += __shfl_xor(sum, 32);
            rs[mf] = 1.0f / sum;
        }
        f32x4 acco[4][2] = {};
#pragma unroll
        for (int c = 0; c < 4; c++) {
#pragma unroll
            for (int nfi = 0; nfi < 4; nfi++) {
                const int nf = c * 4 + nfi;
                const int kt = nf >> 1;
                const int gr = (nf & 1) * 2 + (gw >> 1);
                const int lr = l15 + 16 * gr;
                const int j0 = (gw & 1) * 4;
#pragma unroll
                for (int mf = 0; mf < 2; mf++) {
                    uint2 pk;
                    pk.x = (unsigned)f2b(accs[nf][mf][0] * rs[mf]) |
                           ((unsigned)f2b(accs[nf][mf][1] * rs[mf]) << 16);
                    pk.y = (unsigned)f2b(accs[nf][mf][2] * rs[mf]) |
                           ((unsigned)f2b(accs[nf][mf][3] * rs[mf]) << 16);
                    *(uint2*)(Pw + ((kt & 1) * 2 + mf) * 1024 + lr * 16 + j0 * 2) = pk;
                }
            }
#pragma unroll
            for (int kti = 0; kti < 2; kti++) {
                const int kt = c * 2 + kti;
                short8 vf[4];
#pragma unroll
                for (int df = 0; df < 4; df++) {
                    const int d = df * 16 + l15;
                    vf[df] = *(const short8*)(SL + d * 512 + (((kt * 4 + gw) ^ (d & 15)) << 4));
                }
#pragma unroll
                for (int mf = 0; mf < 2; mf++) {
                    const short8 pf = *(const short8*)(Pw + (kti * 2 + mf) * 1024 + l * 16);
#pragma unroll
                    for (int df = 0; df < 4; df++)
                        acco[df][mf] = __builtin_amdgcn_mfma_f32_16x16x32_bf16(vf[df], pf, acco[df][mf], 0, 0, 0);
                }
            }
        }
#pragma unroll
        for (int df = 0; df < 4; df++)
#pragma unroll
            for (int mf = 0; mf < 2; mf++) {
                const int m = mbase + mf * 16 + l15;
                const int d = df * 16 + gw * 4;
                unsigned short o[4];
#pragma unroll
                for (int r = 0; r < 4; r++) o[r] = f2b(acco[df][mf][r]);
                *(uint2*)(AOb + ((long)(b * NN + m) * 256 + h * 64 + d)) = *(uint2*)o;
            }
    }
}

// ---------------- slot logits + softmax over slots (bf16 K reads) ----------------
// grid (BB, 16); per-chunk sums written to sums2[b][chunk][s] (no global atomics).
// mout != nullptr on last iteration: writes masks [b][s][n].
__global__ __launch_bounds__(256) void slot_logits(const unsigned short* __restrict__ KVin,
                                                   const float* __restrict__ Qs,
                                                   float* __restrict__ sattn,
                                                   float* __restrict__ sums2,
                                                   float* __restrict__ mout) {
    const int b = blockIdx.x;
    const int chunk = blockIdx.y;
    __shared__ float qs[NSL][FD];
    __shared__ float colsum[NSL];
    const int tid = threadIdx.x;
    for (int i = tid; i < NSL * FD; i += 256) qs[i / FD][i % FD] = Qs[(long)b * NSL * FD + i];
    if (tid < NSL) colsum[tid] = 0.0f;
    __syncthreads();
    const int wv = tid >> 6, lane = tid & 63;
    float wsum[NSL] = {};
#pragma unroll
    for (int rr = 0; rr < 4; rr++) {
        const int r = chunk * 16 + wv * 4 + rr;
        const unsigned short* kr = KVin + ((long)b * NN + r) * 640;
        float acc[NSL] = {};
#pragma unroll
        for (int i = 0; i < 5; i++) {
            const int t = lane + (i << 6);
            const float kv = b2f(kr[t]);
#pragma unroll
            for (int s = 0; s < NSL; s++) acc[s] = fmaf(kv, qs[s][t], acc[s]);
        }
#pragma unroll
        for (int s = 0; s < NSL; s++)
#pragma unroll
            for (int o = 32; o; o >>= 1) acc[s] += __shfl_down(acc[s], o);
        if (lane == 0) {
            const float scale = 0.055901699437494740f;  // 1/sqrt(320)
            float mx = -1e30f;
#pragma unroll
            for (int s = 0; s < NSL; s++) { acc[s] *= scale; mx = fmaxf(mx, acc[s]); }
            float e[NSL], sum = 0.0f;
#pragma unroll
            for (int s = 0; s < NSL; s++) { e[s] = expf(acc[s] - mx); sum += e[s]; }
            const float rsum = 1.0f / sum;
            float* outp = sattn + ((long)b * NN + r) * NSL;
#pragma unroll
            for (int s = 0; s < NSL; s++) {
                const float pp = e[s] * rsum;
                outp[s] = pp;
                wsum[s] += pp;
                if (mout) mout[(long)b * 2048 + s * 256 + r] = pp;
            }
        }
    }
    if (lane == 0) {
#pragma unroll
        for (int s = 0; s < NSL; s++) atomicAdd(&colsum[s], wsum[s]);
    }
    __syncthreads();
    if (tid < NSL) sums2[((long)(b << 4) + chunk) * NSL + tid] = colsum[tid];
}

// ---------------- slot updates: block per b, LDS reduce, bf16 in/out ----------------
__global__ __launch_bounds__(256) void slot_updates(const float* __restrict__ sattn,
                                                    const float* __restrict__ sums2,
                                                    const unsigned short* __restrict__ KVin,
                                                    unsigned short* __restrict__ Updb) {
    const int b = blockIdx.x;
    const int tid = threadIdx.x;
    const int w = tid >> 6, l = tid & 63;
    __shared__ float inv_s[NSL];
    __shared__ float an_s[NN][NSL];
    __shared__ float red[4][NSL][FD];
    if (tid < NSL) {
        float tot = (float)NN * 1e-8f;
#pragma unroll
        for (int c = 0; c < 16; c++) tot += sums2[((long)(b << 4) + c) * NSL + tid];
        inv_s[tid] = 1.0f / tot;
    }
    __syncthreads();
    {
        const float4 p0 = *(const float4*)(sattn + ((long)b * NN + tid) * NSL);
        const float4 p1 = *(const float4*)(sattn + ((long)b * NN + tid) * NSL + 4);
        an_s[tid][0] = (p0.x + 1e-8f) * inv_s[0];
        an_s[tid][1] = (p0.y + 1e-8f) * inv_s[1];
        an_s[tid][2] = (p0.z + 1e-8f) * inv_s[2];
        an_s[tid][3] = (p0.w + 1e-8f) * inv_s[3];
        an_s[tid][4] = (p1.x + 1e-8f) * inv_s[4];
        an_s[tid][5] = (p1.y + 1e-8f) * inv_s[5];
        an_s[tid][6] = (p1.z + 1e-8f) * inv_s[6];
        an_s[tid][7] = (p1.w + 1e-8f) * inv_s[7];
    }
    __syncthreads();
    float acc[NSL][5] = {};
    const unsigned short* vb = KVin + ((long)b * NN + w * 64) * 640 + 320;
    for (int i = 0; i < 64; i++) {
        float v[5];
#pragma unroll
        for (int j = 0; j < 5; j++) v[j] = b2f(vb[(long)i * 640 + l + (j << 6)]);
        float a[NSL];
#pragma unroll
        for (int s = 0; s < NSL; s++) a[s] = an_s[w * 64 + i][s];
#pragma unroll
        for (int s = 0; s < NSL; s++)
#pragma unroll
            for (int j = 0; j < 5; j++)
                acc[s][j] = fmaf(a[s], v[j], acc[s][j]);
    }
#pragma unroll
    for (int s = 0; s < NSL; s++)
#pragma unroll
        for (int j = 0; j < 5; j++)
            red[w][s][l + (j << 6)] = acc[s][j];
    __syncthreads();
    for (int idx = tid; idx < NSL * FD; idx += 256) {
        const int s = idx / FD, f = idx % FD;
        const float tot = red[0][s][f] + red[1][s][f] + red[2][s][f] + red[3][s][f];
        Updb[((long)b * NSL + s) * FD + f] = f2b(tot);
    }
}

// ---------------- host launcher ----------------
extern "C" void kernel_launch(void* const* d_in, const int* in_sizes, int n_in,
                              void* d_out, int out_size, void* d_ws, size_t ws_size,
                              hipStream_t stream) {
    const float* state    = (const float*)d_in[0];
    const float* conv_w   = (const float*)d_in[1];
    const float* conv_b   = (const float*)d_in[2];
    const float* mlp_ln_g = (const float*)d_in[3];
    const float* mlp_ln_b = (const float*)d_in[4];
    const float* mlp_w1   = (const float*)d_in[5];
    const float* mlp_b1   = (const float*)d_in[6];
    const float* mlp_w2   = (const float*)d_in[7];
    const float* mlp_b2   = (const float*)d_in[8];
    const float* qkv_w    = (const float*)d_in[9];
    const float* qkv_b    = (const float*)d_in[10];
    const float* proj_w   = (const float*)d_in[11];
    const float* proj_b   = (const float*)d_in[12];
    const float* ni_g     = (const float*)d_in[13];
    const float* ni_b     = (const float*)d_in[14];
    const float* ns_g     = (const float*)d_in[15];
    const float* ns_b     = (const float*)d_in[16];
    const float* nm_g     = (const float*)d_in[17];
    const float* nm_b     = (const float*)d_in[18];
    const float* q_w      = (const float*)d_in[19];
    const float* k_w      = (const float*)d_in[20];
    const float* v_w      = (const float*)d_in[21];
    const float* gru_wih  = (const float*)d_in[22];
    const float* gru_whh  = (const float*)d_in[23];
    const float* gru_bih  = (const float*)d_in[24];
    const float* gru_bhh  = (const float*)d_in[25];
    const float* smlp_w1  = (const float*)d_in[26];
    const float* smlp_b1  = (const float*)d_in[27];
    const float* smlp_w2  = (const float*)d_in[28];
    const float* smlp_b2  = (const float*)d_in[29];

    float* ws = (float*)d_ws;
    const int M = BB * NN;  // 16384
    typedef unsigned short u16;

    // ---- workspace layout (float offsets) ----
    u16*   X0b  = (u16*)(ws + 0L);
    u16*   Qr   = (u16*)(ws + 0L);
    u16*   Kr   = (u16*)(ws + 2097152L);
    float* X1   = ws + 6291456L;
    u16*   XLNb = (u16*)(ws + 10485760L);
    u16*   Hbufb= (u16*)(ws + 12582912L);
    u16*   QKVb = (u16*)(ws + 6291456L);
    u16*   X2b  = (u16*)(ws + 23068672L);
    float* X2   = ws + 31457280L;
    u16*   Xnb  = (u16*)(ws + 31457280L);
    float* X3   = ws + 35651584L;
    float* Slots= ws + 35651584L;     // 163840
    float* Qs   = ws + 35979264L;     // 163840
    float* Satt = ws + 36143104L;     // 131072
    float* Sums2= ws + 36274176L;     // 8192 (b x 16 x 8)
    float* GI   = ws + 36438528L;     // 491520
    float* GH   = ws + 36930048L;     // 491520
    u16*   SLnb = (u16*)(ws + 37421568L);  // 163840 u16
    u16*   Updb = (u16*)(ws + 37503488L);  // 163840 u16
    u16*   Slotsb=(u16*)(ws + 37585408L);  // 163840 u16
    u16*   Mhb  = (u16*)(ws + 37667328L);  // 327680 u16
    u16*   KVinb= (u16*)(ws + 39845888L);  // 16384*640 u16 = 10485760 u16
    u16*   AOb    = (u16*)(ws + 50331648L);
    u16*   wb     = (u16*)(ws + 52428800L);   // 2011136 u16 contiguous
    u16*   conv_wb= wb + 0;
    u16*   mlp_w1b= wb + 196608;
    u16*   mlp_w2b= wb + 327680;
    u16*   qkv_wb = wb + 458752;
    u16*   proj_wb= wb + 655360;
    u16*   kv_wb  = wb + 720896;     // k_w rows (320) then v_w rows (320) = N=640
    u16*   q_wb   = wb + 884736;
    u16*   wihb   = wb + 987136;
    u16*   whhb   = wb + 1294336;
    u16*   smlp1b = wb + 1601536;
    u16*   smlp2b = wb + 1806336;
    float* CS     = ws + 53434368L;
    float* SN     = ws + 53450752L;

    float* out = (float*)d_out;

    auto gemmA = [&](const u16* A, const u16* Wt, const float* bias, const float* res,
                     float* C, u16* Cb, int Mm, int Nn, int Kk, int batch,
                     long sA, long sW, long sC1, long sC2, int cdiv, int ldc,
                     float scale, int act) {
        dim3 grid(Nn / 128, Mm / 128, batch);
        if (act) gemm_bf16<128, 128, 1><<<grid, 256, 0, stream>>>(A, Wt, bias, res, C, Cb, Kk, sA, sW, sC1, sC2, cdiv, ldc, scale);
        else     gemm_bf16<128, 128, 0><<<grid, 256, 0, stream>>>(A, Wt, bias, res, C, Cb, Kk, sA, sW, sC1, sC2, cdiv, ldc, scale);
    };
    auto gemmB = [&](const u16* A, const u16* Wt, u16* Cb, int Mm, int Nn, int Kk) {
        dim3 grid(Nn / 64, Mm / 256, 1);
        gemm_bf16<256, 64, 0><<<grid, 256, 0, stream>>>(A, Wt, nullptr, nullptr, nullptr, Cb, Kk, 0, 0, 0, 0, 1, Nn, 1.0f);
    };
    auto gemmS = [&](const u16* A, const u16* Wt, const float* b0, const float* b1,
                     const float* res, float* C, u16* Cb, int Mm, int Nn, int Kk,
                     int batch, long sA, long sW, long sC, int act) {
        dim3 grid(Nn / 64, Mm / 64, batch);
        if (act) gemm_bf16_s<1><<<grid, 256, 0, stream>>>(A, Wt, b0, b1, res, C, Cb, Kk, Nn, sA, sW, sC, 1.0f);
        else     gemm_bf16_s<0><<<grid, 256, 0, stream>>>(A, Wt, b0, b1, res, C, Cb, Kk, Nn, sA, sW, sC, 1.0f);
    };

    // 0. weight conversions + rope tables
    cvt_weights<<<dim3(2011136 / 256), 256, 0, stream>>>(conv_w, mlp_w1, mlp_w2, qkv_w,
                                                         proj_w, k_w, v_w, q_w,
                                                         gru_wih, gru_whh, smlp_w1, smlp_w2, wb);
    rope_tab<<<dim3(16384 / 256), 256, 0, stream>>>(CS, SN);

    // 1. sobel + onehot + im2col (bf16)
    sobel_im2col<<<dim3((BB * HH * WW) / 256), 256, 0, stream>>>(state, X0b);
    // 2. patch conv GEMM -> X1 fp32
    gemmA(X0b, conv_wb, conv_b, nullptr, X1, nullptr, M, EE, KIM, 1, 0, 0, 0, 0, 1, EE, 1.0f, 0);
    // 3. LN -> bf16, MLP
    ln_rows<u16><<<dim3(M * 64 / 256), 256, 0, stream>>>(X1, XLNb, mlp_ln_g, mlp_ln_b, M, EE);
    gemmA(XLNb, mlp_w1b, mlp_b1, nullptr, nullptr, Hbufb, M, 2 * EE, EE, 1, 0, 0, 0, 0, 1, 2 * EE, 1.0f, 1);
    gemmA(Hbufb, mlp_w2b, mlp_b2, nullptr, X2, X2b, M, EE, 2 * EE, 1, 0, 0, 0, 0, 1, EE, 1.0f, 0);
    // 4. QKV + table rope
    gemmA(X2b, qkv_wb, qkv_b, nullptr, nullptr, QKVb, M, 3 * EE, EE, 1, 0, 0, 0, 0, 1, 3 * EE, 1.0f, 0);
    rope_qk<<<dim3(65536 / 256), 256, 0, stream>>>(QKVb, CS, SN, Qr, Kr);
    // 5. fused attention (p split across z -> 512 blocks)
    fused_attn<<<dim3(NHEAD, BB, 2), 256, 0, stream>>>(Qr, Kr, QKVb, AOb);
    // 6. proj + residual -> X3 fp32
    gemmA(AOb, proj_wb, proj_b, X2, X3, nullptr, M, EE, EE, 1, 0, 0, 0, 0, 1, EE, 1.0f, 0);
    // 7. LN ni -> bf16, fused K/V projection (N=640, bf16 out)
    ln_rows<u16><<<dim3(M * 64 / 256), 256, 0, stream>>>(X3, Xnb, ni_g, ni_b, M, EE);
    gemmB(Xnb, kv_wb, KVinb, M, 640, EE);
    // 8. slot attention loop (bf16 MFMA GEMMs, reduced launch count)
    hipMemsetAsync(Slots, 0, (size_t)BB * NSL * FD * sizeof(float), stream);
    hipMemsetAsync(Slotsb, 0, (size_t)BB * NSL * FD * sizeof(u16), stream);
    for (int it = 0; it < 3; it++) {
        ln_rows<u16><<<dim3(512 * 64 / 256), 256, 0, stream>>>(Slots, SLnb, ns_g, ns_b, 512, FD);
        gemmS(SLnb, q_wb, nullptr, nullptr, nullptr, Qs, nullptr, 512, FD, FD, 1, 0, 0, 0, 0);
        slot_logits<<<dim3(BB, 16), 256, 0, stream>>>(KVinb, Qs, Satt, Sums2,
                                                      (it == 2) ? (out + 163840) : nullptr);
        slot_updates<<<dim3(BB), 256, 0, stream>>>(Satt, Sums2, KVinb, Updb);
        // GI = Updb@wih + bih ; GH = Slotsb@whh + bhh  (one launch, z=2)
        gemmS(Updb, wihb, gru_bih, gru_bhh, nullptr, GI, nullptr, 512, 960, FD,
              2, 163840, 307200, 491520, 0);
        gru_ln<<<dim3(512 * 64 / 256), 256, 0, stream>>>(GI, GH, Slots, nm_g, nm_b, SLnb);
        gemmS(SLnb, smlp1b, smlp_b1, nullptr, nullptr, nullptr, Mhb, 512, 2 * FD, FD, 1, 0, 0, 0, 1);
        if (it < 2)
            gemmS(Mhb, smlp2b, smlp_b2, nullptr, Slots, Slots, Slotsb, 512, FD, 2 * FD, 1, 0, 0, 0, 0);
        else
            gemmS(Mhb, smlp2b, smlp_b2, nullptr, Slots, out, nullptr, 512, FD, 2 * FD, 1, 0, 0, 0, 0);
    }
}

// Round 11
// 616.325 us; speedup vs baseline: 1.8967x; 1.0029x over previous
//
#include <hip/hip_runtime.h>
#include <math.h>

// ---------------- problem constants ----------------
#define BB   64
#define HH   128
#define WW   128
#define GG   16
#define NN   256     // G*G tokens
#define EE   256
#define FD   320
#define NSL  8       // slots
#define NHEAD 4
#define HD   64
#define KIM  768     // 12*8*8 im2col K

using short8 = __attribute__((ext_vector_type(8))) short;
using f32x4  = __attribute__((ext_vector_type(4))) float;

__device__ __forceinline__ float sigm(float x) { return 1.0f / (1.0f + expf(-x)); }
__device__ __forceinline__ float gelu_exact(float x) {
    return 0.5f * x * (1.0f + erff(x * 0.70710678118654752f));
}
// round-to-nearest-even f32 -> bf16
__device__ __forceinline__ unsigned short f2b(float x) {
    unsigned u = __float_as_uint(x);
    u += 0x7fffu + ((u >> 16) & 1u);
    return (unsigned short)(u >> 16);
}
__device__ __forceinline__ float b2f(unsigned short u) {
    return __uint_as_float(((unsigned)u) << 16);
}
__device__ __forceinline__ void gload_lds16(const void* g, void* lds) {
    __builtin_amdgcn_global_load_lds(
        (const __attribute__((address_space(1))) unsigned int*)g,
        (__attribute__((address_space(3))) unsigned int*)lds, 16, 0, 0);
}
__device__ __forceinline__ void store_el(float* p, float v) { *p = v; }
__device__ __forceinline__ void store_el(unsigned short* p, float v) { *p = f2b(v); }
__device__ __forceinline__ float load_el(const float* p) { return *p; }
__device__ __forceinline__ float load_el(const unsigned short* p) { return b2f(*p); }

// ---------------- all weight conversions in one kernel ----------------
__global__ __launch_bounds__(256) void cvt_weights(
    const float* __restrict__ w0, const float* __restrict__ w1,
    const float* __restrict__ w2, const float* __restrict__ w3,
    const float* __restrict__ w4, const float* __restrict__ w5,
    const float* __restrict__ w6, const float* __restrict__ w7,
    const float* __restrict__ w8, const float* __restrict__ w9,
    const float* __restrict__ w10, const float* __restrict__ w11,
    unsigned short* __restrict__ dst) {
    int i = blockIdx.x * 256 + threadIdx.x;   // < 2011136
    float v;
    if      (i <  196608) v = w0[i];
    else if (i <  327680) v = w1[i - 196608];
    else if (i <  458752) v = w2[i - 327680];
    else if (i <  655360) v = w3[i - 458752];
    else if (i <  720896) v = w4[i - 655360];
    else if (i <  802816) v = w5[i - 720896];
    else if (i <  884736) v = w6[i - 802816];
    else if (i <  987136) v = w7[i - 884736];
    else if (i < 1294336) v = w8[i - 987136];
    else if (i < 1601536) v = w9[i - 1294336];
    else if (i < 1806336) v = w10[i - 1601536];
    else                  v = w11[i - 1806336];
    dst[i] = f2b(v);
}

// ---------------- RoPE tables: cs/sn[n][d], n<256, d<64 ----------------
__global__ __launch_bounds__(256) void rope_tab(float* __restrict__ cs,
                                                float* __restrict__ sn) {
    int i = blockIdx.x * 256 + threadIdx.x;   // 16384
    int d = i & 63, n = i >> 6;
    int pos = (d < 32) ? (n >> 4) : (n & 15);
    int j = d & 31;
    float freq = powf(10000.0f, -(float)(j & 15) / 16.0f);
    float p = (float)pos * freq;
    float ang = (j < 16) ? sinf(p) : cosf(p);
    cs[i] = cosf(ang);
    sn[i] = sinf(ang);
}

// ---------------- Sobel + one-hot + im2col (bf16 out, exact) ----------------
__global__ __launch_bounds__(256) void sobel_im2col(const float* __restrict__ state,
                                                    unsigned short* __restrict__ X0) {
    int idx = blockIdx.x * 256 + threadIdx.x;
    if (idx >= BB * HH * WW) return;
    int w = idx % WW;
    int h = (idx / WW) % HH;
    int b = idx / (HH * WW);
    const float* st = state + (long)b * HH * WW;
    auto at = [&](int y, int x) {
        y = min(max(y, 0), HH - 1);
        x = min(max(x, 0), WW - 1);
        return st[y * WW + x];
    };
    float v00 = at(h-1, w-1), v01 = at(h-1, w), v02 = at(h-1, w+1);
    float v10 = at(h,   w-1),                  v12 = at(h,   w+1);
    float v20 = at(h+1, w-1), v21 = at(h+1, w), v22 = at(h+1, w+1);
    float sx = (v02 - v00) + 2.0f * (v12 - v10) + (v22 - v20);
    float sy = (v20 - v00) + 2.0f * (v21 - v01) + (v22 - v02);
    int id = (int)st[h * WW + w];
    int gy = h >> 3, i = h & 7, gx = w >> 3, j = w & 7;
    long row = (long)b * NN + gy * GG + gx;
    unsigned short* xr = X0 + row * KIM + i * 8 + j;
#pragma unroll
    for (int c = 0; c < 10; c++) xr[c * 64] = (id == c) ? 0x3F80u : 0u;
    xr[10 * 64] = f2b(sx);
    xr[11 * 64] = f2b(sy);
}

// ---------------- bf16 MFMA NT GEMM (big path; residual read as bf16) ----------------
template <int BM, int BN, int ACT>
__global__ __launch_bounds__(256) void gemm_bf16(
    const unsigned short* __restrict__ A, const unsigned short* __restrict__ W,
    const float* __restrict__ bias, const unsigned short* __restrict__ resb,
    float* __restrict__ C, unsigned short* __restrict__ Cb,
    int K, long sA, long sW, long sC1, long sC2, int cdiv, int ldc, float scale)
{
    constexpr int WN = BN / 64;
    __shared__ __align__(16) unsigned short As[BM * 32];
    __shared__ __align__(16) unsigned short Bs[BN * 32];
    const int tid = threadIdx.x;
    const int w = tid >> 6, l = tid & 63;
    const int wm = w / WN, wn = w % WN;
    const int bz = blockIdx.z;
    const unsigned short* Ab = A + (long)bz * sA + (long)(blockIdx.y * BM) * K;
    const unsigned short* Wb = W + (long)bz * sW + (long)(blockIdx.x * BN) * K;
    const long offC = (long)(bz / cdiv) * sC1 + (long)(bz % cdiv) * sC2;

    const int rA  = l >> 2;
    const int swz = ((l & 3) ^ ((l >> 3) & 3)) * 8;

    f32x4 acc[4][4] = {};

    for (int k0 = 0; k0 < K; k0 += 32) {
#pragma unroll
        for (int c = 0; c < BM / 64; c++) {
            const int chunk = w * (BM / 64) + c;
            gload_lds16(Ab + (long)(chunk * 16 + rA) * K + k0 + swz, (char*)As + chunk * 1024);
        }
#pragma unroll
        for (int c = 0; c < BN / 64; c++) {
            const int chunk = w * (BN / 64) + c;
            gload_lds16(Wb + (long)(chunk * 16 + rA) * K + k0 + swz, (char*)Bs + chunk * 1024);
        }
        __syncthreads();
        short8 af[4], bfr[4];
#pragma unroll
        for (int m = 0; m < 4; m++) {
            const int row = wm * 64 + m * 16 + (l & 15);
            const int byte = row * 64 + (((l >> 4) ^ ((row >> 1) & 3)) << 4);
            af[m] = *(const short8*)((const char*)As + byte);
        }
#pragma unroll
        for (int n = 0; n < 4; n++) {
            const int row = wn * 64 + n * 16 + (l & 15);
            const int byte = row * 64 + (((l >> 4) ^ ((row >> 1) & 3)) << 4);
            bfr[n] = *(const short8*)((const char*)Bs + byte);
        }
#pragma unroll
        for (int m = 0; m < 4; m++)
#pragma unroll
            for (int n = 0; n < 4; n++)
                acc[m][n] = __builtin_amdgcn_mfma_f32_16x16x32_bf16(af[m], bfr[n], acc[m][n], 0, 0, 0);
        __syncthreads();
    }

    const int crow0 = blockIdx.y * BM + wm * 64;
    const int ccol0 = blockIdx.x * BN + wn * 64;
#pragma unroll
    for (int m = 0; m < 4; m++) {
#pragma unroll
        for (int n = 0; n < 4; n++) {
            const int row = crow0 + m * 16 + ((l >> 4) << 2);
            const int col = ccol0 + n * 16 + (l & 15);
#pragma unroll
            for (int r = 0; r < 4; r++) {
                float v = acc[m][n][r] * scale;
                if (bias) v += bias[col];
                if (ACT == 1) v = gelu_exact(v);
                const long idx = offC + (long)(row + r) * ldc + col;
                if (resb) v += b2f(resb[idx]);
                if (C)  C[idx] = v;
                if (Cb) Cb[idx] = f2b(v);
            }
        }
    }
}

// ---------------- small bf16 MFMA NT GEMM (slot loop): 64x64 tile ----------------
template <int ACT>
__global__ __launch_bounds__(256) void gemm_bf16_s(
    const unsigned short* __restrict__ A, const unsigned short* __restrict__ W,
    const float* __restrict__ bias0, const float* __restrict__ bias1,
    const float* __restrict__ res,
    float* __restrict__ C, unsigned short* __restrict__ Cb,
    int K, int N, long sA, long sW, long sC, float scale)
{
    __shared__ __align__(16) unsigned short As[64 * 32];
    __shared__ __align__(16) unsigned short Bs[64 * 32];
    const int tid = threadIdx.x;
    const int w = tid >> 6, l = tid & 63;
    const int gw = l >> 4, l15 = l & 15;
    const int bz = blockIdx.z;
    const unsigned short* Ab = A + (long)bz * sA + (long)(blockIdx.y * 64) * K;
    const unsigned short* Wb = W + (long)bz * sW + (long)(blockIdx.x * 64) * K;
    const float* bias = (bz == 0) ? bias0 : bias1;
    const long offC = (long)bz * sC;

    const int rA  = l >> 2;
    const int swz = ((l & 3) ^ ((l >> 3) & 3)) * 8;

    f32x4 acc[4] = {};

    for (int k0 = 0; k0 < K; k0 += 32) {
        gload_lds16(Ab + (long)(w * 16 + rA) * K + k0 + swz, (char*)As + w * 1024);
        gload_lds16(Wb + (long)(w * 16 + rA) * K + k0 + swz, (char*)Bs + w * 1024);
        __syncthreads();
        short8 af[4];
#pragma unroll
        for (int m = 0; m < 4; m++) {
            const int row = m * 16 + l15;
            af[m] = *(const short8*)((const char*)As + row * 64 + ((gw ^ ((row >> 1) & 3)) << 4));
        }
        const int brow = w * 16 + l15;
        const short8 bf = *(const short8*)((const char*)Bs + brow * 64 + ((gw ^ ((brow >> 1) & 3)) << 4));
#pragma unroll
        for (int m = 0; m < 4; m++)
            acc[m] = __builtin_amdgcn_mfma_f32_16x16x32_bf16(af[m], bf, acc[m], 0, 0, 0);
        __syncthreads();
    }

    const int col = blockIdx.x * 64 + w * 16 + l15;
    const int row0 = blockIdx.y * 64;
#pragma unroll
    for (int m = 0; m < 4; m++) {
        const int row = row0 + m * 16 + (gw << 2);
#pragma unroll
        for (int r = 0; r < 4; r++) {
            float v = acc[m][r] * scale;
            if (bias) v += bias[col];
            if (ACT == 1) v = gelu_exact(v);
            const long idx = offC + (long)(row + r) * N + col;
            if (res) v += res[idx];
            if (C)  C[idx] = v;
            if (Cb) Cb[idx] = f2b(v);
        }
    }
}

// ---------------- LayerNorm (wave per row), templated in/out ----------------
template <typename IT, typename OT>
__global__ __launch_bounds__(256) void ln_rows(const IT* __restrict__ X,
                                               OT* __restrict__ Y,
                                               const float* __restrict__ g,
                                               const float* __restrict__ b,
                                               int rows, int D) {
    int gtid = blockIdx.x * 256 + threadIdx.x;
    int row = gtid >> 6;
    int lane = gtid & 63;
    if (row >= rows) return;
    const IT* x = X + (long)row * D;
    const int nv = D >> 6;
    float v[5];
    float s = 0.0f;
#pragma unroll 5
    for (int i = 0; i < nv; i++) { v[i] = load_el(&x[lane + (i << 6)]); s += v[i]; }
#pragma unroll
    for (int o = 32; o; o >>= 1) s += __shfl_down(s, o);
    s = __shfl(s, 0);
    float mean = s / (float)D;
    float s2 = 0.0f;
#pragma unroll 5
    for (int i = 0; i < nv; i++) { float d = v[i] - mean; s2 += d * d; }
#pragma unroll
    for (int o = 32; o; o >>= 1) s2 += __shfl_down(s2, o);
    s2 = __shfl(s2, 0);
    float inv = rsqrtf(s2 / (float)D + 1e-5f);
    OT* y = Y + (long)row * D;
#pragma unroll 5
    for (int i = 0; i < nv; i++) {
        int d = lane + (i << 6);
        store_el(&y[d], (v[i] - mean) * inv * g[d] + b[d]);
    }
}

// ---------------- fused GRU + LayerNorm(nm) (wave per row) ----------------
__global__ __launch_bounds__(256) void gru_ln(const float* __restrict__ GI,
                                              const float* __restrict__ GH,
                                              float* __restrict__ slots,
                                              const float* __restrict__ g,
                                              const float* __restrict__ b,
                                              unsigned short* __restrict__ SLnb) {
    int gtid = blockIdx.x * 256 + threadIdx.x;
    int row = gtid >> 6;        // < 512
    int lane = gtid & 63;
    const float* gi = GI + (long)row * 960;
    const float* gh = GH + (long)row * 960;
    float* sl = slots + (long)row * FD;
    float h[5];
    float s = 0.0f;
#pragma unroll
    for (int i = 0; i < 5; i++) {
        const int f = lane + (i << 6);
        const float rr = sigm(gi[f] + gh[f]);
        const float z  = sigm(gi[320 + f] + gh[320 + f]);
        const float nn = tanhf(gi[640 + f] + rr * gh[640 + f]);
        const float hn = (1.0f - z) * nn + z * sl[f];
        h[i] = hn;
        s += hn;
        sl[f] = hn;
    }
#pragma unroll
    for (int o = 32; o; o >>= 1) s += __shfl_down(s, o);
    s = __shfl(s, 0);
    const float mean = s * (1.0f / FD);
    float s2 = 0.0f;
#pragma unroll
    for (int i = 0; i < 5; i++) { const float d = h[i] - mean; s2 += d * d; }
#pragma unroll
    for (int o = 32; o; o >>= 1) s2 += __shfl_down(s2, o);
    s2 = __shfl(s2, 0);
    const float inv = rsqrtf(s2 * (1.0f / FD) + 1e-5f);
    unsigned short* y = SLnb + (long)row * FD;
#pragma unroll
    for (int i = 0; i < 5; i++) {
        const int f = lane + (i << 6);
        y[f] = f2b((h[i] - mean) * inv * g[f] + b[f]);
    }
}

// ---------------- table-driven RoPE: QKVb -> Qr, Kr (bf16) ----------------
__global__ __launch_bounds__(256) void rope_qk(const unsigned short* __restrict__ QKVb,
                                               const float* __restrict__ cs,
                                               const float* __restrict__ sn,
                                               unsigned short* __restrict__ Qr,
                                               unsigned short* __restrict__ Kr) {
    const int rid = blockIdx.x * 256 + threadIdx.x;   // b*1024 + h*256 + n
    const int n = rid & 255;
    const int h = (rid >> 8) & 3;
    const int b = rid >> 10;
    const unsigned short* src = QKVb + ((long)(b * 256 + n)) * 768 + h * 64;
    float cv[64], sv[64];
#pragma unroll
    for (int i = 0; i < 16; i++) {
        *(float4*)&cv[i * 4] = *(const float4*)(cs + n * 64 + i * 4);
        *(float4*)&sv[i * 4] = *(const float4*)(sn + n * 64 + i * 4);
    }
#pragma unroll
    for (int qk = 0; qk < 2; qk++) {
        const unsigned short* s0 = src + qk * 256;
        unsigned short* dst = (qk == 0 ? Qr : Kr) + (long)rid * 64;
        float x[64];
#pragma unroll
        for (int i = 0; i < 8; i++) {
            short8 v = *(const short8*)(s0 + i * 8);
#pragma unroll
            for (int j = 0; j < 8; j++) x[i * 8 + j] = b2f((unsigned short)v[j]);
        }
        unsigned short o[64];
#pragma unroll
        for (int d = 0; d < 64; d++) {
            const float rot = (d < 32) ? -x[2 * d + 1] : x[2 * (d - 32)];
            o[d] = f2b(x[d] * cv[d] + rot * sv[d]);
        }
#pragma unroll
        for (int i = 0; i < 8; i++)
            *(short8*)(dst + i * 8) = *(short8*)&o[i * 8];
    }
}

// ---------------- fused attention: one wg per (b,h,p) ----------------
__global__ __launch_bounds__(256, 1) void fused_attn(
    const unsigned short* __restrict__ Qr,
    const unsigned short* __restrict__ Kr,
    const unsigned short* __restrict__ QKVb,
    unsigned short* __restrict__ AOb)
{
    __shared__ __align__(16) char SL[49152];   // V^T 32KB + P 16KB
    const int h = blockIdx.x, b = blockIdx.y;
    const int p = blockIdx.z;
    const int tid = threadIdx.x;
    const int w = tid >> 6, l = tid & 63;
    const int gw = l >> 4, l15 = l & 15;
    const long bh = (long)b * 4 + h;
    const unsigned short* Qb = Qr + bh * NN * 64;
    const unsigned short* Kb = Kr + bh * NN * 64;

    {
        const int n0 = (tid & 127) * 2;
        const int dh = tid >> 7;
        const unsigned short* v0p = QKVb + ((long)b * NN + n0) * 768 + h * 64 + 512 + dh * 32;
        const unsigned short* v1p = v0p + 768;
        unsigned short v0[32], v1[32];
#pragma unroll
        for (int i = 0; i < 4; i++) {
            *(short8*)&v0[i * 8] = *(const short8*)(v0p + i * 8);
            *(short8*)&v1[i * 8] = *(const short8*)(v1p + i * 8);
        }
#pragma unroll
        for (int i = 0; i < 32; i++) {
            const int d = dh * 32 + i;
            const unsigned val = (unsigned)v0[i] | ((unsigned)v1[i] << 16);
            *(unsigned*)(SL + d * 512 + (((n0 >> 3) ^ (d & 15)) << 4) + (n0 & 7) * 2) = val;
        }
    }
    __syncthreads();

    char* Pw = SL + 32768 + w * 4096;

    {
        const int mbase = w * 64 + p * 32;
        f32x4 accs[16][2] = {};
#pragma unroll
        for (int kk = 0; kk < 2; kk++) {
            short8 bq[2];
#pragma unroll
            for (int mf = 0; mf < 2; mf++)
                bq[mf] = *(const short8*)(Qb + ((mbase + mf * 16 + l15) << 6) + kk * 32 + gw * 8);
#pragma unroll
            for (int nf = 0; nf < 16; nf++) {
                const short8 ak = *(const short8*)(Kb + ((nf * 16 + l15) << 6) + kk * 32 + gw * 8);
#pragma unroll
                for (int mf = 0; mf < 2; mf++)
                    accs[nf][mf] = __builtin_amdgcn_mfma_f32_16x16x32_bf16(ak, bq[mf], accs[nf][mf], 0, 0, 0);
            }
        }
        float rs[2];
#pragma unroll
        for (int mf = 0; mf < 2; mf++) {
            float mx = -1e30f;
#pragma unroll
            for (int nf = 0; nf < 16; nf++)
#pragma unroll
                for (int r = 0; r < 4; r++) mx = fmaxf(mx, accs[nf][mf][r]);
            mx = fmaxf(mx, __shfl_xor(mx, 16));
            mx = fmaxf(mx, __shfl_xor(mx, 32));
            float sum = 0.0f;
#pragma unroll
            for (int nf = 0; nf < 16; nf++)
#pragma unroll
                for (int r = 0; r < 4; r++) {
                    const float e = expf((accs[nf][mf][r] - mx) * 0.125f);
                    accs[nf][mf][r] = e;
                    sum += e;
                }
            sum += __shfl_xor(sum, 16);
            sum += __shfl_xor(sum, 32);
            rs[mf] = 1.0f / sum;
        }
        f32x4 acco[4][2] = {};
#pragma unroll
        for (int c = 0; c < 4; c++) {
#pragma unroll
            for (int nfi = 0; nfi < 4; nfi++) {
                const int nf = c * 4 + nfi;
                const int kt = nf >> 1;
                const int gr = (nf & 1) * 2 + (gw >> 1);
                const int lr = l15 + 16 * gr;
                const int j0 = (gw & 1) * 4;
#pragma unroll
                for (int mf = 0; mf < 2; mf++) {
                    uint2 pk;
                    pk.x = (unsigned)f2b(accs[nf][mf][0] * rs[mf]) |
                           ((unsigned)f2b(accs[nf][mf][1] * rs[mf]) << 16);
                    pk.y = (unsigned)f2b(accs[nf][mf][2] * rs[mf]) |
                           ((unsigned)f2b(accs[nf][mf][3] * rs[mf]) << 16);
                    *(uint2*)(Pw + ((kt & 1) * 2 + mf) * 1024 + lr * 16 + j0 * 2) = pk;
                }
            }
#pragma unroll
            for (int kti = 0; kti < 2; kti++) {
                const int kt = c * 2 + kti;
                short8 vf[4];
#pragma unroll
                for (int df = 0; df < 4; df++) {
                    const int d = df * 16 + l15;
                    vf[df] = *(const short8*)(SL + d * 512 + (((kt * 4 + gw) ^ (d & 15)) << 4));
                }
#pragma unroll
                for (int mf = 0; mf < 2; mf++) {
                    const short8 pf = *(const short8*)(Pw + (kti * 2 + mf) * 1024 + l * 16);
#pragma unroll
                    for (int df = 0; df < 4; df++)
                        acco[df][mf] = __builtin_amdgcn_mfma_f32_16x16x32_bf16(vf[df], pf, acco[df][mf], 0, 0, 0);
                }
            }
        }
#pragma unroll
        for (int df = 0; df < 4; df++)
#pragma unroll
            for (int mf = 0; mf < 2; mf++) {
                const int m = mbase + mf * 16 + l15;
                const int d = df * 16 + gw * 4;
                unsigned short o[4];
#pragma unroll
                for (int r = 0; r < 4; r++) o[r] = f2b(acco[df][mf][r]);
                *(uint2*)(AOb + ((long)(b * NN + m) * 256 + h * 64 + d)) = *(uint2*)o;
            }
    }
}

// ---------------- slot logits + softmax over slots (bf16 K reads) ----------------
__global__ __launch_bounds__(256) void slot_logits(const unsigned short* __restrict__ KVin,
                                                   const float* __restrict__ Qs,
                                                   float* __restrict__ sattn,
                                                   float* __restrict__ sums2,
                                                   float* __restrict__ mout) {
    const int b = blockIdx.x;
    const int chunk = blockIdx.y;
    __shared__ float qs[NSL][FD];
    __shared__ float colsum[NSL];
    const int tid = threadIdx.x;
    for (int i = tid; i < NSL * FD; i += 256) qs[i / FD][i % FD] = Qs[(long)b * NSL * FD + i];
    if (tid < NSL) colsum[tid] = 0.0f;
    __syncthreads();
    const int wv = tid >> 6, lane = tid & 63;
    float wsum[NSL] = {};
#pragma unroll
    for (int rr = 0; rr < 4; rr++) {
        const int r = chunk * 16 + wv * 4 + rr;
        const unsigned short* kr = KVin + ((long)b * NN + r) * 640;
        float acc[NSL] = {};
#pragma unroll
        for (int i = 0; i < 5; i++) {
            const int t = lane + (i << 6);
            const float kv = b2f(kr[t]);
#pragma unroll
            for (int s = 0; s < NSL; s++) acc[s] = fmaf(kv, qs[s][t], acc[s]);
        }
#pragma unroll
        for (int s = 0; s < NSL; s++)
#pragma unroll
            for (int o = 32; o; o >>= 1) acc[s] += __shfl_down(acc[s], o);
        if (lane == 0) {
            const float scale = 0.055901699437494740f;  // 1/sqrt(320)
            float mx = -1e30f;
#pragma unroll
            for (int s = 0; s < NSL; s++) { acc[s] *= scale; mx = fmaxf(mx, acc[s]); }
            float e[NSL], sum = 0.0f;
#pragma unroll
            for (int s = 0; s < NSL; s++) { e[s] = expf(acc[s] - mx); sum += e[s]; }
            const float rsum = 1.0f / sum;
            float* outp = sattn + ((long)b * NN + r) * NSL;
#pragma unroll
            for (int s = 0; s < NSL; s++) {
                const float pp = e[s] * rsum;
                outp[s] = pp;
                wsum[s] += pp;
                if (mout) mout[(long)b * 2048 + s * 256 + r] = pp;
            }
        }
    }
    if (lane == 0) {
#pragma unroll
        for (int s = 0; s < NSL; s++) atomicAdd(&colsum[s], wsum[s]);
    }
    __syncthreads();
    if (tid < NSL) sums2[((long)(b << 4) + chunk) * NSL + tid] = colsum[tid];
}

// ---------------- slot updates: block per b, LDS reduce, bf16 in/out ----------------
__global__ __launch_bounds__(256) void slot_updates(const float* __restrict__ sattn,
                                                    const float* __restrict__ sums2,
                                                    const unsigned short* __restrict__ KVin,
                                                    unsigned short* __restrict__ Updb) {
    const int b = blockIdx.x;
    const int tid = threadIdx.x;
    const int w = tid >> 6, l = tid & 63;
    __shared__ float inv_s[NSL];
    __shared__ float an_s[NN][NSL];
    __shared__ float red[4][NSL][FD];
    if (tid < NSL) {
        float tot = (float)NN * 1e-8f;
#pragma unroll
        for (int c = 0; c < 16; c++) tot += sums2[((long)(b << 4) + c) * NSL + tid];
        inv_s[tid] = 1.0f / tot;
    }
    __syncthreads();
    {
        const float4 p0 = *(const float4*)(sattn + ((long)b * NN + tid) * NSL);
        const float4 p1 = *(const float4*)(sattn + ((long)b * NN + tid) * NSL + 4);
        an_s[tid][0] = (p0.x + 1e-8f) * inv_s[0];
        an_s[tid][1] = (p0.y + 1e-8f) * inv_s[1];
        an_s[tid][2] = (p0.z + 1e-8f) * inv_s[2];
        an_s[tid][3] = (p0.w + 1e-8f) * inv_s[3];
        an_s[tid][4] = (p1.x + 1e-8f) * inv_s[4];
        an_s[tid][5] = (p1.y + 1e-8f) * inv_s[5];
        an_s[tid][6] = (p1.z + 1e-8f) * inv_s[6];
        an_s[tid][7] = (p1.w + 1e-8f) * inv_s[7];
    }
    __syncthreads();
    float acc[NSL][5] = {};
    const unsigned short* vb = KVin + ((long)b * NN + w * 64) * 640 + 320;
    for (int i = 0; i < 64; i++) {
        float v[5];
#pragma unroll
        for (int j = 0; j < 5; j++) v[j] = b2f(vb[(long)i * 640 + l + (j << 6)]);
        float a[NSL];
#pragma unroll
        for (int s = 0; s < NSL; s++) a[s] = an_s[w * 64 + i][s];
#pragma unroll
        for (int s = 0; s < NSL; s++)
#pragma unroll
            for (int j = 0; j < 5; j++)
                acc[s][j] = fmaf(a[s], v[j], acc[s][j]);
    }
#pragma unroll
    for (int s = 0; s < NSL; s++)
#pragma unroll
        for (int j = 0; j < 5; j++)
            red[w][s][l + (j << 6)] = acc[s][j];
    __syncthreads();
    for (int idx = tid; idx < NSL * FD; idx += 256) {
        const int s = idx / FD, f = idx % FD;
        const float tot = red[0][s][f] + red[1][s][f] + red[2][s][f] + red[3][s][f];
        Updb[((long)b * NSL + s) * FD + f] = f2b(tot);
    }
}

// ---------------- host launcher ----------------
extern "C" void kernel_launch(void* const* d_in, const int* in_sizes, int n_in,
                              void* d_out, int out_size, void* d_ws, size_t ws_size,
                              hipStream_t stream) {
    const float* state    = (const float*)d_in[0];
    const float* conv_w   = (const float*)d_in[1];
    const float* conv_b   = (const float*)d_in[2];
    const float* mlp_ln_g = (const float*)d_in[3];
    const float* mlp_ln_b = (const float*)d_in[4];
    const float* mlp_w1   = (const float*)d_in[5];
    const float* mlp_b1   = (const float*)d_in[6];
    const float* mlp_w2   = (const float*)d_in[7];
    const float* mlp_b2   = (const float*)d_in[8];
    const float* qkv_w    = (const float*)d_in[9];
    const float* qkv_b    = (const float*)d_in[10];
    const float* proj_w   = (const float*)d_in[11];
    const float* proj_b   = (const float*)d_in[12];
    const float* ni_g     = (const float*)d_in[13];
    const float* ni_b     = (const float*)d_in[14];
    const float* ns_g     = (const float*)d_in[15];
    const float* ns_b     = (const float*)d_in[16];
    const float* nm_g     = (const float*)d_in[17];
    const float* nm_b     = (const float*)d_in[18];
    const float* q_w      = (const float*)d_in[19];
    const float* k_w      = (const float*)d_in[20];
    const float* v_w      = (const float*)d_in[21];
    const float* gru_wih  = (const float*)d_in[22];
    const float* gru_whh  = (const float*)d_in[23];
    const float* gru_bih  = (const float*)d_in[24];
    const float* gru_bhh  = (const float*)d_in[25];
    const float* smlp_w1  = (const float*)d_in[26];
    const float* smlp_b1  = (const float*)d_in[27];
    const float* smlp_w2  = (const float*)d_in[28];
    const float* smlp_b2  = (const float*)d_in[29];

    float* ws = (float*)d_ws;
    const int M = BB * NN;  // 16384
    typedef unsigned short u16;

    // ---- workspace layout (float offsets) ----
    u16*   X0b  = (u16*)(ws + 0L);
    u16*   Qr   = (u16*)(ws + 0L);
    u16*   Kr   = (u16*)(ws + 2097152L);
    u16*   X1b  = (u16*)(ws + 6291456L);       // 4194304 u16
    u16*   XLNb = (u16*)(ws + 10485760L);
    u16*   Hbufb= (u16*)(ws + 12582912L);
    u16*   QKVb = (u16*)(ws + 6291456L);       // aliases X1b region (X1b dead by then)
    u16*   X2b  = (u16*)(ws + 23068672L);
    u16*   X3b  = (u16*)(ws + 31457280L);      // 4194304 u16
    u16*   Xnb  = (u16*)(ws + 33554432L);
    float* Slots= ws + 35651584L;              // 163840 f32
    float* Qs   = ws + 35979264L;              // 163840
    float* Satt = ws + 36143104L;              // 131072
    float* Sums2= ws + 36274176L;              // 8192 (b x 16 x 8)
    float* GI   = ws + 36438528L;              // 491520
    float* GH   = ws + 36930048L;              // 491520
    u16*   SLnb = (u16*)(ws + 37421568L);      // 163840 u16
    u16*   Updb = (u16*)(ws + 37503488L);      // 163840 u16
    u16*   Slotsb=(u16*)(ws + 37585408L);      // 163840 u16 == Updb + 163840 (z=2 stride!)
    u16*   Mhb  = (u16*)(ws + 37667328L);      // 327680 u16
    u16*   KVinb= (u16*)(ws + 39845888L);      // 16384*640 u16
    u16*   AOb    = (u16*)(ws + 50331648L);
    u16*   wb     = (u16*)(ws + 52428800L);    // 2011136 u16 contiguous
    u16*   conv_wb= wb + 0;
    u16*   mlp_w1b= wb + 196608;
    u16*   mlp_w2b= wb + 327680;
    u16*   qkv_wb = wb + 458752;
    u16*   proj_wb= wb + 655360;
    u16*   kv_wb  = wb + 720896;     // k_w rows (320) then v_w rows (320) = N=640
    u16*   q_wb   = wb + 884736;
    u16*   wihb   = wb + 987136;
    u16*   whhb   = wb + 1294336;
    u16*   smlp1b = wb + 1601536;
    u16*   smlp2b = wb + 1806336;
    float* CS     = ws + 53434368L;
    float* SN     = ws + 53450752L;

    float* out = (float*)d_out;

    auto gemmA = [&](const u16* A, const u16* Wt, const float* bias, const u16* resb,
                     float* C, u16* Cb, int Mm, int Nn, int Kk, int batch,
                     long sA, long sW, long sC1, long sC2, int cdiv, int ldc,
                     float scale, int act) {
        dim3 grid(Nn / 128, Mm / 128, batch);
        if (act) gemm_bf16<128, 128, 1><<<grid, 256, 0, stream>>>(A, Wt, bias, resb, C, Cb, Kk, sA, sW, sC1, sC2, cdiv, ldc, scale);
        else     gemm_bf16<128, 128, 0><<<grid, 256, 0, stream>>>(A, Wt, bias, resb, C, Cb, Kk, sA, sW, sC1, sC2, cdiv, ldc, scale);
    };
    auto gemmB = [&](const u16* A, const u16* Wt, u16* Cb, int Mm, int Nn, int Kk) {
        dim3 grid(Nn / 64, Mm / 256, 1);
        gemm_bf16<256, 64, 0><<<grid, 256, 0, stream>>>(A, Wt, nullptr, nullptr, nullptr, Cb, Kk, 0, 0, 0, 0, 1, Nn, 1.0f);
    };
    auto gemmS = [&](const u16* A, const u16* Wt, const float* b0, const float* b1,
                     const float* res, float* C, u16* Cb, int Mm, int Nn, int Kk,
                     int batch, long sA, long sW, long sC, int act) {
        dim3 grid(Nn / 64, Mm / 64, batch);
        if (act) gemm_bf16_s<1><<<grid, 256, 0, stream>>>(A, Wt, b0, b1, res, C, Cb, Kk, Nn, sA, sW, sC, 1.0f);
        else     gemm_bf16_s<0><<<grid, 256, 0, stream>>>(A, Wt, b0, b1, res, C, Cb, Kk, Nn, sA, sW, sC, 1.0f);
    };

    // 0. weight conversions + rope tables
    cvt_weights<<<dim3(2011136 / 256), 256, 0, stream>>>(conv_w, mlp_w1, mlp_w2, qkv_w,
                                                         proj_w, k_w, v_w, q_w,
                                                         gru_wih, gru_whh, smlp_w1, smlp_w2, wb);
    rope_tab<<<dim3(16384 / 256), 256, 0, stream>>>(CS, SN);

    // 1. sobel + onehot + im2col (bf16)
    sobel_im2col<<<dim3((BB * HH * WW) / 256), 256, 0, stream>>>(state, X0b);
    // 2. patch conv GEMM -> X1b bf16
    gemmA(X0b, conv_wb, conv_b, nullptr, nullptr, X1b, M, EE, KIM, 1, 0, 0, 0, 0, 1, EE, 1.0f, 0);
    // 3. LN -> bf16, MLP (bf16 intermediates throughout)
    ln_rows<<<dim3(M * 64 / 256), 256, 0, stream>>>(X1b, XLNb, mlp_ln_g, mlp_ln_b, M, EE);
    gemmA(XLNb, mlp_w1b, mlp_b1, nullptr, nullptr, Hbufb, M, 2 * EE, EE, 1, 0, 0, 0, 0, 1, 2 * EE, 1.0f, 1);
    gemmA(Hbufb, mlp_w2b, mlp_b2, nullptr, nullptr, X2b, M, EE, 2 * EE, 1, 0, 0, 0, 0, 1, EE, 1.0f, 0);
    // 4. QKV + table rope
    gemmA(X2b, qkv_wb, qkv_b, nullptr, nullptr, QKVb, M, 3 * EE, EE, 1, 0, 0, 0, 0, 1, 3 * EE, 1.0f, 0);
    rope_qk<<<dim3(65536 / 256), 256, 0, stream>>>(QKVb, CS, SN, Qr, Kr);
    // 5. fused attention (p split across z -> 512 blocks)
    fused_attn<<<dim3(NHEAD, BB, 2), 256, 0, stream>>>(Qr, Kr, QKVb, AOb);
    // 6. proj + residual (bf16 res) -> X3b bf16
    gemmA(AOb, proj_wb, proj_b, X2b, nullptr, X3b, M, EE, EE, 1, 0, 0, 0, 0, 1, EE, 1.0f, 0);
    // 7. LN ni -> bf16, fused K/V projection (N=640, bf16 out)
    ln_rows<<<dim3(M * 64 / 256), 256, 0, stream>>>(X3b, Xnb, ni_g, ni_b, M, EE);
    gemmB(Xnb, kv_wb, KVinb, M, 640, EE);
    // 8. slot attention loop
    hipMemsetAsync(Slots, 0, (size_t)BB * NSL * FD * sizeof(float), stream);
    hipMemsetAsync(Slotsb, 0, (size_t)BB * NSL * FD * sizeof(u16), stream);
    for (int it = 0; it < 3; it++) {
        ln_rows<<<dim3(512 * 64 / 256), 256, 0, stream>>>(Slots, SLnb, ns_g, ns_b, 512, FD);
        gemmS(SLnb, q_wb, nullptr, nullptr, nullptr, Qs, nullptr, 512, FD, FD, 1, 0, 0, 0, 0);
        slot_logits<<<dim3(BB, 16), 256, 0, stream>>>(KVinb, Qs, Satt, Sums2,
                                                      (it == 2) ? (out + 163840) : nullptr);
        slot_updates<<<dim3(BB), 256, 0, stream>>>(Satt, Sums2, KVinb, Updb);
        // GI = Updb@wih + bih ; GH = Slotsb@whh + bhh  (one launch, z=2; Slotsb == Updb+163840)
        gemmS(Updb, wihb, gru_bih, gru_bhh, nullptr, GI, nullptr, 512, 960, FD,
              2, 163840, 307200, 491520, 0);
        gru_ln<<<dim3(512 * 64 / 256), 256, 0, stream>>>(GI, GH, Slots, nm_g, nm_b, SLnb);
        gemmS(SLnb, smlp1b, smlp_b1, nullptr, nullptr, nullptr, Mhb, 512, 2 * FD, FD, 1, 0, 0, 0, 1);
        if (it < 2)
            gemmS(Mhb, smlp2b, smlp_b2, nullptr, Slots, Slots, Slotsb, 512, FD, 2 * FD, 1, 0, 0, 0, 0);
        else
            gemmS(Mhb, smlp2b, smlp_b2, nullptr, Slots, out, nullptr, 512, FD, 2 * FD, 1, 0, 0, 0, 0);
    }
}

// Round 12
// 583.751 us; speedup vs baseline: 2.0025x; 1.0558x over previous
//
#include <hip/hip_runtime.h>
#include <math.h>

// ---------------- problem constants ----------------
#define BB   64
#define HH   128
#define WW   128
#define GG   16
#define NN   256     // G*G tokens
#define EE   256
#define FD   320
#define NSL  8       // slots
#define NHEAD 4
#define HD   64
#define KIM  768     // 12*8*8 im2col K

using short8 = __attribute__((ext_vector_type(8))) short;
using f32x4  = __attribute__((ext_vector_type(4))) float;

__device__ __forceinline__ float sigm(float x) { return 1.0f / (1.0f + expf(-x)); }
__device__ __forceinline__ float gelu_exact(float x) {
    return 0.5f * x * (1.0f + erff(x * 0.70710678118654752f));
}
// round-to-nearest-even f32 -> bf16
__device__ __forceinline__ unsigned short f2b(float x) {
    unsigned u = __float_as_uint(x);
    u += 0x7fffu + ((u >> 16) & 1u);
    return (unsigned short)(u >> 16);
}
__device__ __forceinline__ float b2f(unsigned short u) {
    return __uint_as_float(((unsigned)u) << 16);
}
__device__ __forceinline__ void gload_lds16(const void* g, void* lds) {
    __builtin_amdgcn_global_load_lds(
        (const __attribute__((address_space(1))) unsigned int*)g,
        (__attribute__((address_space(3))) unsigned int*)lds, 16, 0, 0);
}
__device__ __forceinline__ void store_el(float* p, float v) { *p = v; }
__device__ __forceinline__ void store_el(unsigned short* p, float v) { *p = f2b(v); }
__device__ __forceinline__ float load_el(const float* p) { return *p; }
__device__ __forceinline__ float load_el(const unsigned short* p) { return b2f(*p); }

// ---------------- prep: weight cvt + rope tables + sobel/im2col in ONE kernel ----------------
// ranges (all 256-block-aligned): [0,2011136) weights, [2011136,2027520) rope,
// [2027520,3076096) sobel
__global__ __launch_bounds__(256) void prep_all(
    const float* __restrict__ w0, const float* __restrict__ w1,
    const float* __restrict__ w2, const float* __restrict__ w3,
    const float* __restrict__ w4, const float* __restrict__ w5,
    const float* __restrict__ w6, const float* __restrict__ w7,
    const float* __restrict__ w8, const float* __restrict__ w9,
    const float* __restrict__ w10, const float* __restrict__ w11,
    unsigned short* __restrict__ dst,
    float* __restrict__ cs, float* __restrict__ sn,
    const float* __restrict__ state, unsigned short* __restrict__ X0) {
    int i = blockIdx.x * 256 + threadIdx.x;
    if (i < 2011136) {
        float v;
        if      (i <  196608) v = w0[i];
        else if (i <  327680) v = w1[i - 196608];
        else if (i <  458752) v = w2[i - 327680];
        else if (i <  655360) v = w3[i - 458752];
        else if (i <  720896) v = w4[i - 655360];
        else if (i <  802816) v = w5[i - 720896];
        else if (i <  884736) v = w6[i - 802816];
        else if (i <  987136) v = w7[i - 884736];
        else if (i < 1294336) v = w8[i - 987136];
        else if (i < 1601536) v = w9[i - 1294336];
        else if (i < 1806336) v = w10[i - 1601536];
        else                  v = w11[i - 1806336];
        dst[i] = f2b(v);
    } else if (i < 2027520) {
        int t = i - 2011136;          // < 16384
        int d = t & 63, n = t >> 6;
        int pos = (d < 32) ? (n >> 4) : (n & 15);
        int j = d & 31;
        float freq = powf(10000.0f, -(float)(j & 15) / 16.0f);
        float p = (float)pos * freq;
        float ang = (j < 16) ? sinf(p) : cosf(p);
        cs[t] = cosf(ang);
        sn[t] = sinf(ang);
    } else {
        int idx = i - 2027520;        // < 1048576 = BB*HH*WW
        int w = idx % WW;
        int h = (idx / WW) % HH;
        int b = idx / (HH * WW);
        const float* st = state + (long)b * HH * WW;
        auto at = [&](int y, int x) {
            y = min(max(y, 0), HH - 1);
            x = min(max(x, 0), WW - 1);
            return st[y * WW + x];
        };
        float v00 = at(h-1, w-1), v01 = at(h-1, w), v02 = at(h-1, w+1);
        float v10 = at(h,   w-1),                  v12 = at(h,   w+1);
        float v20 = at(h+1, w-1), v21 = at(h+1, w), v22 = at(h+1, w+1);
        float sx = (v02 - v00) + 2.0f * (v12 - v10) + (v22 - v20);
        float sy = (v20 - v00) + 2.0f * (v21 - v01) + (v22 - v02);
        int id = (int)st[h * WW + w];
        int gy = h >> 3, ii = h & 7, gx = w >> 3, jj = w & 7;
        long row = (long)b * NN + gy * GG + gx;
        unsigned short* xr = X0 + row * KIM + ii * 8 + jj;
#pragma unroll
        for (int c = 0; c < 10; c++) xr[c * 64] = (id == c) ? 0x3F80u : 0u;
        xr[10 * 64] = f2b(sx);
        xr[11 * 64] = f2b(sy);
    }
}

// ---------------- bf16 MFMA NT GEMM (big path; residual read as bf16) ----------------
// Wave mapping: standard (BM*BN==16384): 4 waves of 64x64.
// HALF (BM=128,BN=64): 4 waves of 32x64 -> 2 blocks/CU at grid 512.
template <int BM, int BN, int ACT>
__global__ __launch_bounds__(256) void gemm_bf16(
    const unsigned short* __restrict__ A, const unsigned short* __restrict__ W,
    const float* __restrict__ bias, const unsigned short* __restrict__ resb,
    float* __restrict__ C, unsigned short* __restrict__ Cb,
    int K, long sA, long sW, long sC1, long sC2, int cdiv, int ldc, float scale)
{
    constexpr bool HALF = (BM == 128 && BN == 64);
    constexpr int WN = BN / 64;
    constexpr int MF = HALF ? 2 : 4;
    __shared__ __align__(16) unsigned short As[BM * 32];
    __shared__ __align__(16) unsigned short Bs[BN * 32];
    const int tid = threadIdx.x;
    const int w = tid >> 6, l = tid & 63;
    const int wrow0 = HALF ? w * 32 : (w / WN) * 64;
    const int wcol0 = HALF ? 0 : (w % WN) * 64;
    const int bz = blockIdx.z;
    const unsigned short* Ab = A + (long)bz * sA + (long)(blockIdx.y * BM) * K;
    const unsigned short* Wb = W + (long)bz * sW + (long)(blockIdx.x * BN) * K;
    const long offC = (long)(bz / cdiv) * sC1 + (long)(bz % cdiv) * sC2;

    const int rA  = l >> 2;
    const int swz = ((l & 3) ^ ((l >> 3) & 3)) * 8;

    f32x4 acc[MF][4] = {};

    for (int k0 = 0; k0 < K; k0 += 32) {
#pragma unroll
        for (int c = 0; c < BM / 64; c++) {
            const int chunk = w * (BM / 64) + c;
            gload_lds16(Ab + (long)(chunk * 16 + rA) * K + k0 + swz, (char*)As + chunk * 1024);
        }
#pragma unroll
        for (int c = 0; c < BN / 64; c++) {
            const int chunk = w * (BN / 64) + c;
            gload_lds16(Wb + (long)(chunk * 16 + rA) * K + k0 + swz, (char*)Bs + chunk * 1024);
        }
        __syncthreads();
        short8 af[MF], bfr[4];
#pragma unroll
        for (int m = 0; m < MF; m++) {
            const int row = wrow0 + m * 16 + (l & 15);
            const int byte = row * 64 + (((l >> 4) ^ ((row >> 1) & 3)) << 4);
            af[m] = *(const short8*)((const char*)As + byte);
        }
#pragma unroll
        for (int n = 0; n < 4; n++) {
            const int row = wcol0 + n * 16 + (l & 15);
            const int byte = row * 64 + (((l >> 4) ^ ((row >> 1) & 3)) << 4);
            bfr[n] = *(const short8*)((const char*)Bs + byte);
        }
#pragma unroll
        for (int m = 0; m < MF; m++)
#pragma unroll
            for (int n = 0; n < 4; n++)
                acc[m][n] = __builtin_amdgcn_mfma_f32_16x16x32_bf16(af[m], bfr[n], acc[m][n], 0, 0, 0);
        __syncthreads();
    }

    const int crow0 = blockIdx.y * BM + wrow0;
    const int ccol0 = blockIdx.x * BN + wcol0;
#pragma unroll
    for (int m = 0; m < MF; m++) {
#pragma unroll
        for (int n = 0; n < 4; n++) {
            const int row = crow0 + m * 16 + ((l >> 4) << 2);
            const int col = ccol0 + n * 16 + (l & 15);
#pragma unroll
            for (int r = 0; r < 4; r++) {
                float v = acc[m][n][r] * scale;
                if (bias) v += bias[col];
                if (ACT == 1) v = gelu_exact(v);
                const long idx = offC + (long)(row + r) * ldc + col;
                if (resb) v += b2f(resb[idx]);
                if (C)  C[idx] = v;
                if (Cb) Cb[idx] = f2b(v);
            }
        }
    }
}

// ---------------- small bf16 MFMA NT GEMM (slot loop): 64x64 tile ----------------
template <int ACT>
__global__ __launch_bounds__(256) void gemm_bf16_s(
    const unsigned short* __restrict__ A, const unsigned short* __restrict__ W,
    const float* __restrict__ bias0, const float* __restrict__ bias1,
    const float* __restrict__ res,
    float* __restrict__ C, unsigned short* __restrict__ Cb,
    int K, int N, long sA, long sW, long sC, float scale)
{
    __shared__ __align__(16) unsigned short As[64 * 32];
    __shared__ __align__(16) unsigned short Bs[64 * 32];
    const int tid = threadIdx.x;
    const int w = tid >> 6, l = tid & 63;
    const int gw = l >> 4, l15 = l & 15;
    const int bz = blockIdx.z;
    const unsigned short* Ab = A + (long)bz * sA + (long)(blockIdx.y * 64) * K;
    const unsigned short* Wb = W + (long)bz * sW + (long)(blockIdx.x * 64) * K;
    const float* bias = (bz == 0) ? bias0 : bias1;
    const long offC = (long)bz * sC;

    const int rA  = l >> 2;
    const int swz = ((l & 3) ^ ((l >> 3) & 3)) * 8;

    f32x4 acc[4] = {};

    for (int k0 = 0; k0 < K; k0 += 32) {
        gload_lds16(Ab + (long)(w * 16 + rA) * K + k0 + swz, (char*)As + w * 1024);
        gload_lds16(Wb + (long)(w * 16 + rA) * K + k0 + swz, (char*)Bs + w * 1024);
        __syncthreads();
        short8 af[4];
#pragma unroll
        for (int m = 0; m < 4; m++) {
            const int row = m * 16 + l15;
            af[m] = *(const short8*)((const char*)As + row * 64 + ((gw ^ ((row >> 1) & 3)) << 4));
        }
        const int brow = w * 16 + l15;
        const short8 bf = *(const short8*)((const char*)Bs + brow * 64 + ((gw ^ ((brow >> 1) & 3)) << 4));
#pragma unroll
        for (int m = 0; m < 4; m++)
            acc[m] = __builtin_amdgcn_mfma_f32_16x16x32_bf16(af[m], bf, acc[m], 0, 0, 0);
        __syncthreads();
    }

    const int col = blockIdx.x * 64 + w * 16 + l15;
    const int row0 = blockIdx.y * 64;
#pragma unroll
    for (int m = 0; m < 4; m++) {
        const int row = row0 + m * 16 + (gw << 2);
#pragma unroll
        for (int r = 0; r < 4; r++) {
            float v = acc[m][r] * scale;
            if (bias) v += bias[col];
            if (ACT == 1) v = gelu_exact(v);
            const long idx = offC + (long)(row + r) * N + col;
            if (res) v += res[idx];
            if (C)  C[idx] = v;
            if (Cb) Cb[idx] = f2b(v);
        }
    }
}

// ---------------- LayerNorm (wave per row), templated in/out ----------------
template <typename IT, typename OT>
__global__ __launch_bounds__(256) void ln_rows(const IT* __restrict__ X,
                                               OT* __restrict__ Y,
                                               const float* __restrict__ g,
                                               const float* __restrict__ b,
                                               int rows, int D) {
    int gtid = blockIdx.x * 256 + threadIdx.x;
    int row = gtid >> 6;
    int lane = gtid & 63;
    if (row >= rows) return;
    const IT* x = X + (long)row * D;
    const int nv = D >> 6;
    float v[5];
    float s = 0.0f;
#pragma unroll 5
    for (int i = 0; i < nv; i++) { v[i] = load_el(&x[lane + (i << 6)]); s += v[i]; }
#pragma unroll
    for (int o = 32; o; o >>= 1) s += __shfl_down(s, o);
    s = __shfl(s, 0);
    float mean = s / (float)D;
    float s2 = 0.0f;
#pragma unroll 5
    for (int i = 0; i < nv; i++) { float d = v[i] - mean; s2 += d * d; }
#pragma unroll
    for (int o = 32; o; o >>= 1) s2 += __shfl_down(s2, o);
    s2 = __shfl(s2, 0);
    float inv = rsqrtf(s2 / (float)D + 1e-5f);
    OT* y = Y + (long)row * D;
#pragma unroll 5
    for (int i = 0; i < nv; i++) {
        int d = lane + (i << 6);
        store_el(&y[d], (v[i] - mean) * inv * g[d] + b[d]);
    }
}

// ---------------- fused GRU + LayerNorm(nm) (wave per row) ----------------
__global__ __launch_bounds__(256) void gru_ln(const float* __restrict__ GI,
                                              const float* __restrict__ GH,
                                              float* __restrict__ slots,
                                              const float* __restrict__ g,
                                              const float* __restrict__ b,
                                              unsigned short* __restrict__ SLnb) {
    int gtid = blockIdx.x * 256 + threadIdx.x;
    int row = gtid >> 6;        // < 512
    int lane = gtid & 63;
    const float* gi = GI + (long)row * 960;
    const float* gh = GH + (long)row * 960;
    float* sl = slots + (long)row * FD;
    float h[5];
    float s = 0.0f;
#pragma unroll
    for (int i = 0; i < 5; i++) {
        const int f = lane + (i << 6);
        const float rr = sigm(gi[f] + gh[f]);
        const float z  = sigm(gi[320 + f] + gh[320 + f]);
        const float nn = tanhf(gi[640 + f] + rr * gh[640 + f]);
        const float hn = (1.0f - z) * nn + z * sl[f];
        h[i] = hn;
        s += hn;
        sl[f] = hn;
    }
#pragma unroll
    for (int o = 32; o; o >>= 1) s += __shfl_down(s, o);
    s = __shfl(s, 0);
    const float mean = s * (1.0f / FD);
    float s2 = 0.0f;
#pragma unroll
    for (int i = 0; i < 5; i++) { const float d = h[i] - mean; s2 += d * d; }
#pragma unroll
    for (int o = 32; o; o >>= 1) s2 += __shfl_down(s2, o);
    s2 = __shfl(s2, 0);
    const float inv = rsqrtf(s2 * (1.0f / FD) + 1e-5f);
    unsigned short* y = SLnb + (long)row * FD;
#pragma unroll
    for (int i = 0; i < 5; i++) {
        const int f = lane + (i << 6);
        y[f] = f2b((h[i] - mean) * inv * g[f] + b[f]);
    }
}

// ---------------- table-driven RoPE: QKVb -> Qr, Kr (bf16) ----------------
__global__ __launch_bounds__(256) void rope_qk(const unsigned short* __restrict__ QKVb,
                                               const float* __restrict__ cs,
                                               const float* __restrict__ sn,
                                               unsigned short* __restrict__ Qr,
                                               unsigned short* __restrict__ Kr) {
    const int rid = blockIdx.x * 256 + threadIdx.x;   // b*1024 + h*256 + n
    const int n = rid & 255;
    const int h = (rid >> 8) & 3;
    const int b = rid >> 10;
    const unsigned short* src = QKVb + ((long)(b * 256 + n)) * 768 + h * 64;
    float cv[64], sv[64];
#pragma unroll
    for (int i = 0; i < 16; i++) {
        *(float4*)&cv[i * 4] = *(const float4*)(cs + n * 64 + i * 4);
        *(float4*)&sv[i * 4] = *(const float4*)(sn + n * 64 + i * 4);
    }
#pragma unroll
    for (int qk = 0; qk < 2; qk++) {
        const unsigned short* s0 = src + qk * 256;
        unsigned short* dst = (qk == 0 ? Qr : Kr) + (long)rid * 64;
        float x[64];
#pragma unroll
        for (int i = 0; i < 8; i++) {
            short8 v = *(const short8*)(s0 + i * 8);
#pragma unroll
            for (int j = 0; j < 8; j++) x[i * 8 + j] = b2f((unsigned short)v[j]);
        }
        unsigned short o[64];
#pragma unroll
        for (int d = 0; d < 64; d++) {
            const float rot = (d < 32) ? -x[2 * d + 1] : x[2 * (d - 32)];
            o[d] = f2b(x[d] * cv[d] + rot * sv[d]);
        }
#pragma unroll
        for (int i = 0; i < 8; i++)
            *(short8*)(dst + i * 8) = *(short8*)&o[i * 8];
    }
}

// ---------------- fused attention: one wg per (b,h,p) ----------------
__global__ __launch_bounds__(256, 1) void fused_attn(
    const unsigned short* __restrict__ Qr,
    const unsigned short* __restrict__ Kr,
    const unsigned short* __restrict__ QKVb,
    unsigned short* __restrict__ AOb)
{
    __shared__ __align__(16) char SL[49152];   // V^T 32KB + P 16KB
    const int h = blockIdx.x, b = blockIdx.y;
    const int p = blockIdx.z;
    const int tid = threadIdx.x;
    const int w = tid >> 6, l = tid & 63;
    const int gw = l >> 4, l15 = l & 15;
    const long bh = (long)b * 4 + h;
    const unsigned short* Qb = Qr + bh * NN * 64;
    const unsigned short* Kb = Kr + bh * NN * 64;

    {
        const int n0 = (tid & 127) * 2;
        const int dh = tid >> 7;
        const unsigned short* v0p = QKVb + ((long)b * NN + n0) * 768 + h * 64 + 512 + dh * 32;
        const unsigned short* v1p = v0p + 768;
        unsigned short v0[32], v1[32];
#pragma unroll
        for (int i = 0; i < 4; i++) {
            *(short8*)&v0[i * 8] = *(const short8*)(v0p + i * 8);
            *(short8*)&v1[i * 8] = *(const short8*)(v1p + i * 8);
        }
#pragma unroll
        for (int i = 0; i < 32; i++) {
            const int d = dh * 32 + i;
            const unsigned val = (unsigned)v0[i] | ((unsigned)v1[i] << 16);
            *(unsigned*)(SL + d * 512 + (((n0 >> 3) ^ (d & 15)) << 4) + (n0 & 7) * 2) = val;
        }
    }
    __syncthreads();

    char* Pw = SL + 32768 + w * 4096;

    {
        const int mbase = w * 64 + p * 32;
        f32x4 accs[16][2] = {};
#pragma unroll
        for (int kk = 0; kk < 2; kk++) {
            short8 bq[2];
#pragma unroll
            for (int mf = 0; mf < 2; mf++)
                bq[mf] = *(const short8*)(Qb + ((mbase + mf * 16 + l15) << 6) + kk * 32 + gw * 8);
#pragma unroll
            for (int nf = 0; nf < 16; nf++) {
                const short8 ak = *(const short8*)(Kb + ((nf * 16 + l15) << 6) + kk * 32 + gw * 8);
#pragma unroll
                for (int mf = 0; mf < 2; mf++)
                    accs[nf][mf] = __builtin_amdgcn_mfma_f32_16x16x32_bf16(ak, bq[mf], accs[nf][mf], 0, 0, 0);
            }
        }
        float rs[2];
#pragma unroll
        for (int mf = 0; mf < 2; mf++) {
            float mx = -1e30f;
#pragma unroll
            for (int nf = 0; nf < 16; nf++)
#pragma unroll
                for (int r = 0; r < 4; r++) mx = fmaxf(mx, accs[nf][mf][r]);
            mx = fmaxf(mx, __shfl_xor(mx, 16));
            mx = fmaxf(mx, __shfl_xor(mx, 32));
            float sum = 0.0f;
#pragma unroll
            for (int nf = 0; nf < 16; nf++)
#pragma unroll
                for (int r = 0; r < 4; r++) {
                    const float e = expf((accs[nf][mf][r] - mx) * 0.125f);
                    accs[nf][mf][r] = e;
                    sum += e;
                }
            sum += __shfl_xor(sum, 16);
            sum += __shfl_xor(sum, 32);
            rs[mf] = 1.0f / sum;
        }
        f32x4 acco[4][2] = {};
#pragma unroll
        for (int c = 0; c < 4; c++) {
#pragma unroll
            for (int nfi = 0; nfi < 4; nfi++) {
                const int nf = c * 4 + nfi;
                const int kt = nf >> 1;
                const int gr = (nf & 1) * 2 + (gw >> 1);
                const int lr = l15 + 16 * gr;
                const int j0 = (gw & 1) * 4;
#pragma unroll
                for (int mf = 0; mf < 2; mf++) {
                    uint2 pk;
                    pk.x = (unsigned)f2b(accs[nf][mf][0] * rs[mf]) |
                           ((unsigned)f2b(accs[nf][mf][1] * rs[mf]) << 16);
                    pk.y = (unsigned)f2b(accs[nf][mf][2] * rs[mf]) |
                           ((unsigned)f2b(accs[nf][mf][3] * rs[mf]) << 16);
                    *(uint2*)(Pw + ((kt & 1) * 2 + mf) * 1024 + lr * 16 + j0 * 2) = pk;
                }
            }
#pragma unroll
            for (int kti = 0; kti < 2; kti++) {
                const int kt = c * 2 + kti;
                short8 vf[4];
#pragma unroll
                for (int df = 0; df < 4; df++) {
                    const int d = df * 16 + l15;
                    vf[df] = *(const short8*)(SL + d * 512 + (((kt * 4 + gw) ^ (d & 15)) << 4));
                }
#pragma unroll
                for (int mf = 0; mf < 2; mf++) {
                    const short8 pf = *(const short8*)(Pw + (kti * 2 + mf) * 1024 + l * 16);
#pragma unroll
                    for (int df = 0; df < 4; df++)
                        acco[df][mf] = __builtin_amdgcn_mfma_f32_16x16x32_bf16(vf[df], pf, acco[df][mf], 0, 0, 0);
                }
            }
        }
#pragma unroll
        for (int df = 0; df < 4; df++)
#pragma unroll
            for (int mf = 0; mf < 2; mf++) {
                const int m = mbase + mf * 16 + l15;
                const int d = df * 16 + gw * 4;
                unsigned short o[4];
#pragma unroll
                for (int r = 0; r < 4; r++) o[r] = f2b(acco[df][mf][r]);
                *(uint2*)(AOb + ((long)(b * NN + m) * 256 + h * 64 + d)) = *(uint2*)o;
            }
    }
}

// ---------------- slot logits + softmax over slots (bf16 K reads) ----------------
__global__ __launch_bounds__(256) void slot_logits(const unsigned short* __restrict__ KVin,
                                                   const float* __restrict__ Qs,
                                                   float* __restrict__ sattn,
                                                   float* __restrict__ sums2,
                                                   float* __restrict__ mout) {
    const int b = blockIdx.x;
    const int chunk = blockIdx.y;
    __shared__ float qs[NSL][FD];
    __shared__ float colsum[NSL];
    const int tid = threadIdx.x;
    for (int i = tid; i < NSL * FD; i += 256) qs[i / FD][i % FD] = Qs[(long)b * NSL * FD + i];
    if (tid < NSL) colsum[tid] = 0.0f;
    __syncthreads();
    const int wv = tid >> 6, lane = tid & 63;
    float wsum[NSL] = {};
#pragma unroll
    for (int rr = 0; rr < 4; rr++) {
        const int r = chunk * 16 + wv * 4 + rr;
        const unsigned short* kr = KVin + ((long)b * NN + r) * 640;
        float acc[NSL] = {};
#pragma unroll
        for (int i = 0; i < 5; i++) {
            const int t = lane + (i << 6);
            const float kv = b2f(kr[t]);
#pragma unroll
            for (int s = 0; s < NSL; s++) acc[s] = fmaf(kv, qs[s][t], acc[s]);
        }
#pragma unroll
        for (int s = 0; s < NSL; s++)
#pragma unroll
            for (int o = 32; o; o >>= 1) acc[s] += __shfl_down(acc[s], o);
        if (lane == 0) {
            const float scale = 0.055901699437494740f;  // 1/sqrt(320)
            float mx = -1e30f;
#pragma unroll
            for (int s = 0; s < NSL; s++) { acc[s] *= scale; mx = fmaxf(mx, acc[s]); }
            float e[NSL], sum = 0.0f;
#pragma unroll
            for (int s = 0; s < NSL; s++) { e[s] = expf(acc[s] - mx); sum += e[s]; }
            const float rsum = 1.0f / sum;
            float* outp = sattn + ((long)b * NN + r) * NSL;
#pragma unroll
            for (int s = 0; s < NSL; s++) {
                const float pp = e[s] * rsum;
                outp[s] = pp;
                wsum[s] += pp;
                if (mout) mout[(long)b * 2048 + s * 256 + r] = pp;
            }
        }
    }
    if (lane == 0) {
#pragma unroll
        for (int s = 0; s < NSL; s++) atomicAdd(&colsum[s], wsum[s]);
    }
    __syncthreads();
    if (tid < NSL) sums2[((long)(b << 4) + chunk) * NSL + tid] = colsum[tid];
}

// ---------------- slot updates: block per b, LDS reduce, bf16 in/out ----------------
__global__ __launch_bounds__(256) void slot_updates(const float* __restrict__ sattn,
                                                    const float* __restrict__ sums2,
                                                    const unsigned short* __restrict__ KVin,
                                                    unsigned short* __restrict__ Updb) {
    const int b = blockIdx.x;
    const int tid = threadIdx.x;
    const int w = tid >> 6, l = tid & 63;
    __shared__ float inv_s[NSL];
    __shared__ float an_s[NN][NSL];
    __shared__ float red[4][NSL][FD];
    if (tid < NSL) {
        float tot = (float)NN * 1e-8f;
#pragma unroll
        for (int c = 0; c < 16; c++) tot += sums2[((long)(b << 4) + c) * NSL + tid];
        inv_s[tid] = 1.0f / tot;
    }
    __syncthreads();
    {
        const float4 p0 = *(const float4*)(sattn + ((long)b * NN + tid) * NSL);
        const float4 p1 = *(const float4*)(sattn + ((long)b * NN + tid) * NSL + 4);
        an_s[tid][0] = (p0.x + 1e-8f) * inv_s[0];
        an_s[tid][1] = (p0.y + 1e-8f) * inv_s[1];
        an_s[tid][2] = (p0.z + 1e-8f) * inv_s[2];
        an_s[tid][3] = (p0.w + 1e-8f) * inv_s[3];
        an_s[tid][4] = (p1.x + 1e-8f) * inv_s[4];
        an_s[tid][5] = (p1.y + 1e-8f) * inv_s[5];
        an_s[tid][6] = (p1.z + 1e-8f) * inv_s[6];
        an_s[tid][7] = (p1.w + 1e-8f) * inv_s[7];
    }
    __syncthreads();
    float acc[NSL][5] = {};
    const unsigned short* vb = KVin + ((long)b * NN + w * 64) * 640 + 320;
    for (int i = 0; i < 64; i++) {
        float v[5];
#pragma unroll
        for (int j = 0; j < 5; j++) v[j] = b2f(vb[(long)i * 640 + l + (j << 6)]);
        float a[NSL];
#pragma unroll
        for (int s = 0; s < NSL; s++) a[s] = an_s[w * 64 + i][s];
#pragma unroll
        for (int s = 0; s < NSL; s++)
#pragma unroll
            for (int j = 0; j < 5; j++)
                acc[s][j] = fmaf(a[s], v[j], acc[s][j]);
    }
#pragma unroll
    for (int s = 0; s < NSL; s++)
#pragma unroll
        for (int j = 0; j < 5; j++)
            red[w][s][l + (j << 6)] = acc[s][j];
    __syncthreads();
    for (int idx = tid; idx < NSL * FD; idx += 256) {
        const int s = idx / FD, f = idx % FD;
        const float tot = red[0][s][f] + red[1][s][f] + red[2][s][f] + red[3][s][f];
        Updb[((long)b * NSL + s) * FD + f] = f2b(tot);
    }
}

// ---------------- host launcher ----------------
extern "C" void kernel_launch(void* const* d_in, const int* in_sizes, int n_in,
                              void* d_out, int out_size, void* d_ws, size_t ws_size,
                              hipStream_t stream) {
    const float* state    = (const float*)d_in[0];
    const float* conv_w   = (const float*)d_in[1];
    const float* conv_b   = (const float*)d_in[2];
    const float* mlp_ln_g = (const float*)d_in[3];
    const float* mlp_ln_b = (const float*)d_in[4];
    const float* mlp_w1   = (const float*)d_in[5];
    const float* mlp_b1   = (const float*)d_in[6];
    const float* mlp_w2   = (const float*)d_in[7];
    const float* mlp_b2   = (const float*)d_in[8];
    const float* qkv_w    = (const float*)d_in[9];
    const float* qkv_b    = (const float*)d_in[10];
    const float* proj_w   = (const float*)d_in[11];
    const float* proj_b   = (const float*)d_in[12];
    const float* ni_g     = (const float*)d_in[13];
    const float* ni_b     = (const float*)d_in[14];
    const float* ns_g     = (const float*)d_in[15];
    const float* ns_b     = (const float*)d_in[16];
    const float* nm_g     = (const float*)d_in[17];
    const float* nm_b     = (const float*)d_in[18];
    const float* q_w      = (const float*)d_in[19];
    const float* k_w      = (const float*)d_in[20];
    const float* v_w      = (const float*)d_in[21];
    const float* gru_wih  = (const float*)d_in[22];
    const float* gru_whh  = (const float*)d_in[23];
    const float* gru_bih  = (const float*)d_in[24];
    const float* gru_bhh  = (const float*)d_in[25];
    const float* smlp_w1  = (const float*)d_in[26];
    const float* smlp_b1  = (const float*)d_in[27];
    const float* smlp_w2  = (const float*)d_in[28];
    const float* smlp_b2  = (const float*)d_in[29];

    float* ws = (float*)d_ws;
    const int M = BB * NN;  // 16384
    typedef unsigned short u16;

    // ---- workspace layout (float offsets) ----
    u16*   X0b  = (u16*)(ws + 0L);
    u16*   Qr   = (u16*)(ws + 0L);
    u16*   Kr   = (u16*)(ws + 2097152L);
    u16*   X1b  = (u16*)(ws + 6291456L);       // 4194304 u16
    u16*   XLNb = (u16*)(ws + 10485760L);
    u16*   Hbufb= (u16*)(ws + 12582912L);
    u16*   QKVb = (u16*)(ws + 6291456L);       // aliases X1b region (X1b dead by then)
    u16*   X2b  = (u16*)(ws + 23068672L);
    u16*   X3b  = (u16*)(ws + 31457280L);      // 4194304 u16
    u16*   Xnb  = (u16*)(ws + 33554432L);
    float* Slots= ws + 35651584L;              // 163840 f32
    float* Qs   = ws + 35979264L;              // 163840
    float* Satt = ws + 36143104L;              // 131072
    float* Sums2= ws + 36274176L;              // 8192 (b x 16 x 8)
    float* GI   = ws + 36438528L;              // 491520
    float* GH   = ws + 36930048L;              // 491520
    u16*   SLnb = (u16*)(ws + 37421568L);      // 163840 u16
    u16*   Updb = (u16*)(ws + 37503488L);      // 163840 u16
    u16*   Slotsb=(u16*)(ws + 37585408L);      // 163840 u16 == Updb + 163840 (z=2 stride!)
    u16*   Mhb  = (u16*)(ws + 37667328L);      // 327680 u16
    u16*   KVinb= (u16*)(ws + 39845888L);      // 16384*640 u16
    u16*   AOb    = (u16*)(ws + 50331648L);
    u16*   wb     = (u16*)(ws + 52428800L);    // 2011136 u16 contiguous
    u16*   conv_wb= wb + 0;
    u16*   mlp_w1b= wb + 196608;
    u16*   mlp_w2b= wb + 327680;
    u16*   qkv_wb = wb + 458752;
    u16*   proj_wb= wb + 655360;
    u16*   kv_wb  = wb + 720896;     // k_w rows (320) then v_w rows (320) = N=640
    u16*   q_wb   = wb + 884736;
    u16*   wihb   = wb + 987136;
    u16*   whhb   = wb + 1294336;
    u16*   smlp1b = wb + 1601536;
    u16*   smlp2b = wb + 1806336;
    float* CS     = ws + 53434368L;
    float* SN     = ws + 53450752L;

    float* out = (float*)d_out;

    auto gemmA = [&](const u16* A, const u16* Wt, const float* bias, const u16* resb,
                     float* C, u16* Cb, int Mm, int Nn, int Kk, int batch,
                     long sA, long sW, long sC1, long sC2, int cdiv, int ldc,
                     float scale, int act) {
        dim3 grid(Nn / 128, Mm / 128, batch);
        if (act) gemm_bf16<128, 128, 1><<<grid, 256, 0, stream>>>(A, Wt, bias, resb, C, Cb, Kk, sA, sW, sC1, sC2, cdiv, ldc, scale);
        else     gemm_bf16<128, 128, 0><<<grid, 256, 0, stream>>>(A, Wt, bias, resb, C, Cb, Kk, sA, sW, sC1, sC2, cdiv, ldc, scale);
    };
    // 128x64-tile variant: 2 blocks/CU for N=256 GEMMs
    auto gemmA64 = [&](const u16* A, const u16* Wt, const float* bias, const u16* resb,
                       float* C, u16* Cb, int Mm, int Nn, int Kk, int ldc) {
        dim3 grid(Nn / 64, Mm / 128, 1);
        gemm_bf16<128, 64, 0><<<grid, 256, 0, stream>>>(A, Wt, bias, resb, C, Cb, Kk, 0, 0, 0, 0, 1, ldc, 1.0f);
    };
    auto gemmB = [&](const u16* A, const u16* Wt, u16* Cb, int Mm, int Nn, int Kk) {
        dim3 grid(Nn / 64, Mm / 256, 1);
        gemm_bf16<256, 64, 0><<<grid, 256, 0, stream>>>(A, Wt, nullptr, nullptr, nullptr, Cb, Kk, 0, 0, 0, 0, 1, Nn, 1.0f);
    };
    auto gemmS = [&](const u16* A, const u16* Wt, const float* b0, const float* b1,
                     const float* res, float* C, u16* Cb, int Mm, int Nn, int Kk,
                     int batch, long sA, long sW, long sC, int act) {
        dim3 grid(Nn / 64, Mm / 64, batch);
        if (act) gemm_bf16_s<1><<<grid, 256, 0, stream>>>(A, Wt, b0, b1, res, C, Cb, Kk, Nn, sA, sW, sC, 1.0f);
        else     gemm_bf16_s<0><<<grid, 256, 0, stream>>>(A, Wt, b0, b1, res, C, Cb, Kk, Nn, sA, sW, sC, 1.0f);
    };

    // 0. prep: weight cvt + rope tables + sobel/im2col (one kernel)
    prep_all<<<dim3(3076096 / 256), 256, 0, stream>>>(conv_w, mlp_w1, mlp_w2, qkv_w,
                                                      proj_w, k_w, v_w, q_w,
                                                      gru_wih, gru_whh, smlp_w1, smlp_w2,
                                                      wb, CS, SN, state, X0b);

    // 2. patch conv GEMM -> X1b bf16 (128x64 tiles, 512 blocks)
    gemmA64(X0b, conv_wb, conv_b, nullptr, nullptr, X1b, M, EE, KIM, EE);
    // 3. LN -> bf16, MLP
    ln_rows<<<dim3(M * 64 / 256), 256, 0, stream>>>(X1b, XLNb, mlp_ln_g, mlp_ln_b, M, EE);
    gemmA(XLNb, mlp_w1b, mlp_b1, nullptr, nullptr, Hbufb, M, 2 * EE, EE, 1, 0, 0, 0, 0, 1, 2 * EE, 1.0f, 1);
    gemmA64(Hbufb, mlp_w2b, mlp_b2, nullptr, nullptr, X2b, M, EE, 2 * EE, EE);
    // 4. QKV + table rope
    gemmA(X2b, qkv_wb, qkv_b, nullptr, nullptr, QKVb, M, 3 * EE, EE, 1, 0, 0, 0, 0, 1, 3 * EE, 1.0f, 0);
    rope_qk<<<dim3(65536 / 256), 256, 0, stream>>>(QKVb, CS, SN, Qr, Kr);
    // 5. fused attention (p split across z -> 512 blocks)
    fused_attn<<<dim3(NHEAD, BB, 2), 256, 0, stream>>>(Qr, Kr, QKVb, AOb);
    // 6. proj + residual (bf16 res) -> X3b bf16 (128x64 tiles)
    gemmA64(AOb, proj_wb, proj_b, X2b, nullptr, X3b, M, EE, EE, EE);
    // 7. LN ni -> bf16, fused K/V projection (N=640, bf16 out)
    ln_rows<<<dim3(M * 64 / 256), 256, 0, stream>>>(X3b, Xnb, ni_g, ni_b, M, EE);
    gemmB(Xnb, kv_wb, KVinb, M, 640, EE);
    // 8. slot attention loop
    hipMemsetAsync(Slots, 0, (size_t)BB * NSL * FD * sizeof(float), stream);
    hipMemsetAsync(Slotsb, 0, (size_t)BB * NSL * FD * sizeof(u16), stream);
    for (int it = 0; it < 3; it++) {
        ln_rows<<<dim3(512 * 64 / 256), 256, 0, stream>>>(Slots, SLnb, ns_g, ns_b, 512, FD);
        gemmS(SLnb, q_wb, nullptr, nullptr, nullptr, Qs, nullptr, 512, FD, FD, 1, 0, 0, 0, 0);
        slot_logits<<<dim3(BB, 16), 256, 0, stream>>>(KVinb, Qs, Satt, Sums2,
                                                      (it == 2) ? (out + 163840) : nullptr);
        slot_updates<<<dim3(BB), 256, 0, stream>>>(Satt, Sums2, KVinb, Updb);
        // GI = Updb@wih + bih ; GH = Slotsb@whh + bhh  (one launch, z=2; Slotsb == Updb+163840)
        gemmS(Updb, wihb, gru_bih, gru_bhh, nullptr, GI, nullptr, 512, 960, FD,
              2, 163840, 307200, 491520, 0);
        gru_ln<<<dim3(512 * 64 / 256), 256, 0, stream>>>(GI, GH, Slots, nm_g, nm_b, SLnb);
        gemmS(SLnb, smlp1b, smlp_b1, nullptr, nullptr, nullptr, Mhb, 512, 2 * FD, FD, 1, 0, 0, 0, 1);
        if (it < 2)
            gemmS(Mhb, smlp2b, smlp_b2, nullptr, Slots, Slots, Slotsb, 512, FD, 2 * FD, 1, 0, 0, 0, 0);
        else
            gemmS(Mhb, smlp2b, smlp_b2, nullptr, Slots, out, nullptr, 512, FD, 2 * FD, 1, 0, 0, 0, 0);
    }
}

// Round 13
// 578.972 us; speedup vs baseline: 2.0190x; 1.0083x over previous
//
#include <hip/hip_runtime.h>
#include <math.h>

// ---------------- problem constants ----------------
#define BB   64
#define HH   128
#define WW   128
#define GG   16
#define NN   256     // G*G tokens
#define EE   256
#define FD   320
#define NSL  8       // slots
#define NHEAD 4
#define HD   64
#define KIM  768     // 12*8*8 im2col K

using short8 = __attribute__((ext_vector_type(8))) short;
using f32x4  = __attribute__((ext_vector_type(4))) float;

__device__ __forceinline__ float sigm(float x) { return 1.0f / (1.0f + expf(-x)); }
__device__ __forceinline__ float gelu_exact(float x) {
    return 0.5f * x * (1.0f + erff(x * 0.70710678118654752f));
}
// round-to-nearest-even f32 -> bf16
__device__ __forceinline__ unsigned short f2b(float x) {
    unsigned u = __float_as_uint(x);
    u += 0x7fffu + ((u >> 16) & 1u);
    return (unsigned short)(u >> 16);
}
__device__ __forceinline__ float b2f(unsigned short u) {
    return __uint_as_float(((unsigned)u) << 16);
}
__device__ __forceinline__ void gload_lds16(const void* g, void* lds) {
    __builtin_amdgcn_global_load_lds(
        (const __attribute__((address_space(1))) unsigned int*)g,
        (__attribute__((address_space(3))) unsigned int*)lds, 16, 0, 0);
}
__device__ __forceinline__ void store_el(float* p, float v) { *p = v; }
__device__ __forceinline__ void store_el(unsigned short* p, float v) { *p = f2b(v); }
__device__ __forceinline__ float load_el(const float* p) { return *p; }
__device__ __forceinline__ float load_el(const unsigned short* p) { return b2f(*p); }

// ---------------- prep: weights + rope tables + sobel/im2col + slot zero (ONE kernel) ----------------
// ranges (256-aligned): [0,2011136) weights, [2011136,2027520) rope,
// [2027520,3076096) sobel, [3076096,3239936) Slots=0, [3239936,3403776) Slotsb=0
__global__ __launch_bounds__(256) void prep_all(
    const float* __restrict__ w0, const float* __restrict__ w1,
    const float* __restrict__ w2, const float* __restrict__ w3,
    const float* __restrict__ w4, const float* __restrict__ w5,
    const float* __restrict__ w6, const float* __restrict__ w7,
    const float* __restrict__ w8, const float* __restrict__ w9,
    const float* __restrict__ w10, const float* __restrict__ w11,
    unsigned short* __restrict__ dst,
    float* __restrict__ cs, float* __restrict__ sn,
    const float* __restrict__ state, unsigned short* __restrict__ X0,
    float* __restrict__ slots0, unsigned short* __restrict__ slotsb0) {
    int i = blockIdx.x * 256 + threadIdx.x;
    if (i < 2011136) {
        float v;
        if      (i <  196608) v = w0[i];
        else if (i <  327680) v = w1[i - 196608];
        else if (i <  458752) v = w2[i - 327680];
        else if (i <  655360) v = w3[i - 458752];
        else if (i <  720896) v = w4[i - 655360];
        else if (i <  802816) v = w5[i - 720896];
        else if (i <  884736) v = w6[i - 802816];
        else if (i <  987136) v = w7[i - 884736];
        else if (i < 1294336) v = w8[i - 987136];
        else if (i < 1601536) v = w9[i - 1294336];
        else if (i < 1806336) v = w10[i - 1601536];
        else                  v = w11[i - 1806336];
        dst[i] = f2b(v);
    } else if (i < 2027520) {
        int t = i - 2011136;          // < 16384
        int d = t & 63, n = t >> 6;
        int pos = (d < 32) ? (n >> 4) : (n & 15);
        int j = d & 31;
        float freq = powf(10000.0f, -(float)(j & 15) / 16.0f);
        float p = (float)pos * freq;
        float ang = (j < 16) ? sinf(p) : cosf(p);
        cs[t] = cosf(ang);
        sn[t] = sinf(ang);
    } else if (i < 3076096) {
        int idx = i - 2027520;        // < 1048576 = BB*HH*WW
        int w = idx % WW;
        int h = (idx / WW) % HH;
        int b = idx / (HH * WW);
        const float* st = state + (long)b * HH * WW;
        auto at = [&](int y, int x) {
            y = min(max(y, 0), HH - 1);
            x = min(max(x, 0), WW - 1);
            return st[y * WW + x];
        };
        float v00 = at(h-1, w-1), v01 = at(h-1, w), v02 = at(h-1, w+1);
        float v10 = at(h,   w-1),                  v12 = at(h,   w+1);
        float v20 = at(h+1, w-1), v21 = at(h+1, w), v22 = at(h+1, w+1);
        float sx = (v02 - v00) + 2.0f * (v12 - v10) + (v22 - v20);
        float sy = (v20 - v00) + 2.0f * (v21 - v01) + (v22 - v02);
        int id = (int)st[h * WW + w];
        int gy = h >> 3, ii = h & 7, gx = w >> 3, jj = w & 7;
        long row = (long)b * NN + gy * GG + gx;
        unsigned short* xr = X0 + row * KIM + ii * 8 + jj;
#pragma unroll
        for (int c = 0; c < 10; c++) xr[c * 64] = (id == c) ? 0x3F80u : 0u;
        xr[10 * 64] = f2b(sx);
        xr[11 * 64] = f2b(sy);
    } else if (i < 3239936) {
        slots0[i - 3076096] = 0.0f;
    } else {
        slotsb0[i - 3239936] = 0;
    }
}

// ---------------- bf16 MFMA NT GEMM (big path; residual read as bf16) ----------------
template <int BM, int BN, int ACT>
__global__ __launch_bounds__(256) void gemm_bf16(
    const unsigned short* __restrict__ A, const unsigned short* __restrict__ W,
    const float* __restrict__ bias, const unsigned short* __restrict__ resb,
    float* __restrict__ C, unsigned short* __restrict__ Cb,
    int K, long sA, long sW, long sC1, long sC2, int cdiv, int ldc, float scale)
{
    constexpr bool HALF = (BM == 128 && BN == 64);
    constexpr int WN = BN / 64;
    constexpr int MF = HALF ? 2 : 4;
    __shared__ __align__(16) unsigned short As[BM * 32];
    __shared__ __align__(16) unsigned short Bs[BN * 32];
    const int tid = threadIdx.x;
    const int w = tid >> 6, l = tid & 63;
    const int wrow0 = HALF ? w * 32 : (w / WN) * 64;
    const int wcol0 = HALF ? 0 : (w % WN) * 64;
    const int bz = blockIdx.z;
    const unsigned short* Ab = A + (long)bz * sA + (long)(blockIdx.y * BM) * K;
    const unsigned short* Wb = W + (long)bz * sW + (long)(blockIdx.x * BN) * K;
    const long offC = (long)(bz / cdiv) * sC1 + (long)(bz % cdiv) * sC2;

    const int rA  = l >> 2;
    const int swz = ((l & 3) ^ ((l >> 3) & 3)) * 8;

    f32x4 acc[MF][4] = {};

    for (int k0 = 0; k0 < K; k0 += 32) {
#pragma unroll
        for (int c = 0; c < BM / 64; c++) {
            const int chunk = w * (BM / 64) + c;
            gload_lds16(Ab + (long)(chunk * 16 + rA) * K + k0 + swz, (char*)As + chunk * 1024);
        }
#pragma unroll
        for (int c = 0; c < BN / 64; c++) {
            const int chunk = w * (BN / 64) + c;
            gload_lds16(Wb + (long)(chunk * 16 + rA) * K + k0 + swz, (char*)Bs + chunk * 1024);
        }
        __syncthreads();
        short8 af[MF], bfr[4];
#pragma unroll
        for (int m = 0; m < MF; m++) {
            const int row = wrow0 + m * 16 + (l & 15);
            const int byte = row * 64 + (((l >> 4) ^ ((row >> 1) & 3)) << 4);
            af[m] = *(const short8*)((const char*)As + byte);
        }
#pragma unroll
        for (int n = 0; n < 4; n++) {
            const int row = wcol0 + n * 16 + (l & 15);
            const int byte = row * 64 + (((l >> 4) ^ ((row >> 1) & 3)) << 4);
            bfr[n] = *(const short8*)((const char*)Bs + byte);
        }
#pragma unroll
        for (int m = 0; m < MF; m++)
#pragma unroll
            for (int n = 0; n < 4; n++)
                acc[m][n] = __builtin_amdgcn_mfma_f32_16x16x32_bf16(af[m], bfr[n], acc[m][n], 0, 0, 0);
        __syncthreads();
    }

    const int crow0 = blockIdx.y * BM + wrow0;
    const int ccol0 = blockIdx.x * BN + wcol0;
#pragma unroll
    for (int m = 0; m < MF; m++) {
#pragma unroll
        for (int n = 0; n < 4; n++) {
            const int row = crow0 + m * 16 + ((l >> 4) << 2);
            const int col = ccol0 + n * 16 + (l & 15);
#pragma unroll
            for (int r = 0; r < 4; r++) {
                float v = acc[m][n][r] * scale;
                if (bias) v += bias[col];
                if (ACT == 1) v = gelu_exact(v);
                const long idx = offC + (long)(row + r) * ldc + col;
                if (resb) v += b2f(resb[idx]);
                if (C)  C[idx] = v;
                if (Cb) Cb[idx] = f2b(v);
            }
        }
    }
}

// ---------------- small bf16 MFMA NT GEMM (slot loop): 64x64 tile ----------------
template <int ACT>
__global__ __launch_bounds__(256) void gemm_bf16_s(
    const unsigned short* __restrict__ A, const unsigned short* __restrict__ W,
    const float* __restrict__ bias0, const float* __restrict__ bias1,
    const float* __restrict__ res,
    float* __restrict__ C, unsigned short* __restrict__ Cb,
    int K, int N, long sA, long sW, long sC, float scale)
{
    __shared__ __align__(16) unsigned short As[64 * 32];
    __shared__ __align__(16) unsigned short Bs[64 * 32];
    const int tid = threadIdx.x;
    const int w = tid >> 6, l = tid & 63;
    const int gw = l >> 4, l15 = l & 15;
    const int bz = blockIdx.z;
    const unsigned short* Ab = A + (long)bz * sA + (long)(blockIdx.y * 64) * K;
    const unsigned short* Wb = W + (long)bz * sW + (long)(blockIdx.x * 64) * K;
    const float* bias = (bz == 0) ? bias0 : bias1;
    const long offC = (long)bz * sC;

    const int rA  = l >> 2;
    const int swz = ((l & 3) ^ ((l >> 3) & 3)) * 8;

    f32x4 acc[4] = {};

    for (int k0 = 0; k0 < K; k0 += 32) {
        gload_lds16(Ab + (long)(w * 16 + rA) * K + k0 + swz, (char*)As + w * 1024);
        gload_lds16(Wb + (long)(w * 16 + rA) * K + k0 + swz, (char*)Bs + w * 1024);
        __syncthreads();
        short8 af[4];
#pragma unroll
        for (int m = 0; m < 4; m++) {
            const int row = m * 16 + l15;
            af[m] = *(const short8*)((const char*)As + row * 64 + ((gw ^ ((row >> 1) & 3)) << 4));
        }
        const int brow = w * 16 + l15;
        const short8 bf = *(const short8*)((const char*)Bs + brow * 64 + ((gw ^ ((brow >> 1) & 3)) << 4));
#pragma unroll
        for (int m = 0; m < 4; m++)
            acc[m] = __builtin_amdgcn_mfma_f32_16x16x32_bf16(af[m], bf, acc[m], 0, 0, 0);
        __syncthreads();
    }

    const int col = blockIdx.x * 64 + w * 16 + l15;
    const int row0 = blockIdx.y * 64;
#pragma unroll
    for (int m = 0; m < 4; m++) {
        const int row = row0 + m * 16 + (gw << 2);
#pragma unroll
        for (int r = 0; r < 4; r++) {
            float v = acc[m][r] * scale;
            if (bias) v += bias[col];
            if (ACT == 1) v = gelu_exact(v);
            const long idx = offC + (long)(row + r) * N + col;
            if (res) v += res[idx];
            if (C)  C[idx] = v;
            if (Cb) Cb[idx] = f2b(v);
        }
    }
}

// ---------------- LayerNorm (wave per row), templated in/out ----------------
template <typename IT, typename OT>
__global__ __launch_bounds__(256) void ln_rows(const IT* __restrict__ X,
                                               OT* __restrict__ Y,
                                               const float* __restrict__ g,
                                               const float* __restrict__ b,
                                               int rows, int D) {
    int gtid = blockIdx.x * 256 + threadIdx.x;
    int row = gtid >> 6;
    int lane = gtid & 63;
    if (row >= rows) return;
    const IT* x = X + (long)row * D;
    const int nv = D >> 6;
    float v[5];
    float s = 0.0f;
#pragma unroll 5
    for (int i = 0; i < nv; i++) { v[i] = load_el(&x[lane + (i << 6)]); s += v[i]; }
#pragma unroll
    for (int o = 32; o; o >>= 1) s += __shfl_down(s, o);
    s = __shfl(s, 0);
    float mean = s / (float)D;
    float s2 = 0.0f;
#pragma unroll 5
    for (int i = 0; i < nv; i++) { float d = v[i] - mean; s2 += d * d; }
#pragma unroll
    for (int o = 32; o; o >>= 1) s2 += __shfl_down(s2, o);
    s2 = __shfl(s2, 0);
    float inv = rsqrtf(s2 / (float)D + 1e-5f);
    OT* y = Y + (long)row * D;
#pragma unroll 5
    for (int i = 0; i < nv; i++) {
        int d = lane + (i << 6);
        store_el(&y[d], (v[i] - mean) * inv * g[d] + b[d]);
    }
}

// ---------------- fused GRU + LayerNorm(nm) (wave per row) ----------------
__global__ __launch_bounds__(256) void gru_ln(const float* __restrict__ GI,
                                              const float* __restrict__ GH,
                                              float* __restrict__ slots,
                                              const float* __restrict__ g,
                                              const float* __restrict__ b,
                                              unsigned short* __restrict__ SLnb) {
    int gtid = blockIdx.x * 256 + threadIdx.x;
    int row = gtid >> 6;        // < 512
    int lane = gtid & 63;
    const float* gi = GI + (long)row * 960;
    const float* gh = GH + (long)row * 960;
    float* sl = slots + (long)row * FD;
    float h[5];
    float s = 0.0f;
#pragma unroll
    for (int i = 0; i < 5; i++) {
        const int f = lane + (i << 6);
        const float rr = sigm(gi[f] + gh[f]);
        const float z  = sigm(gi[320 + f] + gh[320 + f]);
        const float nn = tanhf(gi[640 + f] + rr * gh[640 + f]);
        const float hn = (1.0f - z) * nn + z * sl[f];
        h[i] = hn;
        s += hn;
        sl[f] = hn;
    }
#pragma unroll
    for (int o = 32; o; o >>= 1) s += __shfl_down(s, o);
    s = __shfl(s, 0);
    const float mean = s * (1.0f / FD);
    float s2 = 0.0f;
#pragma unroll
    for (int i = 0; i < 5; i++) { const float d = h[i] - mean; s2 += d * d; }
#pragma unroll
    for (int o = 32; o; o >>= 1) s2 += __shfl_down(s2, o);
    s2 = __shfl(s2, 0);
    const float inv = rsqrtf(s2 * (1.0f / FD) + 1e-5f);
    unsigned short* y = SLnb + (long)row * FD;
#pragma unroll
    for (int i = 0; i < 5; i++) {
        const int f = lane + (i << 6);
        y[f] = f2b((h[i] - mean) * inv * g[f] + b[f]);
    }
}

// ---------------- fused attention w/ in-kernel RoPE: one wg per (b,h,p) ----------------
// LDS: V^T 32K @0, K 32K @32768, Q 16K @65536, P 16K @81920
__global__ __launch_bounds__(256, 1) void fused_attn(
    const unsigned short* __restrict__ QKVb,
    const float* __restrict__ cs, const float* __restrict__ sn,
    unsigned short* __restrict__ AOb)
{
    __shared__ __align__(16) char SL[98304];
    const int h = blockIdx.x, b = blockIdx.y;
    const int p = blockIdx.z;
    const int tid = threadIdx.x;
    const int w = tid >> 6, l = tid & 63;
    const int gw = l >> 4, l15 = l & 15;

    // ---- V^T staging (swizzled) ----
    {
        const int n0 = (tid & 127) * 2;
        const int dh = tid >> 7;
        const unsigned short* v0p = QKVb + ((long)b * NN + n0) * 768 + h * 64 + 512 + dh * 32;
        const unsigned short* v1p = v0p + 768;
        unsigned short v0[32], v1[32];
#pragma unroll
        for (int i = 0; i < 4; i++) {
            *(short8*)&v0[i * 8] = *(const short8*)(v0p + i * 8);
            *(short8*)&v1[i * 8] = *(const short8*)(v1p + i * 8);
        }
#pragma unroll
        for (int i = 0; i < 32; i++) {
            const int d = dh * 32 + i;
            const unsigned val = (unsigned)v0[i] | ((unsigned)v1[i] << 16);
            *(unsigned*)(SL + d * 512 + (((n0 >> 3) ^ (d & 15)) << 4) + (n0 & 7) * 2) = val;
        }
    }
    // ---- K rope staging: thread t ropes row n = t ----
    {
        const int n = tid;
        const unsigned short* src = QKVb + ((long)(b * NN + n)) * 768 + h * 64 + 256;
        float x[64];
#pragma unroll
        for (int i = 0; i < 8; i++) {
            short8 v = *(const short8*)(src + i * 8);
#pragma unroll
            for (int j = 0; j < 8; j++) x[i * 8 + j] = b2f((unsigned short)v[j]);
        }
        unsigned short o[64];
#pragma unroll
        for (int d = 0; d < 64; d++) {
            const float rot = (d < 32) ? -x[2 * d + 1] : x[2 * (d - 32)];
            o[d] = f2b(x[d] * cs[n * 64 + d] + rot * sn[n * 64 + d]);
        }
        char* kb = SL + 32768 + n * 128;
        const int xo = (n & 7) << 4;
#pragma unroll
        for (int i = 0; i < 8; i++)
            *(short8*)(kb + ((i * 16) ^ xo)) = *(short8*)&o[i * 8];
    }
    // ---- Q rope staging: t<128 ropes local row r=t, global row (t>>5)*64 + p*32 + (t&31) ----
    if (tid < 128) {
        const int r = tid;
        const int gq = (r >> 5) * 64 + p * 32 + (r & 31);
        const unsigned short* src = QKVb + ((long)(b * NN + gq)) * 768 + h * 64;
        float x[64];
#pragma unroll
        for (int i = 0; i < 8; i++) {
            short8 v = *(const short8*)(src + i * 8);
#pragma unroll
            for (int j = 0; j < 8; j++) x[i * 8 + j] = b2f((unsigned short)v[j]);
        }
        unsigned short o[64];
#pragma unroll
        for (int d = 0; d < 64; d++) {
            const float rot = (d < 32) ? -x[2 * d + 1] : x[2 * (d - 32)];
            o[d] = f2b(x[d] * cs[gq * 64 + d] + rot * sn[gq * 64 + d]);
        }
        char* qb = SL + 65536 + r * 128;
        const int xo = (r & 7) << 4;
#pragma unroll
        for (int i = 0; i < 8; i++)
            *(short8*)(qb + ((i * 16) ^ xo)) = *(short8*)&o[i * 8];
    }
    __syncthreads();

    char* Pw = SL + 81920 + w * 4096;

    {
        const int mbase = w * 64 + p * 32;
        f32x4 accs[16][2] = {};
#pragma unroll
        for (int kk = 0; kk < 2; kk++) {
            const int cb = (kk * 64 + gw * 16);
            short8 bq[2];
#pragma unroll
            for (int mf = 0; mf < 2; mf++) {
                const int r = w * 32 + mf * 16 + l15;
                bq[mf] = *(const short8*)(SL + 65536 + r * 128 + (cb ^ ((r & 7) << 4)));
            }
#pragma unroll
            for (int nf = 0; nf < 16; nf++) {
                const int n = nf * 16 + l15;
                const short8 ak = *(const short8*)(SL + 32768 + n * 128 + (cb ^ ((n & 7) << 4)));
#pragma unroll
                for (int mf = 0; mf < 2; mf++)
                    accs[nf][mf] = __builtin_amdgcn_mfma_f32_16x16x32_bf16(ak, bq[mf], accs[nf][mf], 0, 0, 0);
            }
        }
        float rs[2];
#pragma unroll
        for (int mf = 0; mf < 2; mf++) {
            float mx = -1e30f;
#pragma unroll
            for (int nf = 0; nf < 16; nf++)
#pragma unroll
                for (int r = 0; r < 4; r++) mx = fmaxf(mx, accs[nf][mf][r]);
            mx = fmaxf(mx, __shfl_xor(mx, 16));
            mx = fmaxf(mx, __shfl_xor(mx, 32));
            float sum = 0.0f;
#pragma unroll
            for (int nf = 0; nf < 16; nf++)
#pragma unroll
                for (int r = 0; r < 4; r++) {
                    const float e = expf((accs[nf][mf][r] - mx) * 0.125f);
                    accs[nf][mf][r] = e;
                    sum += e;
                }
            sum += __shfl_xor(sum, 16);
            sum += __shfl_xor(sum, 32);
            rs[mf] = 1.0f / sum;
        }
        f32x4 acco[4][2] = {};
#pragma unroll
        for (int c = 0; c < 4; c++) {
#pragma unroll
            for (int nfi = 0; nfi < 4; nfi++) {
                const int nf = c * 4 + nfi;
                const int kt = nf >> 1;
                const int gr = (nf & 1) * 2 + (gw >> 1);
                const int lr = l15 + 16 * gr;
                const int j0 = (gw & 1) * 4;
#pragma unroll
                for (int mf = 0; mf < 2; mf++) {
                    uint2 pk;
                    pk.x = (unsigned)f2b(accs[nf][mf][0] * rs[mf]) |
                           ((unsigned)f2b(accs[nf][mf][1] * rs[mf]) << 16);
                    pk.y = (unsigned)f2b(accs[nf][mf][2] * rs[mf]) |
                           ((unsigned)f2b(accs[nf][mf][3] * rs[mf]) << 16);
                    *(uint2*)(Pw + ((kt & 1) * 2 + mf) * 1024 + lr * 16 + j0 * 2) = pk;
                }
            }
#pragma unroll
            for (int kti = 0; kti < 2; kti++) {
                const int kt = c * 2 + kti;
                short8 vf[4];
#pragma unroll
                for (int df = 0; df < 4; df++) {
                    const int d = df * 16 + l15;
                    vf[df] = *(const short8*)(SL + d * 512 + (((kt * 4 + gw) ^ (d & 15)) << 4));
                }
#pragma unroll
                for (int mf = 0; mf < 2; mf++) {
                    const short8 pf = *(const short8*)(Pw + (kti * 2 + mf) * 1024 + l * 16);
#pragma unroll
                    for (int df = 0; df < 4; df++)
                        acco[df][mf] = __builtin_amdgcn_mfma_f32_16x16x32_bf16(vf[df], pf, acco[df][mf], 0, 0, 0);
                }
            }
        }
#pragma unroll
        for (int df = 0; df < 4; df++)
#pragma unroll
            for (int mf = 0; mf < 2; mf++) {
                const int m = mbase + mf * 16 + l15;
                const int d = df * 16 + gw * 4;
                unsigned short o[4];
#pragma unroll
                for (int r = 0; r < 4; r++) o[r] = f2b(acco[df][mf][r]);
                *(uint2*)(AOb + ((long)(b * NN + m) * 256 + h * 64 + d)) = *(uint2*)o;
            }
    }
}

// ---------------- slot logits + softmax over slots (bf16 K reads) ----------------
__global__ __launch_bounds__(256) void slot_logits(const unsigned short* __restrict__ KVin,
                                                   const float* __restrict__ Qs,
                                                   float* __restrict__ sattn,
                                                   float* __restrict__ sums2,
                                                   float* __restrict__ mout) {
    const int b = blockIdx.x;
    const int chunk = blockIdx.y;
    __shared__ float qs[NSL][FD];
    __shared__ float colsum[NSL];
    const int tid = threadIdx.x;
    for (int i = tid; i < NSL * FD; i += 256) qs[i / FD][i % FD] = Qs[(long)b * NSL * FD + i];
    if (tid < NSL) colsum[tid] = 0.0f;
    __syncthreads();
    const int wv = tid >> 6, lane = tid & 63;
    float wsum[NSL] = {};
#pragma unroll
    for (int rr = 0; rr < 4; rr++) {
        const int r = chunk * 16 + wv * 4 + rr;
        const unsigned short* kr = KVin + ((long)b * NN + r) * 640;
        float acc[NSL] = {};
#pragma unroll
        for (int i = 0; i < 5; i++) {
            const int t = lane + (i << 6);
            const float kv = b2f(kr[t]);
#pragma unroll
            for (int s = 0; s < NSL; s++) acc[s] = fmaf(kv, qs[s][t], acc[s]);
        }
#pragma unroll
        for (int s = 0; s < NSL; s++)
#pragma unroll
            for (int o = 32; o; o >>= 1) acc[s] += __shfl_down(acc[s], o);
        if (lane == 0) {
            const float scale = 0.055901699437494740f;  // 1/sqrt(320)
            float mx = -1e30f;
#pragma unroll
            for (int s = 0; s < NSL; s++) { acc[s] *= scale; mx = fmaxf(mx, acc[s]); }
            float e[NSL], sum = 0.0f;
#pragma unroll
            for (int s = 0; s < NSL; s++) { e[s] = expf(acc[s] - mx); sum += e[s]; }
            const float rsum = 1.0f / sum;
            float* outp = sattn + ((long)b * NN + r) * NSL;
#pragma unroll
            for (int s = 0; s < NSL; s++) {
                const float pp = e[s] * rsum;
                outp[s] = pp;
                wsum[s] += pp;
                if (mout) mout[(long)b * 2048 + s * 256 + r] = pp;
            }
        }
    }
    if (lane == 0) {
#pragma unroll
        for (int s = 0; s < NSL; s++) atomicAdd(&colsum[s], wsum[s]);
    }
    __syncthreads();
    if (tid < NSL) sums2[((long)(b << 4) + chunk) * NSL + tid] = colsum[tid];
}

// ---------------- slot updates: block per b, LDS reduce, bf16 in/out ----------------
__global__ __launch_bounds__(256) void slot_updates(const float* __restrict__ sattn,
                                                    const float* __restrict__ sums2,
                                                    const unsigned short* __restrict__ KVin,
                                                    unsigned short* __restrict__ Updb) {
    const int b = blockIdx.x;
    const int tid = threadIdx.x;
    const int w = tid >> 6, l = tid & 63;
    __shared__ float inv_s[NSL];
    __shared__ float an_s[NN][NSL];
    __shared__ float red[4][NSL][FD];
    if (tid < NSL) {
        float tot = (float)NN * 1e-8f;
#pragma unroll
        for (int c = 0; c < 16; c++) tot += sums2[((long)(b << 4) + c) * NSL + tid];
        inv_s[tid] = 1.0f / tot;
    }
    __syncthreads();
    {
        const float4 p0 = *(const float4*)(sattn + ((long)b * NN + tid) * NSL);
        const float4 p1 = *(const float4*)(sattn + ((long)b * NN + tid) * NSL + 4);
        an_s[tid][0] = (p0.x + 1e-8f) * inv_s[0];
        an_s[tid][1] = (p0.y + 1e-8f) * inv_s[1];
        an_s[tid][2] = (p0.z + 1e-8f) * inv_s[2];
        an_s[tid][3] = (p0.w + 1e-8f) * inv_s[3];
        an_s[tid][4] = (p1.x + 1e-8f) * inv_s[4];
        an_s[tid][5] = (p1.y + 1e-8f) * inv_s[5];
        an_s[tid][6] = (p1.z + 1e-8f) * inv_s[6];
        an_s[tid][7] = (p1.w + 1e-8f) * inv_s[7];
    }
    __syncthreads();
    float acc[NSL][5] = {};
    const unsigned short* vb = KVin + ((long)b * NN + w * 64) * 640 + 320;
    for (int i = 0; i < 64; i++) {
        float v[5];
#pragma unroll
        for (int j = 0; j < 5; j++) v[j] = b2f(vb[(long)i * 640 + l + (j << 6)]);
        float a[NSL];
#pragma unroll
        for (int s = 0; s < NSL; s++) a[s] = an_s[w * 64 + i][s];
#pragma unroll
        for (int s = 0; s < NSL; s++)
#pragma unroll
            for (int j = 0; j < 5; j++)
                acc[s][j] = fmaf(a[s], v[j], acc[s][j]);
    }
#pragma unroll
    for (int s = 0; s < NSL; s++)
#pragma unroll
        for (int j = 0; j < 5; j++)
            red[w][s][l + (j << 6)] = acc[s][j];
    __syncthreads();
    for (int idx = tid; idx < NSL * FD; idx += 256) {
        const int s = idx / FD, f = idx % FD;
        const float tot = red[0][s][f] + red[1][s][f] + red[2][s][f] + red[3][s][f];
        Updb[((long)b * NSL + s) * FD + f] = f2b(tot);
    }
}

// ---------------- host launcher ----------------
extern "C" void kernel_launch(void* const* d_in, const int* in_sizes, int n_in,
                              void* d_out, int out_size, void* d_ws, size_t ws_size,
                              hipStream_t stream) {
    const float* state    = (const float*)d_in[0];
    const float* conv_w   = (const float*)d_in[1];
    const float* conv_b   = (const float*)d_in[2];
    const float* mlp_ln_g = (const float*)d_in[3];
    const float* mlp_ln_b = (const float*)d_in[4];
    const float* mlp_w1   = (const float*)d_in[5];
    const float* mlp_b1   = (const float*)d_in[6];
    const float* mlp_w2   = (const float*)d_in[7];
    const float* mlp_b2   = (const float*)d_in[8];
    const float* qkv_w    = (const float*)d_in[9];
    const float* qkv_b    = (const float*)d_in[10];
    const float* proj_w   = (const float*)d_in[11];
    const float* proj_b   = (const float*)d_in[12];
    const float* ni_g     = (const float*)d_in[13];
    const float* ni_b     = (const float*)d_in[14];
    const float* ns_g     = (const float*)d_in[15];
    const float* ns_b     = (const float*)d_in[16];
    const float* nm_g     = (const float*)d_in[17];
    const float* nm_b     = (const float*)d_in[18];
    const float* q_w      = (const float*)d_in[19];
    const float* k_w      = (const float*)d_in[20];
    const float* v_w      = (const float*)d_in[21];
    const float* gru_wih  = (const float*)d_in[22];
    const float* gru_whh  = (const float*)d_in[23];
    const float* gru_bih  = (const float*)d_in[24];
    const float* gru_bhh  = (const float*)d_in[25];
    const float* smlp_w1  = (const float*)d_in[26];
    const float* smlp_b1  = (const float*)d_in[27];
    const float* smlp_w2  = (const float*)d_in[28];
    const float* smlp_b2  = (const float*)d_in[29];

    float* ws = (float*)d_ws;
    const int M = BB * NN;  // 16384
    typedef unsigned short u16;

    // ---- workspace layout (float offsets) ----
    u16*   X0b  = (u16*)(ws + 0L);
    u16*   X1b  = (u16*)(ws + 6291456L);       // 4194304 u16
    u16*   XLNb = (u16*)(ws + 10485760L);
    u16*   Hbufb= (u16*)(ws + 12582912L);
    u16*   QKVb = (u16*)(ws + 6291456L);       // aliases X1b region (X1b dead by then)
    u16*   X2b  = (u16*)(ws + 23068672L);
    u16*   X3b  = (u16*)(ws + 31457280L);      // 4194304 u16
    u16*   Xnb  = (u16*)(ws + 33554432L);
    float* Slots= ws + 35651584L;              // 163840 f32
    float* Qs   = ws + 35979264L;              // 163840
    float* Satt = ws + 36143104L;              // 131072
    float* Sums2= ws + 36274176L;              // 8192 (b x 16 x 8)
    float* GI   = ws + 36438528L;              // 491520
    float* GH   = ws + 36930048L;              // 491520
    u16*   SLnb = (u16*)(ws + 37421568L);      // 163840 u16
    u16*   Updb = (u16*)(ws + 37503488L);      // 163840 u16
    u16*   Slotsb=(u16*)(ws + 37585408L);      // 163840 u16 == Updb + 163840 (z=2 stride!)
    u16*   Mhb  = (u16*)(ws + 37667328L);      // 327680 u16
    u16*   KVinb= (u16*)(ws + 39845888L);      // 16384*640 u16
    u16*   AOb    = (u16*)(ws + 50331648L);
    u16*   wb     = (u16*)(ws + 52428800L);    // 2011136 u16 contiguous
    u16*   conv_wb= wb + 0;
    u16*   mlp_w1b= wb + 196608;
    u16*   mlp_w2b= wb + 327680;
    u16*   qkv_wb = wb + 458752;
    u16*   proj_wb= wb + 655360;
    u16*   kv_wb  = wb + 720896;     // k_w rows (320) then v_w rows (320) = N=640
    u16*   q_wb   = wb + 884736;
    u16*   wihb   = wb + 987136;
    u16*   whhb   = wb + 1294336;
    u16*   smlp1b = wb + 1601536;
    u16*   smlp2b = wb + 1806336;
    float* CS     = ws + 53434368L;
    float* SN     = ws + 53450752L;

    float* out = (float*)d_out;

    auto gemmA = [&](const u16* A, const u16* Wt, const float* bias, const u16* resb,
                     float* C, u16* Cb, int Mm, int Nn, int Kk, int batch,
                     long sA, long sW, long sC1, long sC2, int cdiv, int ldc,
                     float scale, int act) {
        dim3 grid(Nn / 128, Mm / 128, batch);
        if (act) gemm_bf16<128, 128, 1><<<grid, 256, 0, stream>>>(A, Wt, bias, resb, C, Cb, Kk, sA, sW, sC1, sC2, cdiv, ldc, scale);
        else     gemm_bf16<128, 128, 0><<<grid, 256, 0, stream>>>(A, Wt, bias, resb, C, Cb, Kk, sA, sW, sC1, sC2, cdiv, ldc, scale);
    };
    // 128x64-tile variant: 2 blocks/CU for N=256 GEMMs
    auto gemmA64 = [&](const u16* A, const u16* Wt, const float* bias, const u16* resb,
                       float* C, u16* Cb, int Mm, int Nn, int Kk, int ldc) {
        dim3 grid(Nn / 64, Mm / 128, 1);
        gemm_bf16<128, 64, 0><<<grid, 256, 0, stream>>>(A, Wt, bias, resb, C, Cb, Kk, 0, 0, 0, 0, 1, ldc, 1.0f);
    };
    auto gemmB = [&](const u16* A, const u16* Wt, u16* Cb, int Mm, int Nn, int Kk) {
        dim3 grid(Nn / 64, Mm / 256, 1);
        gemm_bf16<256, 64, 0><<<grid, 256, 0, stream>>>(A, Wt, nullptr, nullptr, nullptr, Cb, Kk, 0, 0, 0, 0, 1, Nn, 1.0f);
    };
    auto gemmS = [&](const u16* A, const u16* Wt, const float* b0, const float* b1,
                     const float* res, float* C, u16* Cb, int Mm, int Nn, int Kk,
                     int batch, long sA, long sW, long sC, int act) {
        dim3 grid(Nn / 64, Mm / 64, batch);
        if (act) gemm_bf16_s<1><<<grid, 256, 0, stream>>>(A, Wt, b0, b1, res, C, Cb, Kk, Nn, sA, sW, sC, 1.0f);
        else     gemm_bf16_s<0><<<grid, 256, 0, stream>>>(A, Wt, b0, b1, res, C, Cb, Kk, Nn, sA, sW, sC, 1.0f);
    };

    // 0. prep: weight cvt + rope tables + sobel/im2col + slot zeroing (one kernel)
    prep_all<<<dim3(3403776 / 256), 256, 0, stream>>>(conv_w, mlp_w1, mlp_w2, qkv_w,
                                                      proj_w, k_w, v_w, q_w,
                                                      gru_wih, gru_whh, smlp_w1, smlp_w2,
                                                      wb, CS, SN, state, X0b, Slots, Slotsb);

    // 2. patch conv GEMM -> X1b bf16 (128x64 tiles, 512 blocks)
    gemmA64(X0b, conv_wb, conv_b, nullptr, nullptr, X1b, M, EE, KIM, EE);
    // 3. LN -> bf16, MLP
    ln_rows<<<dim3(M * 64 / 256), 256, 0, stream>>>(X1b, XLNb, mlp_ln_g, mlp_ln_b, M, EE);
    gemmA(XLNb, mlp_w1b, mlp_b1, nullptr, nullptr, Hbufb, M, 2 * EE, EE, 1, 0, 0, 0, 0, 1, 2 * EE, 1.0f, 1);
    gemmA64(Hbufb, mlp_w2b, mlp_b2, nullptr, nullptr, X2b, M, EE, 2 * EE, EE);
    // 4. QKV
    gemmA(X2b, qkv_wb, qkv_b, nullptr, nullptr, QKVb, M, 3 * EE, EE, 1, 0, 0, 0, 0, 1, 3 * EE, 1.0f, 0);
    // 5. fused attention (rope inside; p split across z -> 512 blocks)
    fused_attn<<<dim3(NHEAD, BB, 2), 256, 0, stream>>>(QKVb, CS, SN, AOb);
    // 6. proj + residual (bf16 res) -> X3b bf16 (128x64 tiles)
    gemmA64(AOb, proj_wb, proj_b, X2b, nullptr, X3b, M, EE, EE, EE);
    // 7. LN ni -> bf16, fused K/V projection (N=640, bf16 out)
    ln_rows<<<dim3(M * 64 / 256), 256, 0, stream>>>(X3b, Xnb, ni_g, ni_b, M, EE);
    gemmB(Xnb, kv_wb, KVinb, M, 640, EE);
    // 8. slot attention loop
    for (int it = 0; it < 3; it++) {
        ln_rows<<<dim3(512 * 64 / 256), 256, 0, stream>>>(Slots, SLnb, ns_g, ns_b, 512, FD);
        gemmS(SLnb, q_wb, nullptr, nullptr, nullptr, Qs, nullptr, 512, FD, FD, 1, 0, 0, 0, 0);
        slot_logits<<<dim3(BB, 16), 256, 0, stream>>>(KVinb, Qs, Satt, Sums2,
                                                      (it == 2) ? (out + 163840) : nullptr);
        slot_updates<<<dim3(BB), 256, 0, stream>>>(Satt, Sums2, KVinb, Updb);
        // GI = Updb@wih + bih ; GH = Slotsb@whh + bhh  (one launch, z=2; Slotsb == Updb+163840)
        gemmS(Updb, wihb, gru_bih, gru_bhh, nullptr, GI, nullptr, 512, 960, FD,
              2, 163840, 307200, 491520, 0);
        gru_ln<<<dim3(512 * 64 / 256), 256, 0, stream>>>(GI, GH, Slots, nm_g, nm_b, SLnb);
        gemmS(SLnb, smlp1b, smlp_b1, nullptr, nullptr, nullptr, Mhb, 512, 2 * FD, FD, 1, 0, 0, 0, 1);
        if (it < 2)
            gemmS(Mhb, smlp2b, smlp_b2, nullptr, Slots, Slots, Slotsb, 512, FD, 2 * FD, 1, 0, 0, 0, 0);
        else
            gemmS(Mhb, smlp2b, smlp_b2, nullptr, Slots, out, nullptr, 512, FD, 2 * FD, 1, 0, 0, 0, 0);
    }
}